// Round 5
// baseline (438.593 us; speedup 1.0000x reference)
//
#include <hip/hip_runtime.h>
#include <hip/hip_bf16.h>

#define NN 20000
#define EE 320000
#define HD 128   // hidden

typedef _Float16 half8 __attribute__((ext_vector_type(8)));
typedef _Float16 half4 __attribute__((ext_vector_type(4)));
typedef _Float16 half2v __attribute__((ext_vector_type(2)));
typedef float floatx4 __attribute__((ext_vector_type(4)));
typedef float float2v __attribute__((ext_vector_type(2)));

// silu via HW rcp (1-ulp) instead of exact fp32 divide.
__device__ __forceinline__ float silu_f(float x){
  float e = __expf(-x);
  return x * __builtin_amdgcn_rcpf(1.f + e);
}

__device__ __forceinline__ bool ei_is64(const int* __restrict__ ei){
  return (ei[1] | ei[3] | ei[5] | ei[7]) == 0;
}
__device__ __forceinline__ int ei_src(const int* __restrict__ ei, int e, bool is64){
  return is64 ? ei[2*(size_t)e] : ei[e];
}
__device__ __forceinline__ int ei_dst(const int* __restrict__ ei, int e, bool is64){
  return is64 ? ei[2*(size_t)EE + 2*(size_t)e] : ei[EE + e];
}

__global__ __launch_bounds__(256) void sentinel_kernel(float* __restrict__ out, int n, float val){
  int i = blockIdx.x*256 + threadIdx.x;
  if (i < n) out[i] = val;
}

// ---------------- merged weight packing (w1p | w2p | dec) ----------------
__global__ __launch_bounds__(256) void pack_all_kernel(const float* __restrict__ cw1,
                                                       const float* __restrict__ cw2,
                                                       const float* __restrict__ dw1,
                                                       const float* __restrict__ dw2,
                                                       _Float16* __restrict__ w1p,
                                                       _Float16* __restrict__ w2p,
                                                       _Float16* __restrict__ w1dp,
                                                       _Float16* __restrict__ w2dp){
  int idx = blockIdx.x*256 + threadIdx.x;   // 1248 blocks = 319488 exact
  if (idx < 196608){
    int j   = idx & 7;
    int ln  = (idx >> 3) & 63;
    int rest= idx >> 9;
    int cb  = rest & 15;
    int rest2 = rest >> 4;
    int ks  = rest2 & 3;
    int l   = rest2 >> 2;
    int k = ks*32 + (ln>>4)*8 + j;
    int c = cb*16 + (ln&15);
    float v = (c < 128) ? cw1[(size_t)l*33152 + (size_t)k*128 + c]
                        : cw1[(size_t)l*33152 + (size_t)(128+k)*128 + (c-128)];
    w1p[idx] = (_Float16)v;
  } else if (idx < 294912){
    int t = idx - 196608;
    int j   = t & 7;
    int ln  = (t >> 3) & 63;
    int rest= t >> 9;
    int cb  = rest & 7;
    int rest2 = rest >> 3;
    int ks  = rest2 & 3;
    int l   = rest2 >> 2;
    int k = ks*32 + (ln>>4)*8 + j;
    int c = cb*16 + (ln&15);
    w2p[t] = (_Float16)cw2[(size_t)l*16384 + (size_t)k*128 + c];
  } else {
    int t2 = idx - 294912;
    if (t2 < 16384){
      int j = t2 & 7, ln = (t2>>3)&63, cb = (t2>>9)&7, ks = t2>>12;
      int k = ks*32 + (ln>>4)*8 + j;
      int c = cb*16 + (ln&15);
      w1dp[t2] = (_Float16)dw1[(size_t)k*128 + c];
    } else {
      int t = t2 - 16384;
      int j = t & 7, ln = (t>>3)&63, cb = (t>>9)&3, ks = t>>11;
      int k = ks*32 + (ln>>4)*8 + j;
      int c = cb*16 + (ln&15);
      w2dp[t] = (_Float16)dw2[(size_t)k*64 + c];
    }
  }
}

// ---------------- CSR build ----------------
__global__ __launch_bounds__(256) void count_kernel(const int* __restrict__ ei, int* __restrict__ cnt){
  int e = blockIdx.x*256 + threadIdx.x;   // EE/256 exact
  bool is64 = ei_is64(ei);
  atomicAdd(&cnt[ei_dst(ei, e, is64)], 1);
}

__global__ __launch_bounds__(1024) void scan_kernel(int* __restrict__ cntcur,
                                                    int* __restrict__ row_start,
                                                    float* __restrict__ invd){
  __shared__ int part[1024];
  const int t = threadIdx.x;
  const int base = t*20;
  int loc[20];
  int sum = 0;
  #pragma unroll
  for (int i=0;i<20;++i){
    int n = base+i;
    int v = (n < NN) ? cntcur[n] : 0;
    loc[i] = sum; sum += v;
  }
  part[t] = sum;
  __syncthreads();
  for (int off=1; off<1024; off<<=1){
    int v = (t >= off) ? part[t-off] : 0;
    __syncthreads();
    part[t] += v;
    __syncthreads();
  }
  int pre = (t > 0) ? part[t-1] : 0;
  #pragma unroll
  for (int i=0;i<20;++i){
    int n = base+i;
    if (n < NN){
      int rs = pre + loc[i];
      int deg = ((i<19)?loc[i+1]:sum) - loc[i];
      row_start[n] = rs;
      invd[n] = (deg > 0) ? 1.f/(float)deg : 0.f;
      cntcur[n] = rs;
    }
  }
  if (t == 1023) row_start[NN] = part[1023];
}

// scatter: split arrays — src_s (int, pre-scaled offset; 4 consecutive = one
// int4 quad load in edge_agg) + ea_s (half4 per edge).
__global__ __launch_bounds__(256) void scatter_kernel(const int* __restrict__ ei,
                                                      const float* __restrict__ eattr,
                                                      int* __restrict__ cur,
                                                      int* __restrict__ src_s,
                                                      _Float16* __restrict__ ea_s){
  int e = blockIdx.x*256 + threadIdx.x;   // EE/256 exact
  bool is64 = ei_is64(ei);
  int s = ei_src(ei, e, is64);
  int d = ei_dst(ei, e, is64);
  int pos = atomicAdd(&cur[d], 1);
  src_s[pos] = s*256;   // pre-scaled UV row element-offset
  half4 ea;
  ea[0] = (_Float16)eattr[(size_t)e*3+0];
  ea[1] = (_Float16)eattr[(size_t)e*3+1];
  ea[2] = (_Float16)eattr[(size_t)e*3+2];
  ea[3] = (_Float16)0.f;
  *(half4*)(ea_s + (size_t)pos*4) = ea;
}

// ---------------- encoder: x(N,14) -> h(N,128) fp32 + hh fp16 ----------------
__global__ __launch_bounds__(128) void encoder_kernel(
    const float* __restrict__ x, const float* __restrict__ w1, const float* __restrict__ b1,
    const float* __restrict__ w2, const float* __restrict__ b2,
    float* __restrict__ h, _Float16* __restrict__ hh)
{
  __shared__ float xs[16][14];
  __shared__ float s1[16][128];
  const int n0 = blockIdx.x*16;
  const int tid = threadIdx.x;
  for (int idx=tid; idx<224; idx+=128){
    int i = idx/14, k = idx%14;
    xs[i][k] = x[(size_t)(n0+i)*14 + k];
  }
  __syncthreads();
  const int o = tid;
  float acc[16];
  float bv = b1[o];
  #pragma unroll
  for (int i=0;i<16;++i) acc[i] = bv;
  for (int k=0;k<14;++k){
    float w = w1[k*128+o];
    #pragma unroll
    for (int i=0;i<16;++i) acc[i] += xs[i][k]*w;
  }
  #pragma unroll
  for (int i=0;i<16;++i) s1[i][o] = silu_f(acc[i]);
  __syncthreads();
  float bv2 = b2[o];
  #pragma unroll
  for (int i=0;i<16;++i) acc[i] = bv2;
  for (int k=0;k<128;k+=4){
    float w0=w2[(k+0)*128+o], w1v=w2[(k+1)*128+o], w2v=w2[(k+2)*128+o], w3v=w2[(k+3)*128+o];
    #pragma unroll
    for (int i=0;i<16;++i){
      float4 sv = *(const float4*)&s1[i][k];
      acc[i] += sv.x*w0 + sv.y*w1v + sv.z*w2v + sv.w*w3v;
    }
  }
  #pragma unroll
  for (int i=0;i<16;++i){
    size_t off = (size_t)(n0+i)*HD + o;
    h[off] = acc[i];
    hh[off] = (_Float16)acc[i];
  }
}

// ---------------- proj (1250 blocks, 4 cb/wave): UV = [hh·W1d + b1 | hh·W1s] ----------------
__global__ __launch_bounds__(256) void proj_kernel(
    const _Float16* __restrict__ hh, const _Float16* __restrict__ w1p,
    const float* __restrict__ b1, _Float16* __restrict__ UV)
{
  const int tid = threadIdx.x;
  const int wv  = tid >> 6;
  const int ln  = tid & 63;
  const int q   = ln >> 4;
  const int m   = ln & 15;
  const int n0  = blockIdx.x*16;      // grid = NN/16 = 1250 exact

  floatx4 acc[4];
  #pragma unroll
  for (int j=0;j<4;++j) acc[j] = (floatx4){0.f,0.f,0.f,0.f};

  #pragma unroll
  for (int ks=0; ks<4; ++ks){
    half8 a = *(const half8*)(hh + (size_t)(n0+m)*HD + ks*32 + q*8);
    const _Float16* wb = w1p + (size_t)(ks*16*64 + ln)*8;
    #pragma unroll
    for (int j=0; j<4; ++j){
      half8 b = *(const half8*)(wb + (size_t)(wv*4+j)*512);
      acc[j] = __builtin_amdgcn_mfma_f32_16x16x32_f16(a, b, acc[j], 0,0,0);
    }
  }
  #pragma unroll
  for (int j=0; j<4; ++j){
    const int c = (wv*4+j)*16 + m;
    const float bias = (c < 128) ? b1[c] : 0.f;
    #pragma unroll
    for (int r=0;r<4;++r)
      UV[(size_t)(n0+q*4+r)*256 + c] = (_Float16)(acc[j][r] + bias);
  }
}

// ---------------- edge_agg: per-node mean of silu(U+V[src]+ea·We) ----------------
// r5: rolling one-quad-ahead pipeline. Quads start at rs&~3 so src_s int4 and
// ea_s half8 loads are 16B-aligned; foreign leading/trailing edges are masked
// by an unsigned range compare + cndmask (NaN-safe). Per iteration: issue next
// quad's srcq/ea loads + its 4 gathers, THEN compute the current quad from
// registers — gather latency hides under a full iteration of compute, leaving
// only the srcq L2 hit (~200cy/4 edges) in-wave exposed.
__device__ __forceinline__ void edge_term(float2v& acc, half2v v,
                                          float ea0, float ea1, float ea2,
                                          float2v u, float2v wc0, float2v wc1, float2v wc2,
                                          bool ok){
  float2v p = u;
  p += ea0 * wc0;
  p += ea1 * wc1;
  p += ea2 * wc2;
  p[0] += (float)v[0];
  p[1] += (float)v[1];
  float s0 = silu_f(p[0]);
  float s1 = silu_f(p[1]);
  acc[0] += ok ? s0 : 0.f;
  acc[1] += ok ? s1 : 0.f;
}

__global__ __launch_bounds__(256) void edge_agg_kernel(
    const _Float16* __restrict__ UV, const int* __restrict__ row_start,
    const int* __restrict__ src_s, const _Float16* __restrict__ ea_s,
    const float* __restrict__ w1e, const float* __restrict__ invd,
    _Float16* __restrict__ S)
{
  const int tid = threadIdx.x;
  const int wv  = __builtin_amdgcn_readfirstlane(tid >> 6);
  const int ln  = tid & 63;
  const int n   = blockIdx.x*4 + wv;   // grid NN/4 = 5000 exact
  const int c0  = ln*2;

  const float2v wc0 = *(const float2v*)(w1e +   0 + c0);
  const float2v wc1 = *(const float2v*)(w1e + 128 + c0);
  const float2v wc2 = *(const float2v*)(w1e + 256 + c0);

  half2v uvp = *(const half2v*)(UV + (size_t)n*256 + c0);
  float2v u; u[0] = (float)uvp[0]; u[1] = (float)uvp[1];

  const int rs = row_start[n], re = row_start[n+1];
  float2v a0 = {0.f,0.f}, a1 = {0.f,0.f}, a2 = {0.f,0.f}, a3 = {0.f,0.f};

  if (re > rs){
    const _Float16* __restrict__ UVv = UV + 128 + c0;  // V-half base for this lane
    const unsigned OMAX = (unsigned)(NN-1)*256u;
    const unsigned deg = (unsigned)(re - rs);
    const int qb = rs & ~3;
    const int nq = (re - qb + 3) >> 2;

    int e0 = qb;
    int4  sqA  = *(const int4*)(src_s + e0);
    half8 ea0A = *(const half8*)(ea_s + (size_t)e0*4);
    half8 ea1A = *(const half8*)(ea_s + (size_t)e0*4 + 8);
    unsigned o0 = (unsigned)sqA.x, o1 = (unsigned)sqA.y,
             o2 = (unsigned)sqA.z, o3 = (unsigned)sqA.w;
    half2v vA0 = *(const half2v*)(UVv + (o0 < OMAX ? o0 : OMAX));
    half2v vA1 = *(const half2v*)(UVv + (o1 < OMAX ? o1 : OMAX));
    half2v vA2 = *(const half2v*)(UVv + (o2 < OMAX ? o2 : OMAX));
    half2v vA3 = *(const half2v*)(UVv + (o3 < OMAX ? o3 : OMAX));

    for (int it = 1; it < nq; ++it){
      const int e1 = qb + it*4;
      // --- issue next quad's loads + gathers first ---
      int4  sqB  = *(const int4*)(src_s + e1);
      half8 ea0B = *(const half8*)(ea_s + (size_t)e1*4);
      half8 ea1B = *(const half8*)(ea_s + (size_t)e1*4 + 8);
      unsigned p0 = (unsigned)sqB.x, p1 = (unsigned)sqB.y,
               p2 = (unsigned)sqB.z, p3 = (unsigned)sqB.w;
      half2v vB0 = *(const half2v*)(UVv + (p0 < OMAX ? p0 : OMAX));
      half2v vB1 = *(const half2v*)(UVv + (p1 < OMAX ? p1 : OMAX));
      half2v vB2 = *(const half2v*)(UVv + (p2 < OMAX ? p2 : OMAX));
      half2v vB3 = *(const half2v*)(UVv + (p3 < OMAX ? p3 : OMAX));
      // --- compute current quad from registers ---
      edge_term(a0, vA0, (float)ea0A[0], (float)ea0A[1], (float)ea0A[2],
                u, wc0, wc1, wc2, (unsigned)(e0+0-rs) < deg);
      edge_term(a1, vA1, (float)ea0A[4], (float)ea0A[5], (float)ea0A[6],
                u, wc0, wc1, wc2, (unsigned)(e0+1-rs) < deg);
      edge_term(a2, vA2, (float)ea1A[0], (float)ea1A[1], (float)ea1A[2],
                u, wc0, wc1, wc2, (unsigned)(e0+2-rs) < deg);
      edge_term(a3, vA3, (float)ea1A[4], (float)ea1A[5], (float)ea1A[6],
                u, wc0, wc1, wc2, (unsigned)(e0+3-rs) < deg);
      // --- rotate ---
      sqA = sqB; ea0A = ea0B; ea1A = ea1B;
      vA0 = vB0; vA1 = vB1; vA2 = vB2; vA3 = vB3;
      e0 = e1;
    }
    // epilogue: last quad
    edge_term(a0, vA0, (float)ea0A[0], (float)ea0A[1], (float)ea0A[2],
              u, wc0, wc1, wc2, (unsigned)(e0+0-rs) < deg);
    edge_term(a1, vA1, (float)ea0A[4], (float)ea0A[5], (float)ea0A[6],
              u, wc0, wc1, wc2, (unsigned)(e0+1-rs) < deg);
    edge_term(a2, vA2, (float)ea1A[0], (float)ea1A[1], (float)ea1A[2],
              u, wc0, wc1, wc2, (unsigned)(e0+2-rs) < deg);
    edge_term(a3, vA3, (float)ea1A[4], (float)ea1A[5], (float)ea1A[6],
              u, wc0, wc1, wc2, (unsigned)(e0+3-rs) < deg);
  }
  float2v a = (a0 + a1) + (a2 + a3);
  const float iv = invd[n];
  half2v outv; outv[0] = (_Float16)(a[0]*iv); outv[1] = (_Float16)(a[1]*iv);
  *(half2v*)(S + (size_t)n*HD + c0) = outv;
}

// ---------------- node_proj (1250 blocks): h += S·W2 + gate·b2 ; hh ; fused proj(l+1) ----------------
__global__ __launch_bounds__(256) void node_proj_kernel(
    const _Float16* __restrict__ S, const _Float16* __restrict__ w2p,
    const float* __restrict__ b2, const float* __restrict__ invd,
    float* __restrict__ h, _Float16* __restrict__ hh,
    const _Float16* __restrict__ w1pn, const float* __restrict__ b1n,
    _Float16* __restrict__ UV, int do_proj)
{
  __shared__ _Float16 hl[16][136];
  const int tid = threadIdx.x;
  const int wv  = tid >> 6;
  const int ln  = tid & 63;
  const int q   = ln >> 4;
  const int m   = ln & 15;
  const int n0  = blockIdx.x*16;      // grid = NN/16 = 1250 exact

  floatx4 acc[2];
  acc[0] = (floatx4){0.f,0.f,0.f,0.f};
  acc[1] = (floatx4){0.f,0.f,0.f,0.f};
  #pragma unroll
  for (int ks=0; ks<4; ++ks){
    half8 a = *(const half8*)(S + (size_t)(n0+m)*HD + ks*32 + q*8);
    const _Float16* wb = w2p + (size_t)(ks*8*64 + ln)*8;
    #pragma unroll
    for (int j=0;j<2;++j){
      half8 b = *(const half8*)(wb + (size_t)(wv*2+j)*512);
      acc[j] = __builtin_amdgcn_mfma_f32_16x16x32_f16(a, b, acc[j], 0,0,0);
    }
  }
  float gate[4];
  #pragma unroll
  for (int r=0;r<4;++r) gate[r] = (invd[n0 + q*4 + r] > 0.f) ? 1.f : 0.f;
  #pragma unroll
  for (int j=0; j<2; ++j){
    const int c = (wv*2+j)*16 + m;
    const float bv = b2[c];
    #pragma unroll
    for (int r=0;r<4;++r){
      size_t off = (size_t)(n0+q*4+r)*HD + c;
      float hv = h[off] + acc[j][r] + gate[r]*bv;
      h[off] = hv;
      hh[off] = (_Float16)hv;
      hl[q*4+r][c] = (_Float16)hv;
    }
  }
  __syncthreads();
  if (do_proj){
    floatx4 acc2[4];
    #pragma unroll
    for (int j=0;j<4;++j) acc2[j] = (floatx4){0.f,0.f,0.f,0.f};
    #pragma unroll
    for (int ks=0; ks<4; ++ks){
      half8 a = *(const half8*)&hl[m][ks*32 + q*8];
      const _Float16* wb = w1pn + (size_t)(ks*16*64 + ln)*8;
      #pragma unroll
      for (int j=0; j<4; ++j){
        half8 b = *(const half8*)(wb + (size_t)(wv*4+j)*512);
        acc2[j] = __builtin_amdgcn_mfma_f32_16x16x32_f16(a, b, acc2[j], 0,0,0);
      }
    }
    #pragma unroll
    for (int j=0; j<4; ++j){
      const int c = (wv*4+j)*16 + m;
      const float bias = (c < 128) ? b1n[c] : 0.f;
      #pragma unroll
      for (int r=0;r<4;++r)
        UV[(size_t)(n0+q*4+r)*256 + c] = (_Float16)(acc2[j][r] + bias);
    }
  }
}

// ---------------- decoder (1250 blocks): hh -> out(N,9) ----------------
__global__ __launch_bounds__(256) void decoder_kernel(
    const _Float16* __restrict__ hh,
    const _Float16* __restrict__ w1dp, const float* __restrict__ db1,
    const _Float16* __restrict__ w2dp, const float* __restrict__ db2,
    const float* __restrict__ dw3, const float* __restrict__ db3,
    float* __restrict__ out)
{
  __shared__ _Float16 d1[16][136];
  __shared__ float s2m[16][66];
  const int tid = threadIdx.x;
  const int wv  = tid >> 6;
  const int ln  = tid & 63;
  const int q   = ln >> 4;
  const int m   = ln & 15;
  const int n0  = blockIdx.x*16;      // grid = NN/16 = 1250 exact

  // stage 1: 8 cb over 4 waves -> 2 each
  floatx4 acc1[2];
  acc1[0] = (floatx4){0.f,0.f,0.f,0.f};
  acc1[1] = (floatx4){0.f,0.f,0.f,0.f};
  #pragma unroll
  for (int ks=0; ks<4; ++ks){
    half8 a = *(const half8*)(hh + (size_t)(n0+m)*HD + ks*32 + q*8);
    const _Float16* wb = w1dp + (size_t)(ks*8*64 + ln)*8;
    #pragma unroll
    for (int j=0; j<2; ++j){
      half8 b = *(const half8*)(wb + (size_t)(wv*2+j)*512);
      acc1[j] = __builtin_amdgcn_mfma_f32_16x16x32_f16(a, b, acc1[j], 0,0,0);
    }
  }
  #pragma unroll
  for (int j=0; j<2; ++j){
    const int c = (wv*2+j)*16 + m;
    const float bv = db1[c];
    #pragma unroll
    for (int r=0;r<4;++r)
      d1[q*4+r][c] = (_Float16)silu_f(acc1[j][r] + bv);
  }
  __syncthreads();

  // stage 2: 4 cb over 4 waves -> 1 each
  floatx4 acc2 = (floatx4){0.f,0.f,0.f,0.f};
  #pragma unroll
  for (int ks=0; ks<4; ++ks){
    half8 a = *(const half8*)&d1[m][ks*32 + q*8];
    const _Float16* wb = w2dp + (size_t)(ks*4*64 + ln)*8;
    half8 b = *(const half8*)(wb + (size_t)wv*512);
    acc2 = __builtin_amdgcn_mfma_f32_16x16x32_f16(a, b, acc2, 0,0,0);
  }
  {
    const int c = wv*16 + m;
    const float bv = db2[c];
    #pragma unroll
    for (int r=0;r<4;++r)
      s2m[q*4+r][c] = silu_f(acc2[r] + bv);
  }
  __syncthreads();

  // stage 3: 144 outputs over 256 threads
  if (tid < 144){
    int i = tid/9, oo = tid%9;
    float a = db3[oo];
    #pragma unroll 8
    for (int k=0;k<64;++k) a += s2m[i][k]*dw3[k*9+oo];
    out[(size_t)(n0+i)*9 + oo] = a;
  }
}

// ---------------- workspace layout (35,439,168 B) ----------------
constexpr size_t OFF_H    = 0;                         // 10,240,000
constexpr size_t OFF_HH   = 10240000;                  //  5,120,000
constexpr size_t OFF_UV   = 15360000;                  // 10,240,000
constexpr size_t OFF_S    = 25600000;                  //  5,120,000 (fp16)
constexpr size_t OFF_INVD = 30720000;                  //     80,000
constexpr size_t OFF_RS   = 30800000;                  //     80,064
constexpr size_t OFF_CUR  = 30880064;                  //     80,000
constexpr size_t OFF_SRC  = 30960064;                  //  1,280,064 (incl 16B slack)
constexpr size_t OFF_EA   = 32240128;                  //  2,560,064 (incl 32B slack)
constexpr size_t OFF_W1P  = 34800192;                  //    393,216
constexpr size_t OFF_W2P  = 35193408;                  //    196,608
constexpr size_t OFF_DW1P = 35390016;                  //     32,768
constexpr size_t OFF_DW2P = 35422784;                  //     16,384
constexpr size_t WS_NEEDED= 35439168;

extern "C" void kernel_launch(void* const* d_in, const int* in_sizes, int n_in,
                              void* d_out, int out_size, void* d_ws, size_t ws_size,
                              hipStream_t stream)
{
  float* out = (float*)d_out;
  const int nout_blk = (out_size + 255)/256;

  static const int EXP_SIZES[17] = {280000,640000,960000,1792,128,16384,128,
                                    198912,768,98304,768,16384,128,8192,64,576,9};
  if (n_in != 17){
    sentinel_kernel<<<nout_blk, 256, 0, stream>>>(out, out_size, 2.0e7f + (float)n_in*1.0e3f);
    return;
  }
  for (int i = 0; i < 17; ++i){
    if (in_sizes[i] != EXP_SIZES[i]){
      int sz = in_sizes[i] < 99999 ? in_sizes[i] : 99999;
      sentinel_kernel<<<nout_blk, 256, 0, stream>>>(out, out_size,
          1.0e7f + (float)i*1.0e5f + (float)sz);
      return;
    }
  }
  if (ws_size < WS_NEEDED){
    sentinel_kernel<<<nout_blk, 256, 0, stream>>>(out, out_size, 1.0e6f);
    return;
  }

  const float* x       = (const float*)d_in[0];
  const int*   ei      = (const int*)  d_in[1];
  const float* eattr   = (const float*)d_in[2];
  const float* enc_w1  = (const float*)d_in[3];
  const float* enc_b1  = (const float*)d_in[4];
  const float* enc_w2  = (const float*)d_in[5];
  const float* enc_b2  = (const float*)d_in[6];
  const float* conv_w1 = (const float*)d_in[7];
  const float* conv_b1 = (const float*)d_in[8];
  const float* conv_w2 = (const float*)d_in[9];
  const float* conv_b2 = (const float*)d_in[10];
  const float* dec_w1  = (const float*)d_in[11];
  const float* dec_b1  = (const float*)d_in[12];
  const float* dec_w2  = (const float*)d_in[13];
  const float* dec_b2  = (const float*)d_in[14];
  const float* dec_w3  = (const float*)d_in[15];
  const float* dec_b3  = (const float*)d_in[16];

  char* ws = (char*)d_ws;
  float*    h     = (float*)   (ws + OFF_H);
  _Float16* hh    = (_Float16*)(ws + OFF_HH);
  _Float16* UV    = (_Float16*)(ws + OFF_UV);
  _Float16* S     = (_Float16*)(ws + OFF_S);
  float*    invd  = (float*)   (ws + OFF_INVD);
  int*      rstart= (int*)     (ws + OFF_RS);
  int*      cur   = (int*)     (ws + OFF_CUR);
  int*      src_s = (int*)     (ws + OFF_SRC);
  _Float16* ea_s  = (_Float16*)(ws + OFF_EA);
  _Float16* w1p   = (_Float16*)(ws + OFF_W1P);
  _Float16* w2p   = (_Float16*)(ws + OFF_W2P);
  _Float16* w1dp  = (_Float16*)(ws + OFF_DW1P);
  _Float16* w2dp  = (_Float16*)(ws + OFF_DW2P);

  hipMemsetAsync(cur, 0, (size_t)NN*sizeof(int), stream);

  pack_all_kernel<<<1248, 256, 0, stream>>>(conv_w1, conv_w2, dec_w1, dec_w2,
                                            w1p, w2p, w1dp, w2dp);
  count_kernel<<<EE/256, 256, 0, stream>>>(ei, cur);
  scan_kernel<<<1, 1024, 0, stream>>>(cur, rstart, invd);
  scatter_kernel<<<EE/256, 256, 0, stream>>>(ei, eattr, cur, src_s, ea_s);
  encoder_kernel<<<NN/16, 128, 0, stream>>>(x, enc_w1, enc_b1, enc_w2, enc_b2, h, hh);
  proj_kernel<<<NN/16, 256, 0, stream>>>(hh, w1p, conv_b1, UV);   // layer 0 proj
  for (int l=0; l<6; ++l){
    edge_agg_kernel<<<NN/4, 256, 0, stream>>>(UV, rstart, src_s, ea_s,
                                              conv_w1 + (size_t)l*33152 + 32768,
                                              invd, S);
    const int lp = (l < 5) ? l+1 : 0;   // dummy valid ptrs for last layer
    node_proj_kernel<<<NN/16, 256, 0, stream>>>(S, w2p + (size_t)l*16384,
                                                conv_b2 + (size_t)l*128, invd, h, hh,
                                                w1p + (size_t)lp*32768,
                                                conv_b1 + (size_t)lp*128,
                                                UV, (l < 5) ? 1 : 0);
  }
  decoder_kernel<<<NN/16, 256, 0, stream>>>(hh, w1dp, dec_b1, w2dp, dec_b2,
                                            dec_w3, dec_b3, out);
}

// Round 7
// 422.470 us; speedup vs baseline: 1.0382x; 1.0382x over previous
//
#include <hip/hip_runtime.h>
#include <hip/hip_bf16.h>

#define NN 20000
#define EE 320000
#define EEP 380000   // padded edge-slot capacity: EE + 3*NN
#define HD 128       // hidden

typedef _Float16 half8 __attribute__((ext_vector_type(8)));
typedef _Float16 half4 __attribute__((ext_vector_type(4)));
typedef _Float16 half2v __attribute__((ext_vector_type(2)));
typedef float floatx4 __attribute__((ext_vector_type(4)));
typedef float float2v __attribute__((ext_vector_type(2)));

// silu via HW rcp (1-ulp) instead of exact fp32 divide.
// For sentinel inputs (x = -3000): exp(3000)=inf -> rcp(inf)=0 -> result -0.0 EXACTLY.
__device__ __forceinline__ float silu_f(float x){
  float e = __expf(-x);
  return x * __builtin_amdgcn_rcpf(1.f + e);
}

__device__ __forceinline__ bool ei_is64(const int* __restrict__ ei){
  return (ei[1] | ei[3] | ei[5] | ei[7]) == 0;
}
__device__ __forceinline__ int ei_src(const int* __restrict__ ei, int e, bool is64){
  return is64 ? ei[2*(size_t)e] : ei[e];
}
__device__ __forceinline__ int ei_dst(const int* __restrict__ ei, int e, bool is64){
  return is64 ? ei[2*(size_t)EE + 2*(size_t)e] : ei[EE + e];
}

__global__ __launch_bounds__(256) void sentinel_kernel(float* __restrict__ out, int n, float val){
  int i = blockIdx.x*256 + threadIdx.x;
  if (i < n) out[i] = val;
}

// ---------------- merged weight packing (w1p | w2p | dec) ----------------
__global__ __launch_bounds__(256) void pack_all_kernel(const float* __restrict__ cw1,
                                                       const float* __restrict__ cw2,
                                                       const float* __restrict__ dw1,
                                                       const float* __restrict__ dw2,
                                                       _Float16* __restrict__ w1p,
                                                       _Float16* __restrict__ w2p,
                                                       _Float16* __restrict__ w1dp,
                                                       _Float16* __restrict__ w2dp){
  int idx = blockIdx.x*256 + threadIdx.x;   // 1248 blocks = 319488 exact
  if (idx < 196608){
    int j   = idx & 7;
    int ln  = (idx >> 3) & 63;
    int rest= idx >> 9;
    int cb  = rest & 15;
    int rest2 = rest >> 4;
    int ks  = rest2 & 3;
    int l   = rest2 >> 2;
    int k = ks*32 + (ln>>4)*8 + j;
    int c = cb*16 + (ln&15);
    float v = (c < 128) ? cw1[(size_t)l*33152 + (size_t)k*128 + c]
                        : cw1[(size_t)l*33152 + (size_t)(128+k)*128 + (c-128)];
    w1p[idx] = (_Float16)v;
  } else if (idx < 294912){
    int t = idx - 196608;
    int j   = t & 7;
    int ln  = (t >> 3) & 63;
    int rest= t >> 9;
    int cb  = rest & 7;
    int rest2 = rest >> 3;
    int ks  = rest2 & 3;
    int l   = rest2 >> 2;
    int k = ks*32 + (ln>>4)*8 + j;
    int c = cb*16 + (ln&15);
    w2p[t] = (_Float16)cw2[(size_t)l*16384 + (size_t)k*128 + c];
  } else {
    int t2 = idx - 294912;
    if (t2 < 16384){
      int j = t2 & 7, ln = (t2>>3)&63, cb = (t2>>9)&7, ks = t2>>12;
      int k = ks*32 + (ln>>4)*8 + j;
      int c = cb*16 + (ln&15);
      w1dp[t2] = (_Float16)dw1[(size_t)k*128 + c];
    } else {
      int t = t2 - 16384;
      int j = t & 7, ln = (t>>3)&63, cb = (t>>9)&3, ks = t>>11;
      int k = ks*32 + (ln>>4)*8 + j;
      int c = cb*16 + (ln&15);
      w2dp[t] = (_Float16)dw2[(size_t)k*64 + c];
    }
  }
}

// ---------------- CSR build ----------------
__global__ __launch_bounds__(256) void count_kernel(const int* __restrict__ ei, int* __restrict__ cnt){
  int e = blockIdx.x*256 + threadIdx.x;   // EE/256 exact
  bool is64 = ei_is64(ei);
  atomicAdd(&cnt[ei_dst(ei, e, is64)], 1);
}

// scan over PADDED degrees (ceil(deg/4)*4): row_start entries are quad-aligned.
// invd uses the TRUE degree.
__global__ __launch_bounds__(1024) void scan_kernel(int* __restrict__ cntcur,
                                                    int* __restrict__ row_start,
                                                    float* __restrict__ invd){
  __shared__ int part[1024];
  const int t = threadIdx.x;
  const int base = t*20;
  int loc[20];
  int truedeg[20];
  int sum = 0;
  #pragma unroll
  for (int i=0;i<20;++i){
    int n = base+i;
    int v = (n < NN) ? cntcur[n] : 0;
    truedeg[i] = v;
    loc[i] = sum; sum += (v+3)&~3;
  }
  part[t] = sum;
  __syncthreads();
  for (int off=1; off<1024; off<<=1){
    int v = (t >= off) ? part[t-off] : 0;
    __syncthreads();
    part[t] += v;
    __syncthreads();
  }
  int pre = (t > 0) ? part[t-1] : 0;
  #pragma unroll
  for (int i=0;i<20;++i){
    int n = base+i;
    if (n < NN){
      int rs = pre + loc[i];
      int deg = truedeg[i];
      row_start[n] = rs;
      invd[n] = (deg > 0) ? 1.f/(float)deg : 0.f;
      cntcur[n] = rs;
    }
  }
  if (t == 1023) row_start[NN] = part[1023];
}

// fill: pre-fill ALL padded slots with {sentinel src, ea=0}; scatter overwrites
// the real ones. Also writes the sentinel UV row (index NN) = -3000 so pad
// slots contribute exactly -0.0 through silu. Runs every launch (ws re-poisoned).
__global__ __launch_bounds__(256) void fill_kernel(int* __restrict__ src_s,
                                                   _Float16* __restrict__ ea_s,
                                                   _Float16* __restrict__ UV){
  int i = blockIdx.x*256 + threadIdx.x;
  if (i < EEP){
    src_s[i] = NN*512;            // sentinel row BYTE offset
    half4 z = {(_Float16)0.f,(_Float16)0.f,(_Float16)0.f,(_Float16)0.f};
    *(half4*)(ea_s + (size_t)i*4) = z;
  }
  if (blockIdx.x == 0 && threadIdx.x < 64){
    half4 s;
    s[0]=s[1]=s[2]=s[3]=(_Float16)(-3000.f);
    *(half4*)(UV + (size_t)NN*256 + threadIdx.x*4) = s;
  }
}

// scatter: src_s holds the UV-row BYTE offset (s*512); ea_s half4 per slot.
__global__ __launch_bounds__(256) void scatter_kernel(const int* __restrict__ ei,
                                                      const float* __restrict__ eattr,
                                                      int* __restrict__ cur,
                                                      int* __restrict__ src_s,
                                                      _Float16* __restrict__ ea_s){
  int e = blockIdx.x*256 + threadIdx.x;   // EE/256 exact
  bool is64 = ei_is64(ei);
  int s = ei_src(ei, e, is64);
  int d = ei_dst(ei, e, is64);
  int pos = atomicAdd(&cur[d], 1);
  src_s[pos] = s*512;
  half4 ea;
  ea[0] = (_Float16)eattr[(size_t)e*3+0];
  ea[1] = (_Float16)eattr[(size_t)e*3+1];
  ea[2] = (_Float16)eattr[(size_t)e*3+2];
  ea[3] = (_Float16)0.f;
  *(half4*)(ea_s + (size_t)pos*4) = ea;
}

// ---------------- encoder: x(N,14) -> h(N,128) fp32 + hh fp16 ----------------
__global__ __launch_bounds__(128) void encoder_kernel(
    const float* __restrict__ x, const float* __restrict__ w1, const float* __restrict__ b1,
    const float* __restrict__ w2, const float* __restrict__ b2,
    float* __restrict__ h, _Float16* __restrict__ hh)
{
  __shared__ float xs[16][14];
  __shared__ float s1[16][128];
  const int n0 = blockIdx.x*16;
  const int tid = threadIdx.x;
  for (int idx=tid; idx<224; idx+=128){
    int i = idx/14, k = idx%14;
    xs[i][k] = x[(size_t)(n0+i)*14 + k];
  }
  __syncthreads();
  const int o = tid;
  float acc[16];
  float bv = b1[o];
  #pragma unroll
  for (int i=0;i<16;++i) acc[i] = bv;
  for (int k=0;k<14;++k){
    float w = w1[k*128+o];
    #pragma unroll
    for (int i=0;i<16;++i) acc[i] += xs[i][k]*w;
  }
  #pragma unroll
  for (int i=0;i<16;++i) s1[i][o] = silu_f(acc[i]);
  __syncthreads();
  float bv2 = b2[o];
  #pragma unroll
  for (int i=0;i<16;++i) acc[i] = bv2;
  for (int k=0;k<128;k+=4){
    float w0=w2[(k+0)*128+o], w1v=w2[(k+1)*128+o], w2v=w2[(k+2)*128+o], w3v=w2[(k+3)*128+o];
    #pragma unroll
    for (int i=0;i<16;++i){
      float4 sv = *(const float4*)&s1[i][k];
      acc[i] += sv.x*w0 + sv.y*w1v + sv.z*w2v + sv.w*w3v;
    }
  }
  #pragma unroll
  for (int i=0;i<16;++i){
    size_t off = (size_t)(n0+i)*HD + o;
    h[off] = acc[i];
    hh[off] = (_Float16)acc[i];
  }
}

// ---------------- proj (1250 blocks, 4 cb/wave): UV = [hh·W1d + b1 | hh·W1s] ----------------
__global__ __launch_bounds__(256) void proj_kernel(
    const _Float16* __restrict__ hh, const _Float16* __restrict__ w1p,
    const float* __restrict__ b1, _Float16* __restrict__ UV)
{
  const int tid = threadIdx.x;
  const int wv  = tid >> 6;
  const int ln  = tid & 63;
  const int q   = ln >> 4;
  const int m   = ln & 15;
  const int n0  = blockIdx.x*16;      // grid = NN/16 = 1250 exact

  floatx4 acc[4];
  #pragma unroll
  for (int j=0;j<4;++j) acc[j] = (floatx4){0.f,0.f,0.f,0.f};

  #pragma unroll
  for (int ks=0; ks<4; ++ks){
    half8 a = *(const half8*)(hh + (size_t)(n0+m)*HD + ks*32 + q*8);
    const _Float16* wb = w1p + (size_t)(ks*16*64 + ln)*8;
    #pragma unroll
    for (int j=0; j<4; ++j){
      half8 b = *(const half8*)(wb + (size_t)(wv*4+j)*512);
      acc[j] = __builtin_amdgcn_mfma_f32_16x16x32_f16(a, b, acc[j], 0,0,0);
    }
  }
  #pragma unroll
  for (int j=0; j<4; ++j){
    const int c = (wv*4+j)*16 + m;
    const float bias = (c < 128) ? b1[c] : 0.f;
    #pragma unroll
    for (int r=0;r<4;++r)
      UV[(size_t)(n0+q*4+r)*256 + c] = (_Float16)(acc[j][r] + bias);
  }
}

// ---------------- edge_agg: per-node mean of silu(U+V[src]+ea·We) ----------------
// r6: pair-slot half-wave gathers on a padded CSR. Lanes 0-31 process edge A,
// lanes 32-63 edge B of each pair, 4 channels/lane (8B dwordx2 gathers). Every
// VALU/trans instruction serves TWO edges; VMEM instrs per quad 8 -> 5
// (1 scalar src quad + 2 gathers + 2 ea). Pads hit the -3000 sentinel row ->
// silu contributes exactly -0.0 (no masks, no remainder). One shfl_xor(32)
// per node combines lane halves.
__global__ __launch_bounds__(256, 8) void edge_agg_kernel(
    const _Float16* __restrict__ UV, const int* __restrict__ row_start,
    const int* __restrict__ src_s, const _Float16* __restrict__ ea_s,
    const float* __restrict__ w1e, const float* __restrict__ invd,
    _Float16* __restrict__ S)
{
  const int tid = threadIdx.x;
  const int wv  = __builtin_amdgcn_readfirstlane(tid >> 6);
  const int ln  = tid & 63;
  const int hf  = ln >> 5;            // 0: edge A, 1: edge B of each pair
  const int li  = ln & 31;
  const int n   = blockIdx.x*4 + wv;  // grid NN/4 = 5000 exact
  const int c4  = li*4;               // 4 channels per lane

  const floatx4 wc0 = *(const floatx4*)(w1e +   0 + c4);
  const floatx4 wc1 = *(const floatx4*)(w1e + 128 + c4);
  const floatx4 wc2 = *(const floatx4*)(w1e + 256 + c4);

  half4 u_h = *(const half4*)(UV + (size_t)n*256 + c4);
  floatx4 u4;
  u4[0]=(float)u_h[0]; u4[1]=(float)u_h[1]; u4[2]=(float)u_h[2]; u4[3]=(float)u_h[3];

  const int rs = row_start[n], re = row_start[n+1];   // quad-aligned
  floatx4 acc = {0.f,0.f,0.f,0.f};
  // V-half byte base for this lane (row byte offset added per gather)
  const char* __restrict__ UVvb = (const char*)UV + 256 + (size_t)c4*2;
  const char* __restrict__ eab  = (const char*)ea_s + (size_t)hf*8;

  for (int e = rs; e < re; e += 4){
    const int4 sq = *(const int4*)(src_s + e);        // wave-uniform -> s_load
    const int oA = hf ? sq.y : sq.x;
    const int oB = hf ? sq.w : sq.z;
    half4 vA = *(const half4*)(UVvb + oA);
    half4 vB = *(const half4*)(UVvb + oB);
    half4 eA = *(const half4*)(eab + (size_t)e*8);
    half4 eB = *(const half4*)(eab + (size_t)e*8 + 16);
    {
      floatx4 p = u4;
      p += (float)eA[0] * wc0;
      p += (float)eA[1] * wc1;
      p += (float)eA[2] * wc2;
      p[0] += (float)vA[0]; p[1] += (float)vA[1];
      p[2] += (float)vA[2]; p[3] += (float)vA[3];
      acc[0] += silu_f(p[0]); acc[1] += silu_f(p[1]);
      acc[2] += silu_f(p[2]); acc[3] += silu_f(p[3]);
    }
    {
      floatx4 p = u4;
      p += (float)eB[0] * wc0;
      p += (float)eB[1] * wc1;
      p += (float)eB[2] * wc2;
      p[0] += (float)vB[0]; p[1] += (float)vB[1];
      p[2] += (float)vB[2]; p[3] += (float)vB[3];
      acc[0] += silu_f(p[0]); acc[1] += silu_f(p[1]);
      acc[2] += silu_f(p[2]); acc[3] += silu_f(p[3]);
    }
  }
  // combine lane halves (edge-A sums + edge-B sums, same channels)
  acc[0] += __shfl_xor(acc[0], 32);
  acc[1] += __shfl_xor(acc[1], 32);
  acc[2] += __shfl_xor(acc[2], 32);
  acc[3] += __shfl_xor(acc[3], 32);
  const float iv = invd[n];
  if (hf == 0){
    half4 outv;
    outv[0] = (_Float16)(acc[0]*iv);
    outv[1] = (_Float16)(acc[1]*iv);
    outv[2] = (_Float16)(acc[2]*iv);
    outv[3] = (_Float16)(acc[3]*iv);
    *(half4*)(S + (size_t)n*HD + c4) = outv;
  }
}

// ---------------- node_proj (1250 blocks): h += S·W2 + gate·b2 ; hh ; fused proj(l+1) ----------------
__global__ __launch_bounds__(256) void node_proj_kernel(
    const _Float16* __restrict__ S, const _Float16* __restrict__ w2p,
    const float* __restrict__ b2, const float* __restrict__ invd,
    float* __restrict__ h, _Float16* __restrict__ hh,
    const _Float16* __restrict__ w1pn, const float* __restrict__ b1n,
    _Float16* __restrict__ UV, int do_proj)
{
  __shared__ _Float16 hl[16][136];
  const int tid = threadIdx.x;
  const int wv  = tid >> 6;
  const int ln  = tid & 63;
  const int q   = ln >> 4;
  const int m   = ln & 15;
  const int n0  = blockIdx.x*16;      // grid = NN/16 = 1250 exact

  floatx4 acc[2];
  acc[0] = (floatx4){0.f,0.f,0.f,0.f};
  acc[1] = (floatx4){0.f,0.f,0.f,0.f};
  #pragma unroll
  for (int ks=0; ks<4; ++ks){
    half8 a = *(const half8*)(S + (size_t)(n0+m)*HD + ks*32 + q*8);
    const _Float16* wb = w2p + (size_t)(ks*8*64 + ln)*8;
    #pragma unroll
    for (int j=0;j<2;++j){
      half8 b = *(const half8*)(wb + (size_t)(wv*2+j)*512);
      acc[j] = __builtin_amdgcn_mfma_f32_16x16x32_f16(a, b, acc[j], 0,0,0);
    }
  }
  float gate[4];
  #pragma unroll
  for (int r=0;r<4;++r) gate[r] = (invd[n0 + q*4 + r] > 0.f) ? 1.f : 0.f;
  #pragma unroll
  for (int j=0; j<2; ++j){
    const int c = (wv*2+j)*16 + m;
    const float bv = b2[c];
    #pragma unroll
    for (int r=0;r<4;++r){
      size_t off = (size_t)(n0+q*4+r)*HD + c;
      float hv = h[off] + acc[j][r] + gate[r]*bv;
      h[off] = hv;
      hh[off] = (_Float16)hv;
      hl[q*4+r][c] = (_Float16)hv;
    }
  }
  __syncthreads();
  if (do_proj){
    floatx4 acc2[4];
    #pragma unroll
    for (int j=0;j<4;++j) acc2[j] = (floatx4){0.f,0.f,0.f,0.f};
    #pragma unroll
    for (int ks=0; ks<4; ++ks){
      half8 a = *(const half8*)&hl[m][ks*32 + q*8];
      const _Float16* wb = w1pn + (size_t)(ks*16*64 + ln)*8;
      #pragma unroll
      for (int j=0; j<4; ++j){
        half8 b = *(const half8*)(wb + (size_t)(wv*4+j)*512);
        acc2[j] = __builtin_amdgcn_mfma_f32_16x16x32_f16(a, b, acc2[j], 0,0,0);
      }
    }
    #pragma unroll
    for (int j=0; j<4; ++j){
      const int c = (wv*4+j)*16 + m;
      const float bias = (c < 128) ? b1n[c] : 0.f;
      #pragma unroll
      for (int r=0;r<4;++r)
        UV[(size_t)(n0+q*4+r)*256 + c] = (_Float16)(acc2[j][r] + bias);
    }
  }
}

// ---------------- decoder (1250 blocks): hh -> out(N,9) ----------------
__global__ __launch_bounds__(256) void decoder_kernel(
    const _Float16* __restrict__ hh,
    const _Float16* __restrict__ w1dp, const float* __restrict__ db1,
    const _Float16* __restrict__ w2dp, const float* __restrict__ db2,
    const float* __restrict__ dw3, const float* __restrict__ db3,
    float* __restrict__ out)
{
  __shared__ _Float16 d1[16][136];
  __shared__ float s2m[16][66];
  const int tid = threadIdx.x;
  const int wv  = tid >> 6;
  const int ln  = tid & 63;
  const int q   = ln >> 4;
  const int m   = ln & 15;
  const int n0  = blockIdx.x*16;      // grid = NN/16 = 1250 exact

  // stage 1: 8 cb over 4 waves -> 2 each
  floatx4 acc1[2];
  acc1[0] = (floatx4){0.f,0.f,0.f,0.f};
  acc1[1] = (floatx4){0.f,0.f,0.f,0.f};
  #pragma unroll
  for (int ks=0; ks<4; ++ks){
    half8 a = *(const half8*)(hh + (size_t)(n0+m)*HD + ks*32 + q*8);
    const _Float16* wb = w1dp + (size_t)(ks*8*64 + ln)*8;
    #pragma unroll
    for (int j=0; j<2; ++j){
      half8 b = *(const half8*)(wb + (size_t)(wv*2+j)*512);
      acc1[j] = __builtin_amdgcn_mfma_f32_16x16x32_f16(a, b, acc1[j], 0,0,0);
    }
  }
  #pragma unroll
  for (int j=0; j<2; ++j){
    const int c = (wv*2+j)*16 + m;
    const float bv = db1[c];
    #pragma unroll
    for (int r=0;r<4;++r)
      d1[q*4+r][c] = (_Float16)silu_f(acc1[j][r] + bv);
  }
  __syncthreads();

  // stage 2: 4 cb over 4 waves -> 1 each
  floatx4 acc2 = (floatx4){0.f,0.f,0.f,0.f};
  #pragma unroll
  for (int ks=0; ks<4; ++ks){
    half8 a = *(const half8*)&d1[m][ks*32 + q*8];
    const _Float16* wb = w2dp + (size_t)(ks*4*64 + ln)*8;
    half8 b = *(const half8*)(wb + (size_t)wv*512);
    acc2 = __builtin_amdgcn_mfma_f32_16x16x32_f16(a, b, acc2, 0,0,0);
  }
  {
    const int c = wv*16 + m;
    const float bv = db2[c];
    #pragma unroll
    for (int r=0;r<4;++r)
      s2m[q*4+r][c] = silu_f(acc2[r] + bv);
  }
  __syncthreads();

  // stage 3: 144 outputs over 256 threads
  if (tid < 144){
    int i = tid/9, oo = tid%9;
    float a = db3[oo];
    #pragma unroll 8
    for (int k=0;k<64;++k) a += s2m[i][k]*dw3[k*9+oo];
    out[(size_t)(n0+i)*9 + oo] = a;
  }
}

// ---------------- workspace layout (36,159,552 B) ----------------
constexpr size_t OFF_H    = 0;                         // 10,240,000
constexpr size_t OFF_HH   = 10240000;                  //  5,120,000
constexpr size_t OFF_UV   = 15360000;                  // 10,240,512 (NN+1 rows: sentinel)
constexpr size_t OFF_S    = 25600512;                  //  5,120,000 (fp16)
constexpr size_t OFF_INVD = 30720512;                  //     80,000
constexpr size_t OFF_RS   = 30800512;                  //     80,064
constexpr size_t OFF_CUR  = 30880576;                  //     80,000
constexpr size_t OFF_SRC  = 30960576;                  //  1,520,000 (EEP ints)
constexpr size_t OFF_EA   = 32480576;                  //  3,040,000 (EEP half4)
constexpr size_t OFF_W1P  = 35520576;                  //    393,216
constexpr size_t OFF_W2P  = 35913792;                  //    196,608
constexpr size_t OFF_DW1P = 36110400;                  //     32,768
constexpr size_t OFF_DW2P = 36143168;                  //     16,384
constexpr size_t WS_NEEDED= 36159552;

extern "C" void kernel_launch(void* const* d_in, const int* in_sizes, int n_in,
                              void* d_out, int out_size, void* d_ws, size_t ws_size,
                              hipStream_t stream)
{
  float* out = (float*)d_out;
  const int nout_blk = (out_size + 255)/256;

  static const int EXP_SIZES[17] = {280000,640000,960000,1792,128,16384,128,
                                    198912,768,98304,768,16384,128,8192,64,576,9};
  if (n_in != 17){
    sentinel_kernel<<<nout_blk, 256, 0, stream>>>(out, out_size, 2.0e7f + (float)n_in*1.0e3f);
    return;
  }
  for (int i = 0; i < 17; ++i){
    if (in_sizes[i] != EXP_SIZES[i]){
      int sz = in_sizes[i] < 99999 ? in_sizes[i] : 99999;
      sentinel_kernel<<<nout_blk, 256, 0, stream>>>(out, out_size,
          1.0e7f + (float)i*1.0e5f + (float)sz);
      return;
    }
  }
  if (ws_size < WS_NEEDED){
    sentinel_kernel<<<nout_blk, 256, 0, stream>>>(out, out_size, 1.0e6f);
    return;
  }

  const float* x       = (const float*)d_in[0];
  const int*   ei      = (const int*)  d_in[1];
  const float* eattr   = (const float*)d_in[2];
  const float* enc_w1  = (const float*)d_in[3];
  const float* enc_b1  = (const float*)d_in[4];
  const float* enc_w2  = (const float*)d_in[5];
  const float* enc_b2  = (const float*)d_in[6];
  const float* conv_w1 = (const float*)d_in[7];
  const float* conv_b1 = (const float*)d_in[8];
  const float* conv_w2 = (const float*)d_in[9];
  const float* conv_b2 = (const float*)d_in[10];
  const float* dec_w1  = (const float*)d_in[11];
  const float* dec_b1  = (const float*)d_in[12];
  const float* dec_w2  = (const float*)d_in[13];
  const float* dec_b2  = (const float*)d_in[14];
  const float* dec_w3  = (const float*)d_in[15];
  const float* dec_b3  = (const float*)d_in[16];

  char* ws = (char*)d_ws;
  float*    h     = (float*)   (ws + OFF_H);
  _Float16* hh    = (_Float16*)(ws + OFF_HH);
  _Float16* UV    = (_Float16*)(ws + OFF_UV);
  _Float16* S     = (_Float16*)(ws + OFF_S);
  float*    invd  = (float*)   (ws + OFF_INVD);
  int*      rstart= (int*)     (ws + OFF_RS);
  int*      cur   = (int*)     (ws + OFF_CUR);
  int*      src_s = (int*)     (ws + OFF_SRC);
  _Float16* ea_s  = (_Float16*)(ws + OFF_EA);
  _Float16* w1p   = (_Float16*)(ws + OFF_W1P);
  _Float16* w2p   = (_Float16*)(ws + OFF_W2P);
  _Float16* w1dp  = (_Float16*)(ws + OFF_DW1P);
  _Float16* w2dp  = (_Float16*)(ws + OFF_DW2P);

  hipMemsetAsync(cur, 0, (size_t)NN*sizeof(int), stream);

  pack_all_kernel<<<1248, 256, 0, stream>>>(conv_w1, conv_w2, dec_w1, dec_w2,
                                            w1p, w2p, w1dp, w2dp);
  fill_kernel<<<(EEP+255)/256, 256, 0, stream>>>(src_s, ea_s, UV);
  count_kernel<<<EE/256, 256, 0, stream>>>(ei, cur);
  scan_kernel<<<1, 1024, 0, stream>>>(cur, rstart, invd);
  scatter_kernel<<<EE/256, 256, 0, stream>>>(ei, eattr, cur, src_s, ea_s);
  encoder_kernel<<<NN/16, 128, 0, stream>>>(x, enc_w1, enc_b1, enc_w2, enc_b2, h, hh);
  proj_kernel<<<NN/16, 256, 0, stream>>>(hh, w1p, conv_b1, UV);   // layer 0 proj
  for (int l=0; l<6; ++l){
    edge_agg_kernel<<<NN/4, 256, 0, stream>>>(UV, rstart, src_s, ea_s,
                                              conv_w1 + (size_t)l*33152 + 32768,
                                              invd, S);
    const int lp = (l < 5) ? l+1 : 0;   // dummy valid ptrs for last layer
    node_proj_kernel<<<NN/16, 256, 0, stream>>>(S, w2p + (size_t)l*16384,
                                                conv_b2 + (size_t)l*128, invd, h, hh,
                                                w1p + (size_t)lp*32768,
                                                conv_b1 + (size_t)lp*128,
                                                UV, (l < 5) ? 1 : 0);
  }
  decoder_kernel<<<NN/16, 256, 0, stream>>>(hh, w1dp, dec_b1, w2dp, dec_b2,
                                            dec_w3, dec_b3, out);
}

// Round 8
// 418.983 us; speedup vs baseline: 1.0468x; 1.0083x over previous
//
#include <hip/hip_runtime.h>
#include <hip/hip_bf16.h>

#define NN 20000
#define EE 320000
#define EEP 380000   // padded edge-slot capacity: EE + 3*NN
#define HD 128       // hidden

typedef _Float16 half8 __attribute__((ext_vector_type(8)));
typedef _Float16 half4 __attribute__((ext_vector_type(4)));
typedef _Float16 half2v __attribute__((ext_vector_type(2)));
typedef float floatx4 __attribute__((ext_vector_type(4)));
typedef float float2v __attribute__((ext_vector_type(2)));

// silu via HW rcp (1-ulp) instead of exact fp32 divide.
// Sentinel inputs (p ~= -3000): exp(+3000)=inf -> rcp(inf)=0 -> contribution -0.0 EXACTLY.
__device__ __forceinline__ float silu_f(float x){
  float e = __expf(-x);
  return x * __builtin_amdgcn_rcpf(1.f + e);
}

__device__ __forceinline__ bool ei_is64(const int* __restrict__ ei){
  return (ei[1] | ei[3] | ei[5] | ei[7]) == 0;
}
__device__ __forceinline__ int ei_src(const int* __restrict__ ei, int e, bool is64){
  return is64 ? ei[2*(size_t)e] : ei[e];
}
__device__ __forceinline__ int ei_dst(const int* __restrict__ ei, int e, bool is64){
  return is64 ? ei[2*(size_t)EE + 2*(size_t)e] : ei[EE + e];
}

__global__ __launch_bounds__(256) void sentinel_kernel(float* __restrict__ out, int n, float val){
  int i = blockIdx.x*256 + threadIdx.x;
  if (i < n) out[i] = val;
}

// ---------------- merged weight packing (w1p | w2p | dec) ----------------
__global__ __launch_bounds__(256) void pack_all_kernel(const float* __restrict__ cw1,
                                                       const float* __restrict__ cw2,
                                                       const float* __restrict__ dw1,
                                                       const float* __restrict__ dw2,
                                                       _Float16* __restrict__ w1p,
                                                       _Float16* __restrict__ w2p,
                                                       _Float16* __restrict__ w1dp,
                                                       _Float16* __restrict__ w2dp){
  int idx = blockIdx.x*256 + threadIdx.x;   // 1248 blocks = 319488 exact
  if (idx < 196608){
    int j   = idx & 7;
    int ln  = (idx >> 3) & 63;
    int rest= idx >> 9;
    int cb  = rest & 15;
    int rest2 = rest >> 4;
    int ks  = rest2 & 3;
    int l   = rest2 >> 2;
    int k = ks*32 + (ln>>4)*8 + j;
    int c = cb*16 + (ln&15);
    float v = (c < 128) ? cw1[(size_t)l*33152 + (size_t)k*128 + c]
                        : cw1[(size_t)l*33152 + (size_t)(128+k)*128 + (c-128)];
    w1p[idx] = (_Float16)v;
  } else if (idx < 294912){
    int t = idx - 196608;
    int j   = t & 7;
    int ln  = (t >> 3) & 63;
    int rest= t >> 9;
    int cb  = rest & 7;
    int rest2 = rest >> 3;
    int ks  = rest2 & 3;
    int l   = rest2 >> 2;
    int k = ks*32 + (ln>>4)*8 + j;
    int c = cb*16 + (ln&15);
    w2p[t] = (_Float16)cw2[(size_t)l*16384 + (size_t)k*128 + c];
  } else {
    int t2 = idx - 294912;
    if (t2 < 16384){
      int j = t2 & 7, ln = (t2>>3)&63, cb = (t2>>9)&7, ks = t2>>12;
      int k = ks*32 + (ln>>4)*8 + j;
      int c = cb*16 + (ln&15);
      w1dp[t2] = (_Float16)dw1[(size_t)k*128 + c];
    } else {
      int t = t2 - 16384;
      int j = t & 7, ln = (t>>3)&63, cb = (t>>9)&3, ks = t>>11;
      int k = ks*32 + (ln>>4)*8 + j;
      int c = cb*16 + (ln&15);
      w2dp[t] = (_Float16)dw2[(size_t)k*64 + c];
    }
  }
}

// ---------------- CSR build ----------------
__global__ __launch_bounds__(256) void count_kernel(const int* __restrict__ ei, int* __restrict__ cnt){
  int e = blockIdx.x*256 + threadIdx.x;   // EE/256 exact
  bool is64 = ei_is64(ei);
  atomicAdd(&cnt[ei_dst(ei, e, is64)], 1);
}

// scan over PADDED degrees (ceil(deg/4)*4): row_start entries are quad-aligned.
// invd uses the TRUE degree.
__global__ __launch_bounds__(1024) void scan_kernel(int* __restrict__ cntcur,
                                                    int* __restrict__ row_start,
                                                    float* __restrict__ invd){
  __shared__ int part[1024];
  const int t = threadIdx.x;
  const int base = t*20;
  int loc[20];
  int truedeg[20];
  int sum = 0;
  #pragma unroll
  for (int i=0;i<20;++i){
    int n = base+i;
    int v = (n < NN) ? cntcur[n] : 0;
    truedeg[i] = v;
    loc[i] = sum; sum += (v+3)&~3;
  }
  part[t] = sum;
  __syncthreads();
  for (int off=1; off<1024; off<<=1){
    int v = (t >= off) ? part[t-off] : 0;
    __syncthreads();
    part[t] += v;
    __syncthreads();
  }
  int pre = (t > 0) ? part[t-1] : 0;
  #pragma unroll
  for (int i=0;i<20;++i){
    int n = base+i;
    if (n < NN){
      int rs = pre + loc[i];
      int deg = truedeg[i];
      row_start[n] = rs;
      invd[n] = (deg > 0) ? 1.f/(float)deg : 0.f;
      cntcur[n] = rs;
    }
  }
  if (t == 1023) row_start[NN] = part[1023];
}

// fill: pre-fill ALL padded slots with sentinel rec {0,0,0, NN*256}; scatter
// overwrites the real ones. Also writes sentinel UV row (index NN) = -3000 so
// pad slots contribute exactly -0.0 through silu. Runs every launch.
__global__ __launch_bounds__(256) void fill_kernel(int4* __restrict__ rec,
                                                   _Float16* __restrict__ UV){
  int i = blockIdx.x*256 + threadIdx.x;
  if (i < EEP){
    int4 r; r.x = 0; r.y = 0; r.z = 0; r.w = NN*256;   // ea=0.0f bits, sentinel row elem-offset
    rec[i] = r;
  }
  if (blockIdx.x == 0 && threadIdx.x < 64){
    half4 s;
    s[0]=s[1]=s[2]=s[3]=(_Float16)(-3000.f);
    *(half4*)(UV + (size_t)NN*256 + threadIdx.x*4) = s;
  }
}

// scatter (r4 format): one 16B rec per edge {ea0,ea1,ea2 fp32 bits, src*256}.
__global__ __launch_bounds__(256) void scatter_kernel(const int* __restrict__ ei,
                                                      const float* __restrict__ eattr,
                                                      int* __restrict__ cur,
                                                      int4* __restrict__ rec){
  int e = blockIdx.x*256 + threadIdx.x;   // EE/256 exact
  bool is64 = ei_is64(ei);
  int s = ei_src(ei, e, is64);
  int d = ei_dst(ei, e, is64);
  int pos = atomicAdd(&cur[d], 1);
  int4 r;
  r.x = __float_as_int(eattr[(size_t)e*3+0]);
  r.y = __float_as_int(eattr[(size_t)e*3+1]);
  r.z = __float_as_int(eattr[(size_t)e*3+2]);
  r.w = s*256;   // pre-scaled UV row element-offset
  rec[pos] = r;
}

// ---------------- encoder: x(N,14) -> h(N,128) fp32 + hh fp16 ----------------
__global__ __launch_bounds__(128) void encoder_kernel(
    const float* __restrict__ x, const float* __restrict__ w1, const float* __restrict__ b1,
    const float* __restrict__ w2, const float* __restrict__ b2,
    float* __restrict__ h, _Float16* __restrict__ hh)
{
  __shared__ float xs[16][14];
  __shared__ float s1[16][128];
  const int n0 = blockIdx.x*16;
  const int tid = threadIdx.x;
  for (int idx=tid; idx<224; idx+=128){
    int i = idx/14, k = idx%14;
    xs[i][k] = x[(size_t)(n0+i)*14 + k];
  }
  __syncthreads();
  const int o = tid;
  float acc[16];
  float bv = b1[o];
  #pragma unroll
  for (int i=0;i<16;++i) acc[i] = bv;
  for (int k=0;k<14;++k){
    float w = w1[k*128+o];
    #pragma unroll
    for (int i=0;i<16;++i) acc[i] += xs[i][k]*w;
  }
  #pragma unroll
  for (int i=0;i<16;++i) s1[i][o] = silu_f(acc[i]);
  __syncthreads();
  float bv2 = b2[o];
  #pragma unroll
  for (int i=0;i<16;++i) acc[i] = bv2;
  for (int k=0;k<128;k+=4){
    float w0=w2[(k+0)*128+o], w1v=w2[(k+1)*128+o], w2v=w2[(k+2)*128+o], w3v=w2[(k+3)*128+o];
    #pragma unroll
    for (int i=0;i<16;++i){
      float4 sv = *(const float4*)&s1[i][k];
      acc[i] += sv.x*w0 + sv.y*w1v + sv.z*w2v + sv.w*w3v;
    }
  }
  #pragma unroll
  for (int i=0;i<16;++i){
    size_t off = (size_t)(n0+i)*HD + o;
    h[off] = acc[i];
    hh[off] = (_Float16)acc[i];
  }
}

// ---------------- proj (1250 blocks, 4 cb/wave): UV = [hh·W1d + b1 | hh·W1s] ----------------
__global__ __launch_bounds__(256) void proj_kernel(
    const _Float16* __restrict__ hh, const _Float16* __restrict__ w1p,
    const float* __restrict__ b1, _Float16* __restrict__ UV)
{
  const int tid = threadIdx.x;
  const int wv  = tid >> 6;
  const int ln  = tid & 63;
  const int q   = ln >> 4;
  const int m   = ln & 15;
  const int n0  = blockIdx.x*16;      // grid = NN/16 = 1250 exact

  floatx4 acc[4];
  #pragma unroll
  for (int j=0;j<4;++j) acc[j] = (floatx4){0.f,0.f,0.f,0.f};

  #pragma unroll
  for (int ks=0; ks<4; ++ks){
    half8 a = *(const half8*)(hh + (size_t)(n0+m)*HD + ks*32 + q*8);
    const _Float16* wb = w1p + (size_t)(ks*16*64 + ln)*8;
    #pragma unroll
    for (int j=0; j<4; ++j){
      half8 b = *(const half8*)(wb + (size_t)(wv*4+j)*512);
      acc[j] = __builtin_amdgcn_mfma_f32_16x16x32_f16(a, b, acc[j], 0,0,0);
    }
  }
  #pragma unroll
  for (int j=0; j<4; ++j){
    const int c = (wv*4+j)*16 + m;
    const float bias = (c < 128) ? b1[c] : 0.f;
    #pragma unroll
    for (int r=0;r<4;++r)
      UV[(size_t)(n0+q*4+r)*256 + c] = (_Float16)(acc[j][r] + bias);
  }
}

// ---------------- edge_agg: per-node mean of silu(U+V[src]+ea·We) ----------------
// r8: TLP-doubling quad-parity split. Two waves per node (hf = quad parity),
// each walking HALF the padded quad list with r4's maskless inner loop
// (pads hit the -3000 sentinel row -> exact -0.0). Per-wave serial chain
// halves, wave count doubles (40000), and launch_bounds(256,8) pins VGPR<=64
// for 8 resident waves/SIMD. LDS combine (1KB) merges the pair's partials.
__device__ __forceinline__ float2v edge_contrib(int4 r, half2v v, float2v u,
                                                float2v wc0, float2v wc1, float2v wc2){
  float2v p = u;
  p += __int_as_float(r.x) * wc0;
  p += __int_as_float(r.y) * wc1;
  p += __int_as_float(r.z) * wc2;
  p[0] += (float)v[0];
  p[1] += (float)v[1];
  float2v s;
  s[0] = silu_f(p[0]);
  s[1] = silu_f(p[1]);
  return s;
}

__global__ __launch_bounds__(256, 8) void edge_agg_kernel(
    const _Float16* __restrict__ UV, const int* __restrict__ row_start,
    const int4* __restrict__ rec,
    const float* __restrict__ w1e, const float* __restrict__ invd,
    _Float16* __restrict__ S)
{
  __shared__ float sAcc[2][64][2];
  const int tid = threadIdx.x;
  const int wv  = __builtin_amdgcn_readfirstlane(tid >> 6);
  const int ln  = tid & 63;
  const int nl  = wv >> 1;            // node slot in block (0..1)
  const int hf  = wv & 1;             // quad parity handled by this wave
  const int n   = blockIdx.x*2 + nl;  // grid NN/2 = 10000 exact
  const int c0  = ln*2;

  const float2v wc0 = *(const float2v*)(w1e +   0 + c0);
  const float2v wc1 = *(const float2v*)(w1e + 128 + c0);
  const float2v wc2 = *(const float2v*)(w1e + 256 + c0);

  half2v uvp = *(const half2v*)(UV + (size_t)n*256 + c0);
  float2v u; u[0] = (float)uvp[0]; u[1] = (float)uvp[1];

  const int rs = row_start[n], re = row_start[n+1];   // quad-aligned (padded)
  const int nq = (re - rs) >> 2;
  float2v a0 = {0.f,0.f}, a1 = {0.f,0.f}, a2 = {0.f,0.f}, a3 = {0.f,0.f};

  for (int q = hf; q < nq; q += 2){
    const int e = rs + q*4;
    const int4 r0 = rec[e+0];
    const int4 r1 = rec[e+1];
    const int4 r2 = rec[e+2];
    const int4 r3 = rec[e+3];
    const half2v v0 = *(const half2v*)(UV + (size_t)r0.w + 128 + c0);
    const half2v v1 = *(const half2v*)(UV + (size_t)r1.w + 128 + c0);
    const half2v v2 = *(const half2v*)(UV + (size_t)r2.w + 128 + c0);
    const half2v v3 = *(const half2v*)(UV + (size_t)r3.w + 128 + c0);
    a0 += edge_contrib(r0, v0, u, wc0, wc1, wc2);
    a1 += edge_contrib(r1, v1, u, wc0, wc1, wc2);
    a2 += edge_contrib(r2, v2, u, wc0, wc1, wc2);
    a3 += edge_contrib(r3, v3, u, wc0, wc1, wc2);
  }
  float2v a = (a0 + a1) + (a2 + a3);

  if (hf == 1){
    sAcc[nl][ln][0] = a[0];
    sAcc[nl][ln][1] = a[1];
  }
  __syncthreads();
  if (hf == 0){
    a[0] += sAcc[nl][ln][0];
    a[1] += sAcc[nl][ln][1];
    const float iv = invd[n];
    half2v outv; outv[0] = (_Float16)(a[0]*iv); outv[1] = (_Float16)(a[1]*iv);
    *(half2v*)(S + (size_t)n*HD + c0) = outv;
  }
}

// ---------------- node_proj (1250 blocks): h += S·W2 + gate·b2 ; hh ; fused proj(l+1) ----------------
__global__ __launch_bounds__(256) void node_proj_kernel(
    const _Float16* __restrict__ S, const _Float16* __restrict__ w2p,
    const float* __restrict__ b2, const float* __restrict__ invd,
    float* __restrict__ h, _Float16* __restrict__ hh,
    const _Float16* __restrict__ w1pn, const float* __restrict__ b1n,
    _Float16* __restrict__ UV, int do_proj)
{
  __shared__ _Float16 hl[16][136];
  const int tid = threadIdx.x;
  const int wv  = tid >> 6;
  const int ln  = tid & 63;
  const int q   = ln >> 4;
  const int m   = ln & 15;
  const int n0  = blockIdx.x*16;      // grid = NN/16 = 1250 exact

  floatx4 acc[2];
  acc[0] = (floatx4){0.f,0.f,0.f,0.f};
  acc[1] = (floatx4){0.f,0.f,0.f,0.f};
  #pragma unroll
  for (int ks=0; ks<4; ++ks){
    half8 a = *(const half8*)(S + (size_t)(n0+m)*HD + ks*32 + q*8);
    const _Float16* wb = w2p + (size_t)(ks*8*64 + ln)*8;
    #pragma unroll
    for (int j=0;j<2;++j){
      half8 b = *(const half8*)(wb + (size_t)(wv*2+j)*512);
      acc[j] = __builtin_amdgcn_mfma_f32_16x16x32_f16(a, b, acc[j], 0,0,0);
    }
  }
  float gate[4];
  #pragma unroll
  for (int r=0;r<4;++r) gate[r] = (invd[n0 + q*4 + r] > 0.f) ? 1.f : 0.f;
  #pragma unroll
  for (int j=0; j<2; ++j){
    const int c = (wv*2+j)*16 + m;
    const float bv = b2[c];
    #pragma unroll
    for (int r=0;r<4;++r){
      size_t off = (size_t)(n0+q*4+r)*HD + c;
      float hv = h[off] + acc[j][r] + gate[r]*bv;
      h[off] = hv;
      hh[off] = (_Float16)hv;
      hl[q*4+r][c] = (_Float16)hv;
    }
  }
  __syncthreads();
  if (do_proj){
    floatx4 acc2[4];
    #pragma unroll
    for (int j=0;j<4;++j) acc2[j] = (floatx4){0.f,0.f,0.f,0.f};
    #pragma unroll
    for (int ks=0; ks<4; ++ks){
      half8 a = *(const half8*)&hl[m][ks*32 + q*8];
      const _Float16* wb = w1pn + (size_t)(ks*16*64 + ln)*8;
      #pragma unroll
      for (int j=0; j<4; ++j){
        half8 b = *(const half8*)(wb + (size_t)(wv*4+j)*512);
        acc2[j] = __builtin_amdgcn_mfma_f32_16x16x32_f16(a, b, acc2[j], 0,0,0);
      }
    }
    #pragma unroll
    for (int j=0; j<4; ++j){
      const int c = (wv*4+j)*16 + m;
      const float bias = (c < 128) ? b1n[c] : 0.f;
      #pragma unroll
      for (int r=0;r<4;++r)
        UV[(size_t)(n0+q*4+r)*256 + c] = (_Float16)(acc2[j][r] + bias);
    }
  }
}

// ---------------- decoder (1250 blocks): hh -> out(N,9) ----------------
__global__ __launch_bounds__(256) void decoder_kernel(
    const _Float16* __restrict__ hh,
    const _Float16* __restrict__ w1dp, const float* __restrict__ db1,
    const _Float16* __restrict__ w2dp, const float* __restrict__ db2,
    const float* __restrict__ dw3, const float* __restrict__ db3,
    float* __restrict__ out)
{
  __shared__ _Float16 d1[16][136];
  __shared__ float s2m[16][66];
  const int tid = threadIdx.x;
  const int wv  = tid >> 6;
  const int ln  = tid & 63;
  const int q   = ln >> 4;
  const int m   = ln & 15;
  const int n0  = blockIdx.x*16;      // grid = NN/16 = 1250 exact

  // stage 1: 8 cb over 4 waves -> 2 each
  floatx4 acc1[2];
  acc1[0] = (floatx4){0.f,0.f,0.f,0.f};
  acc1[1] = (floatx4){0.f,0.f,0.f,0.f};
  #pragma unroll
  for (int ks=0; ks<4; ++ks){
    half8 a = *(const half8*)(hh + (size_t)(n0+m)*HD + ks*32 + q*8);
    const _Float16* wb = w1dp + (size_t)(ks*8*64 + ln)*8;
    #pragma unroll
    for (int j=0; j<2; ++j){
      half8 b = *(const half8*)(wb + (size_t)(wv*2+j)*512);
      acc1[j] = __builtin_amdgcn_mfma_f32_16x16x32_f16(a, b, acc1[j], 0,0,0);
    }
  }
  #pragma unroll
  for (int j=0; j<2; ++j){
    const int c = (wv*2+j)*16 + m;
    const float bv = db1[c];
    #pragma unroll
    for (int r=0;r<4;++r)
      d1[q*4+r][c] = (_Float16)silu_f(acc1[j][r] + bv);
  }
  __syncthreads();

  // stage 2: 4 cb over 4 waves -> 1 each
  floatx4 acc2 = (floatx4){0.f,0.f,0.f,0.f};
  #pragma unroll
  for (int ks=0; ks<4; ++ks){
    half8 a = *(const half8*)&d1[m][ks*32 + q*8];
    const _Float16* wb = w2dp + (size_t)(ks*4*64 + ln)*8;
    half8 b = *(const half8*)(wb + (size_t)wv*512);
    acc2 = __builtin_amdgcn_mfma_f32_16x16x32_f16(a, b, acc2, 0,0,0);
  }
  {
    const int c = wv*16 + m;
    const float bv = db2[c];
    #pragma unroll
    for (int r=0;r<4;++r)
      s2m[q*4+r][c] = silu_f(acc2[r] + bv);
  }
  __syncthreads();

  // stage 3: 144 outputs over 256 threads
  if (tid < 144){
    int i = tid/9, oo = tid%9;
    float a = db3[oo];
    #pragma unroll 8
    for (int k=0;k<64;++k) a += s2m[i][k]*dw3[k*9+oo];
    out[(size_t)(n0+i)*9 + oo] = a;
  }
}

// ---------------- workspace layout (37,679,552 B) ----------------
constexpr size_t OFF_H    = 0;                         // 10,240,000
constexpr size_t OFF_HH   = 10240000;                  //  5,120,000
constexpr size_t OFF_UV   = 15360000;                  // 10,240,512 (NN+1 rows: sentinel)
constexpr size_t OFF_S    = 25600512;                  //  5,120,000 (fp16)
constexpr size_t OFF_INVD = 30720512;                  //     80,000
constexpr size_t OFF_RS   = 30800512;                  //     80,064
constexpr size_t OFF_CUR  = 30880576;                  //     80,000
constexpr size_t OFF_REC  = 30960576;                  //  6,080,000 (EEP int4)
constexpr size_t OFF_W1P  = 37040576;                  //    393,216
constexpr size_t OFF_W2P  = 37433792;                  //    196,608
constexpr size_t OFF_DW1P = 37630400;                  //     32,768
constexpr size_t OFF_DW2P = 37663168;                  //     16,384
constexpr size_t WS_NEEDED= 37679552;

extern "C" void kernel_launch(void* const* d_in, const int* in_sizes, int n_in,
                              void* d_out, int out_size, void* d_ws, size_t ws_size,
                              hipStream_t stream)
{
  float* out = (float*)d_out;
  const int nout_blk = (out_size + 255)/256;

  static const int EXP_SIZES[17] = {280000,640000,960000,1792,128,16384,128,
                                    198912,768,98304,768,16384,128,8192,64,576,9};
  if (n_in != 17){
    sentinel_kernel<<<nout_blk, 256, 0, stream>>>(out, out_size, 2.0e7f + (float)n_in*1.0e3f);
    return;
  }
  for (int i = 0; i < 17; ++i){
    if (in_sizes[i] != EXP_SIZES[i]){
      int sz = in_sizes[i] < 99999 ? in_sizes[i] : 99999;
      sentinel_kernel<<<nout_blk, 256, 0, stream>>>(out, out_size,
          1.0e7f + (float)i*1.0e5f + (float)sz);
      return;
    }
  }
  if (ws_size < WS_NEEDED){
    sentinel_kernel<<<nout_blk, 256, 0, stream>>>(out, out_size, 1.0e6f);
    return;
  }

  const float* x       = (const float*)d_in[0];
  const int*   ei      = (const int*)  d_in[1];
  const float* eattr   = (const float*)d_in[2];
  const float* enc_w1  = (const float*)d_in[3];
  const float* enc_b1  = (const float*)d_in[4];
  const float* enc_w2  = (const float*)d_in[5];
  const float* enc_b2  = (const float*)d_in[6];
  const float* conv_w1 = (const float*)d_in[7];
  const float* conv_b1 = (const float*)d_in[8];
  const float* conv_w2 = (const float*)d_in[9];
  const float* conv_b2 = (const float*)d_in[10];
  const float* dec_w1  = (const float*)d_in[11];
  const float* dec_b1  = (const float*)d_in[12];
  const float* dec_w2  = (const float*)d_in[13];
  const float* dec_b2  = (const float*)d_in[14];
  const float* dec_w3  = (const float*)d_in[15];
  const float* dec_b3  = (const float*)d_in[16];

  char* ws = (char*)d_ws;
  float*    h     = (float*)   (ws + OFF_H);
  _Float16* hh    = (_Float16*)(ws + OFF_HH);
  _Float16* UV    = (_Float16*)(ws + OFF_UV);
  _Float16* S     = (_Float16*)(ws + OFF_S);
  float*    invd  = (float*)   (ws + OFF_INVD);
  int*      rstart= (int*)     (ws + OFF_RS);
  int*      cur   = (int*)     (ws + OFF_CUR);
  int4*     rec   = (int4*)    (ws + OFF_REC);
  _Float16* w1p   = (_Float16*)(ws + OFF_W1P);
  _Float16* w2p   = (_Float16*)(ws + OFF_W2P);
  _Float16* w1dp  = (_Float16*)(ws + OFF_DW1P);
  _Float16* w2dp  = (_Float16*)(ws + OFF_DW2P);

  hipMemsetAsync(cur, 0, (size_t)NN*sizeof(int), stream);

  pack_all_kernel<<<1248, 256, 0, stream>>>(conv_w1, conv_w2, dec_w1, dec_w2,
                                            w1p, w2p, w1dp, w2dp);
  fill_kernel<<<(EEP+255)/256, 256, 0, stream>>>(rec, UV);
  count_kernel<<<EE/256, 256, 0, stream>>>(ei, cur);
  scan_kernel<<<1, 1024, 0, stream>>>(cur, rstart, invd);
  scatter_kernel<<<EE/256, 256, 0, stream>>>(ei, eattr, cur, rec);
  encoder_kernel<<<NN/16, 128, 0, stream>>>(x, enc_w1, enc_b1, enc_w2, enc_b2, h, hh);
  proj_kernel<<<NN/16, 256, 0, stream>>>(hh, w1p, conv_b1, UV);   // layer 0 proj
  for (int l=0; l<6; ++l){
    edge_agg_kernel<<<NN/2, 256, 0, stream>>>(UV, rstart, rec,
                                              conv_w1 + (size_t)l*33152 + 32768,
                                              invd, S);
    const int lp = (l < 5) ? l+1 : 0;   // dummy valid ptrs for last layer
    node_proj_kernel<<<NN/16, 256, 0, stream>>>(S, w2p + (size_t)l*16384,
                                                conv_b2 + (size_t)l*128, invd, h, hh,
                                                w1p + (size_t)lp*32768,
                                                conv_b1 + (size_t)lp*128,
                                                UV, (l < 5) ? 1 : 0);
  }
  decoder_kernel<<<NN/16, 256, 0, stream>>>(hh, w1dp, dec_b1, w2dp, dec_b2,
                                            dec_w3, dec_b3, out);
}

// Round 9
// 409.186 us; speedup vs baseline: 1.0719x; 1.0239x over previous
//
#include <hip/hip_runtime.h>
#include <hip/hip_bf16.h>

#define NN 20000
#define EE 320000
#define HD 128   // hidden

typedef _Float16 half8 __attribute__((ext_vector_type(8)));
typedef _Float16 half4 __attribute__((ext_vector_type(4)));
typedef _Float16 half2v __attribute__((ext_vector_type(2)));
typedef float floatx4 __attribute__((ext_vector_type(4)));
typedef float float2v __attribute__((ext_vector_type(2)));

// silu via HW rcp (1-ulp) instead of exact fp32 divide.
__device__ __forceinline__ float silu_f(float x){
  float e = __expf(-x);
  return x * __builtin_amdgcn_rcpf(1.f + e);
}

__device__ __forceinline__ bool ei_is64(const int* __restrict__ ei){
  return (ei[1] | ei[3] | ei[5] | ei[7]) == 0;
}
__device__ __forceinline__ int ei_src(const int* __restrict__ ei, int e, bool is64){
  return is64 ? ei[2*(size_t)e] : ei[e];
}
__device__ __forceinline__ int ei_dst(const int* __restrict__ ei, int e, bool is64){
  return is64 ? ei[2*(size_t)EE + 2*(size_t)e] : ei[EE + e];
}

__global__ __launch_bounds__(256) void sentinel_kernel(float* __restrict__ out, int n, float val){
  int i = blockIdx.x*256 + threadIdx.x;
  if (i < n) out[i] = val;
}

// ---------------- merged weight packing + cur zeroing ----------------
// r9: memset(cur) folded in as blocks past the pack range (independent work;
// count consumes cur in a LATER dispatch). 1327 blocks = 1248 pack + 79 zero.
__global__ __launch_bounds__(256) void pack_all_kernel(const float* __restrict__ cw1,
                                                       const float* __restrict__ cw2,
                                                       const float* __restrict__ dw1,
                                                       const float* __restrict__ dw2,
                                                       _Float16* __restrict__ w1p,
                                                       _Float16* __restrict__ w2p,
                                                       _Float16* __restrict__ w1dp,
                                                       _Float16* __restrict__ w2dp,
                                                       int* __restrict__ cur){
  int idx = blockIdx.x*256 + threadIdx.x;
  if (idx >= 319488){
    int j = idx - 319488;
    if (j < NN) cur[j] = 0;
    return;
  }
  if (idx < 196608){
    int j   = idx & 7;
    int ln  = (idx >> 3) & 63;
    int rest= idx >> 9;
    int cb  = rest & 15;
    int rest2 = rest >> 4;
    int ks  = rest2 & 3;
    int l   = rest2 >> 2;
    int k = ks*32 + (ln>>4)*8 + j;
    int c = cb*16 + (ln&15);
    float v = (c < 128) ? cw1[(size_t)l*33152 + (size_t)k*128 + c]
                        : cw1[(size_t)l*33152 + (size_t)(128+k)*128 + (c-128)];
    w1p[idx] = (_Float16)v;
  } else if (idx < 294912){
    int t = idx - 196608;
    int j   = t & 7;
    int ln  = (t >> 3) & 63;
    int rest= t >> 9;
    int cb  = rest & 7;
    int rest2 = rest >> 3;
    int ks  = rest2 & 3;
    int l   = rest2 >> 2;
    int k = ks*32 + (ln>>4)*8 + j;
    int c = cb*16 + (ln&15);
    w2p[t] = (_Float16)cw2[(size_t)l*16384 + (size_t)k*128 + c];
  } else {
    int t2 = idx - 294912;
    if (t2 < 16384){
      int j = t2 & 7, ln = (t2>>3)&63, cb = (t2>>9)&7, ks = t2>>12;
      int k = ks*32 + (ln>>4)*8 + j;
      int c = cb*16 + (ln&15);
      w1dp[t2] = (_Float16)dw1[(size_t)k*128 + c];
    } else {
      int t = t2 - 16384;
      int j = t & 7, ln = (t>>3)&63, cb = (t>>9)&3, ks = t>>11;
      int k = ks*32 + (ln>>4)*8 + j;
      int c = cb*16 + (ln&15);
      w2dp[t] = (_Float16)dw2[(size_t)k*64 + c];
    }
  }
}

// ---------------- CSR build (r4 exact) ----------------
__global__ __launch_bounds__(256) void count_kernel(const int* __restrict__ ei, int* __restrict__ cnt){
  int e = blockIdx.x*256 + threadIdx.x;   // EE/256 exact
  bool is64 = ei_is64(ei);
  atomicAdd(&cnt[ei_dst(ei, e, is64)], 1);
}

__global__ __launch_bounds__(1024) void scan_kernel(int* __restrict__ cntcur,
                                                    int* __restrict__ row_start,
                                                    float* __restrict__ invd){
  __shared__ int part[1024];
  const int t = threadIdx.x;
  const int base = t*20;
  int loc[20];
  int sum = 0;
  #pragma unroll
  for (int i=0;i<20;++i){
    int n = base+i;
    int v = (n < NN) ? cntcur[n] : 0;
    loc[i] = sum; sum += v;
  }
  part[t] = sum;
  __syncthreads();
  for (int off=1; off<1024; off<<=1){
    int v = (t >= off) ? part[t-off] : 0;
    __syncthreads();
    part[t] += v;
    __syncthreads();
  }
  int pre = (t > 0) ? part[t-1] : 0;
  #pragma unroll
  for (int i=0;i<20;++i){
    int n = base+i;
    if (n < NN){
      int rs = pre + loc[i];
      int deg = ((i<19)?loc[i+1]:sum) - loc[i];
      row_start[n] = rs;
      invd[n] = (deg > 0) ? 1.f/(float)deg : 0.f;
      cntcur[n] = rs;
    }
  }
  if (t == 1023) row_start[NN] = part[1023];
}

// scatter (r4 exact): one 16B rec per edge {ea0,ea1,ea2 fp32 bits, src*256}.
__global__ __launch_bounds__(256) void scatter_kernel(const int* __restrict__ ei,
                                                      const float* __restrict__ eattr,
                                                      int* __restrict__ cur,
                                                      int4* __restrict__ rec){
  int e = blockIdx.x*256 + threadIdx.x;   // EE/256 exact
  bool is64 = ei_is64(ei);
  int s = ei_src(ei, e, is64);
  int d = ei_dst(ei, e, is64);
  int pos = atomicAdd(&cur[d], 1);
  int4 r;
  r.x = __float_as_int(eattr[(size_t)e*3+0]);
  r.y = __float_as_int(eattr[(size_t)e*3+1]);
  r.z = __float_as_int(eattr[(size_t)e*3+2]);
  r.w = s*256;   // pre-scaled UV row element-offset
  rec[pos] = r;
}

// ---------------- encoder + fused layer-0 proj (r9) ----------------
// Block = 16 nodes, 128 threads. Encoder writes h/hh and stages hh in LDS;
// then the 2 waves run proj (8 col-blocks each) from LDS — proj's hh re-read
// (5MB) and one dispatch gap are gone. Consumers of UV are in later dispatches.
__global__ __launch_bounds__(128) void encoder_proj_kernel(
    const float* __restrict__ x, const float* __restrict__ w1, const float* __restrict__ b1,
    const float* __restrict__ w2, const float* __restrict__ b2,
    float* __restrict__ h, _Float16* __restrict__ hh,
    const _Float16* __restrict__ w1p, const float* __restrict__ cb1,
    _Float16* __restrict__ UV)
{
  __shared__ float xs[16][14];
  __shared__ float s1[16][128];
  __shared__ _Float16 hls[16][136];
  const int n0 = blockIdx.x*16;       // grid = NN/16 = 1250 exact
  const int tid = threadIdx.x;
  for (int idx=tid; idx<224; idx+=128){
    int i = idx/14, k = idx%14;
    xs[i][k] = x[(size_t)(n0+i)*14 + k];
  }
  __syncthreads();
  const int o = tid;
  float acc[16];
  float bv = b1[o];
  #pragma unroll
  for (int i=0;i<16;++i) acc[i] = bv;
  for (int k=0;k<14;++k){
    float w = w1[k*128+o];
    #pragma unroll
    for (int i=0;i<16;++i) acc[i] += xs[i][k]*w;
  }
  #pragma unroll
  for (int i=0;i<16;++i) s1[i][o] = silu_f(acc[i]);
  __syncthreads();
  float bv2 = b2[o];
  #pragma unroll
  for (int i=0;i<16;++i) acc[i] = bv2;
  for (int k=0;k<128;k+=4){
    float w0=w2[(k+0)*128+o], w1v=w2[(k+1)*128+o], w2v=w2[(k+2)*128+o], w3v=w2[(k+3)*128+o];
    #pragma unroll
    for (int i=0;i<16;++i){
      float4 sv = *(const float4*)&s1[i][k];
      acc[i] += sv.x*w0 + sv.y*w1v + sv.z*w2v + sv.w*w3v;
    }
  }
  #pragma unroll
  for (int i=0;i<16;++i){
    size_t off = (size_t)(n0+i)*HD + o;
    h[off] = acc[i];
    _Float16 hv = (_Float16)acc[i];
    hh[off] = hv;
    hls[i][o] = hv;
  }
  __syncthreads();

  // ---- fused proj: UV = [hh·W1d + b1 | hh·W1s], 2 waves x 8 cb ----
  const int wv = tid >> 6;            // 0..1
  const int ln = tid & 63;
  const int q  = ln >> 4;
  const int m  = ln & 15;
  floatx4 pacc[8];
  #pragma unroll
  for (int j=0;j<8;++j) pacc[j] = (floatx4){0.f,0.f,0.f,0.f};
  #pragma unroll
  for (int ks=0; ks<4; ++ks){
    half8 a = *(const half8*)&hls[m][ks*32 + q*8];
    const _Float16* wb = w1p + (size_t)(ks*16*64 + ln)*8;
    #pragma unroll
    for (int j=0; j<8; ++j){
      half8 b = *(const half8*)(wb + (size_t)(wv*8+j)*512);
      pacc[j] = __builtin_amdgcn_mfma_f32_16x16x32_f16(a, b, pacc[j], 0,0,0);
    }
  }
  #pragma unroll
  for (int j=0; j<8; ++j){
    const int c = (wv*8+j)*16 + m;
    const float bias = (c < 128) ? cb1[c] : 0.f;
    #pragma unroll
    for (int r=0;r<4;++r)
      UV[(size_t)(n0+q*4+r)*256 + c] = (_Float16)(pacc[j][r] + bias);
  }
}

// ---------------- edge_agg (r4 exact — best known, do not touch) ----------------
__device__ __forceinline__ float2v edge_contrib(int4 r, half2v v, float2v u,
                                                float2v wc0, float2v wc1, float2v wc2){
  float2v p = u;
  p += __int_as_float(r.x) * wc0;
  p += __int_as_float(r.y) * wc1;
  p += __int_as_float(r.z) * wc2;
  p[0] += (float)v[0];
  p[1] += (float)v[1];
  float2v s;
  s[0] = silu_f(p[0]);
  s[1] = silu_f(p[1]);
  return s;
}

__global__ __launch_bounds__(256) void edge_agg_kernel(
    const _Float16* __restrict__ UV, const int* __restrict__ row_start,
    const int4* __restrict__ rec,
    const float* __restrict__ w1e, const float* __restrict__ invd,
    _Float16* __restrict__ S)
{
  const int tid = threadIdx.x;
  const int wv  = __builtin_amdgcn_readfirstlane(tid >> 6);
  const int ln  = tid & 63;
  const int n   = blockIdx.x*4 + wv;   // grid NN/4 = 5000 exact
  const int c0  = ln*2;

  const float2v wc0 = *(const float2v*)(w1e +   0 + c0);
  const float2v wc1 = *(const float2v*)(w1e + 128 + c0);
  const float2v wc2 = *(const float2v*)(w1e + 256 + c0);

  half2v uvp = *(const half2v*)(UV + (size_t)n*256 + c0);
  float2v u; u[0] = (float)uvp[0]; u[1] = (float)uvp[1];

  const int rs = row_start[n], re = row_start[n+1];
  float2v a0 = {0.f,0.f}, a1 = {0.f,0.f}, a2 = {0.f,0.f}, a3 = {0.f,0.f};

  const int nq = (re - rs) >> 2;       // full quads
  int e = rs;
  for (int q = 0; q < nq; ++q, e += 4){
    const int4 r0 = rec[e+0];
    const int4 r1 = rec[e+1];
    const int4 r2 = rec[e+2];
    const int4 r3 = rec[e+3];
    const half2v v0 = *(const half2v*)(UV + (size_t)r0.w + 128 + c0);
    const half2v v1 = *(const half2v*)(UV + (size_t)r1.w + 128 + c0);
    const half2v v2 = *(const half2v*)(UV + (size_t)r2.w + 128 + c0);
    const half2v v3 = *(const half2v*)(UV + (size_t)r3.w + 128 + c0);
    a0 += edge_contrib(r0, v0, u, wc0, wc1, wc2);
    a1 += edge_contrib(r1, v1, u, wc0, wc1, wc2);
    a2 += edge_contrib(r2, v2, u, wc0, wc1, wc2);
    a3 += edge_contrib(r3, v3, u, wc0, wc1, wc2);
  }
  if (e < re){                          // remainder 1-3 edges (wave-uniform)
    const int e1 = (e+1 < re) ? e+1 : e;
    const int e2 = (e+2 < re) ? e+2 : e;
    const int4 r0 = rec[e];
    const int4 r1 = rec[e1];
    const int4 r2 = rec[e2];
    const half2v v0 = *(const half2v*)(UV + (size_t)r0.w + 128 + c0);
    const half2v v1 = *(const half2v*)(UV + (size_t)r1.w + 128 + c0);
    const half2v v2 = *(const half2v*)(UV + (size_t)r2.w + 128 + c0);
    a0 += edge_contrib(r0, v0, u, wc0, wc1, wc2);
    if (e+1 < re) a1 += edge_contrib(r1, v1, u, wc0, wc1, wc2);
    if (e+2 < re) a2 += edge_contrib(r2, v2, u, wc0, wc1, wc2);
  }
  float2v a = (a0 + a1) + (a2 + a3);
  const float iv = invd[n];
  half2v outv; outv[0] = (_Float16)(a[0]*iv); outv[1] = (_Float16)(a[1]*iv);
  *(half2v*)(S + (size_t)n*HD + c0) = outv;
}

// ---------------- node_proj + fused proj(l+1) OR fused decoder (l==5) ----------------
__global__ __launch_bounds__(256) void node_proj_kernel(
    const _Float16* __restrict__ S, const _Float16* __restrict__ w2p,
    const float* __restrict__ b2, const float* __restrict__ invd,
    float* __restrict__ h, _Float16* __restrict__ hh,
    const _Float16* __restrict__ w1pn, const float* __restrict__ b1n,
    _Float16* __restrict__ UV, int do_proj,
    const _Float16* __restrict__ w1dp, const float* __restrict__ db1,
    const _Float16* __restrict__ w2dp, const float* __restrict__ db2,
    const float* __restrict__ dw3, const float* __restrict__ db3,
    float* __restrict__ out, int do_dec)
{
  __shared__ _Float16 hl[16][136];
  __shared__ _Float16 d1[16][136];
  __shared__ float s2m[16][66];
  const int tid = threadIdx.x;
  const int wv  = tid >> 6;
  const int ln  = tid & 63;
  const int q   = ln >> 4;
  const int m   = ln & 15;
  const int n0  = blockIdx.x*16;      // grid = NN/16 = 1250 exact

  floatx4 acc[2];
  acc[0] = (floatx4){0.f,0.f,0.f,0.f};
  acc[1] = (floatx4){0.f,0.f,0.f,0.f};
  #pragma unroll
  for (int ks=0; ks<4; ++ks){
    half8 a = *(const half8*)(S + (size_t)(n0+m)*HD + ks*32 + q*8);
    const _Float16* wb = w2p + (size_t)(ks*8*64 + ln)*8;
    #pragma unroll
    for (int j=0;j<2;++j){
      half8 b = *(const half8*)(wb + (size_t)(wv*2+j)*512);
      acc[j] = __builtin_amdgcn_mfma_f32_16x16x32_f16(a, b, acc[j], 0,0,0);
    }
  }
  float gate[4];
  #pragma unroll
  for (int r=0;r<4;++r) gate[r] = (invd[n0 + q*4 + r] > 0.f) ? 1.f : 0.f;
  #pragma unroll
  for (int j=0; j<2; ++j){
    const int c = (wv*2+j)*16 + m;
    const float bv = b2[c];
    #pragma unroll
    for (int r=0;r<4;++r){
      size_t off = (size_t)(n0+q*4+r)*HD + c;
      float hv = h[off] + acc[j][r] + gate[r]*bv;
      h[off] = hv;
      hh[off] = (_Float16)hv;
      hl[q*4+r][c] = (_Float16)hv;
    }
  }
  __syncthreads();

  if (do_proj){
    floatx4 acc2[4];
    #pragma unroll
    for (int j=0;j<4;++j) acc2[j] = (floatx4){0.f,0.f,0.f,0.f};
    #pragma unroll
    for (int ks=0; ks<4; ++ks){
      half8 a = *(const half8*)&hl[m][ks*32 + q*8];
      const _Float16* wb = w1pn + (size_t)(ks*16*64 + ln)*8;
      #pragma unroll
      for (int j=0; j<4; ++j){
        half8 b = *(const half8*)(wb + (size_t)(wv*4+j)*512);
        acc2[j] = __builtin_amdgcn_mfma_f32_16x16x32_f16(a, b, acc2[j], 0,0,0);
      }
    }
    #pragma unroll
    for (int j=0; j<4; ++j){
      const int c = (wv*4+j)*16 + m;
      const float bias = (c < 128) ? b1n[c] : 0.f;
      #pragma unroll
      for (int r=0;r<4;++r)
        UV[(size_t)(n0+q*4+r)*256 + c] = (_Float16)(acc2[j][r] + bias);
    }
  }

  if (do_dec){
    // ---- fused decoder: reads hl (block-local hh), writes out ----
    floatx4 acc1[2];
    acc1[0] = (floatx4){0.f,0.f,0.f,0.f};
    acc1[1] = (floatx4){0.f,0.f,0.f,0.f};
    #pragma unroll
    for (int ks=0; ks<4; ++ks){
      half8 a = *(const half8*)&hl[m][ks*32 + q*8];
      const _Float16* wb = w1dp + (size_t)(ks*8*64 + ln)*8;
      #pragma unroll
      for (int j=0; j<2; ++j){
        half8 b = *(const half8*)(wb + (size_t)(wv*2+j)*512);
        acc1[j] = __builtin_amdgcn_mfma_f32_16x16x32_f16(a, b, acc1[j], 0,0,0);
      }
    }
    #pragma unroll
    for (int j=0; j<2; ++j){
      const int c = (wv*2+j)*16 + m;
      const float bv = db1[c];
      #pragma unroll
      for (int r=0;r<4;++r)
        d1[q*4+r][c] = (_Float16)silu_f(acc1[j][r] + bv);
    }
    __syncthreads();

    floatx4 acc2 = (floatx4){0.f,0.f,0.f,0.f};
    #pragma unroll
    for (int ks=0; ks<4; ++ks){
      half8 a = *(const half8*)&d1[m][ks*32 + q*8];
      const _Float16* wb = w2dp + (size_t)(ks*4*64 + ln)*8;
      half8 b = *(const half8*)(wb + (size_t)wv*512);
      acc2 = __builtin_amdgcn_mfma_f32_16x16x32_f16(a, b, acc2, 0,0,0);
    }
    {
      const int c = wv*16 + m;
      const float bv = db2[c];
      #pragma unroll
      for (int r=0;r<4;++r)
        s2m[q*4+r][c] = silu_f(acc2[r] + bv);
    }
    __syncthreads();

    if (tid < 144){
      int i = tid/9, oo = tid%9;
      float a = db3[oo];
      #pragma unroll 8
      for (int k=0;k<64;++k) a += s2m[i][k]*dw3[k*9+oo];
      out[(size_t)(n0+i)*9 + oo] = a;
    }
  }
}

// ---------------- workspace layout (36,719,040 B — r4 exact) ----------------
constexpr size_t OFF_H    = 0;                         // 10,240,000
constexpr size_t OFF_HH   = 10240000;                  //  5,120,000
constexpr size_t OFF_UV   = 15360000;                  // 10,240,000
constexpr size_t OFF_S    = 25600000;                  //  5,120,000 (fp16)
constexpr size_t OFF_INVD = 30720000;                  //     80,000
constexpr size_t OFF_RS   = 30800000;                  //     80,064
constexpr size_t OFF_CUR  = 30880064;                  //     80,000
constexpr size_t OFF_REC  = 30960064;                  //  5,120,000 (int4/edge)
constexpr size_t OFF_W1P  = 36080064;                  //    393,216
constexpr size_t OFF_W2P  = 36473280;                  //    196,608
constexpr size_t OFF_DW1P = 36669888;                  //     32,768
constexpr size_t OFF_DW2P = 36702656;                  //     16,384
constexpr size_t WS_NEEDED= 36719040;

extern "C" void kernel_launch(void* const* d_in, const int* in_sizes, int n_in,
                              void* d_out, int out_size, void* d_ws, size_t ws_size,
                              hipStream_t stream)
{
  float* out = (float*)d_out;
  const int nout_blk = (out_size + 255)/256;

  static const int EXP_SIZES[17] = {280000,640000,960000,1792,128,16384,128,
                                    198912,768,98304,768,16384,128,8192,64,576,9};
  if (n_in != 17){
    sentinel_kernel<<<nout_blk, 256, 0, stream>>>(out, out_size, 2.0e7f + (float)n_in*1.0e3f);
    return;
  }
  for (int i = 0; i < 17; ++i){
    if (in_sizes[i] != EXP_SIZES[i]){
      int sz = in_sizes[i] < 99999 ? in_sizes[i] : 99999;
      sentinel_kernel<<<nout_blk, 256, 0, stream>>>(out, out_size,
          1.0e7f + (float)i*1.0e5f + (float)sz);
      return;
    }
  }
  if (ws_size < WS_NEEDED){
    sentinel_kernel<<<nout_blk, 256, 0, stream>>>(out, out_size, 1.0e6f);
    return;
  }

  const float* x       = (const float*)d_in[0];
  const int*   ei      = (const int*)  d_in[1];
  const float* eattr   = (const float*)d_in[2];
  const float* enc_w1  = (const float*)d_in[3];
  const float* enc_b1  = (const float*)d_in[4];
  const float* enc_w2  = (const float*)d_in[5];
  const float* enc_b2  = (const float*)d_in[6];
  const float* conv_w1 = (const float*)d_in[7];
  const float* conv_b1 = (const float*)d_in[8];
  const float* conv_w2 = (const float*)d_in[9];
  const float* conv_b2 = (const float*)d_in[10];
  const float* dec_w1  = (const float*)d_in[11];
  const float* dec_b1  = (const float*)d_in[12];
  const float* dec_w2  = (const float*)d_in[13];
  const float* dec_b2  = (const float*)d_in[14];
  const float* dec_w3  = (const float*)d_in[15];
  const float* dec_b3  = (const float*)d_in[16];

  char* ws = (char*)d_ws;
  float*    h     = (float*)   (ws + OFF_H);
  _Float16* hh    = (_Float16*)(ws + OFF_HH);
  _Float16* UV    = (_Float16*)(ws + OFF_UV);
  _Float16* S     = (_Float16*)(ws + OFF_S);
  float*    invd  = (float*)   (ws + OFF_INVD);
  int*      rstart= (int*)     (ws + OFF_RS);
  int*      cur   = (int*)     (ws + OFF_CUR);
  int4*     rec   = (int4*)    (ws + OFF_REC);
  _Float16* w1p   = (_Float16*)(ws + OFF_W1P);
  _Float16* w2p   = (_Float16*)(ws + OFF_W2P);
  _Float16* w1dp  = (_Float16*)(ws + OFF_DW1P);
  _Float16* w2dp  = (_Float16*)(ws + OFF_DW2P);

  pack_all_kernel<<<1327, 256, 0, stream>>>(conv_w1, conv_w2, dec_w1, dec_w2,
                                            w1p, w2p, w1dp, w2dp, cur);
  count_kernel<<<EE/256, 256, 0, stream>>>(ei, cur);
  scan_kernel<<<1, 1024, 0, stream>>>(cur, rstart, invd);
  scatter_kernel<<<EE/256, 256, 0, stream>>>(ei, eattr, cur, rec);
  encoder_proj_kernel<<<NN/16, 128, 0, stream>>>(x, enc_w1, enc_b1, enc_w2, enc_b2,
                                                 h, hh, w1p, conv_b1, UV);
  for (int l=0; l<6; ++l){
    edge_agg_kernel<<<NN/4, 256, 0, stream>>>(UV, rstart, rec,
                                              conv_w1 + (size_t)l*33152 + 32768,
                                              invd, S);
    const int lp = (l < 5) ? l+1 : 0;   // dummy valid ptrs for last layer
    node_proj_kernel<<<NN/16, 256, 0, stream>>>(S, w2p + (size_t)l*16384,
                                                conv_b2 + (size_t)l*128, invd, h, hh,
                                                w1p + (size_t)lp*32768,
                                                conv_b1 + (size_t)lp*128,
                                                UV, (l < 5) ? 1 : 0,
                                                w1dp, dec_b1, w2dp, dec_b2,
                                                dec_w3, dec_b3, out,
                                                (l == 5) ? 1 : 0);
  }
}

// Round 10
// 405.277 us; speedup vs baseline: 1.0822x; 1.0096x over previous
//
#include <hip/hip_runtime.h>
#include <hip/hip_bf16.h>

#define NN 20000
#define EE 320000
#define HD 128   // hidden

typedef _Float16 half8 __attribute__((ext_vector_type(8)));
typedef _Float16 half4 __attribute__((ext_vector_type(4)));
typedef _Float16 half2v __attribute__((ext_vector_type(2)));
typedef float floatx4 __attribute__((ext_vector_type(4)));
typedef float float2v __attribute__((ext_vector_type(2)));

// silu via HW rcp (1-ulp) instead of exact fp32 divide.
__device__ __forceinline__ float silu_f(float x){
  float e = __expf(-x);
  return x * __builtin_amdgcn_rcpf(1.f + e);
}

__device__ __forceinline__ bool ei_is64(const int* __restrict__ ei){
  return (ei[1] | ei[3] | ei[5] | ei[7]) == 0;
}
__device__ __forceinline__ int ei_src(const int* __restrict__ ei, int e, bool is64){
  return is64 ? ei[2*(size_t)e] : ei[e];
}
__device__ __forceinline__ int ei_dst(const int* __restrict__ ei, int e, bool is64){
  return is64 ? ei[2*(size_t)EE + 2*(size_t)e] : ei[EE + e];
}

__global__ __launch_bounds__(256) void sentinel_kernel(float* __restrict__ out, int n, float val){
  int i = blockIdx.x*256 + threadIdx.x;
  if (i < n) out[i] = val;
}

// ---------------- merged weight packing + cur zeroing (r9 — kept) ----------------
__global__ __launch_bounds__(256) void pack_all_kernel(const float* __restrict__ cw1,
                                                       const float* __restrict__ cw2,
                                                       const float* __restrict__ dw1,
                                                       const float* __restrict__ dw2,
                                                       _Float16* __restrict__ w1p,
                                                       _Float16* __restrict__ w2p,
                                                       _Float16* __restrict__ w1dp,
                                                       _Float16* __restrict__ w2dp,
                                                       int* __restrict__ cur){
  int idx = blockIdx.x*256 + threadIdx.x;
  if (idx >= 319488){
    int j = idx - 319488;
    if (j < NN) cur[j] = 0;
    return;
  }
  if (idx < 196608){
    int j   = idx & 7;
    int ln  = (idx >> 3) & 63;
    int rest= idx >> 9;
    int cb  = rest & 15;
    int rest2 = rest >> 4;
    int ks  = rest2 & 3;
    int l   = rest2 >> 2;
    int k = ks*32 + (ln>>4)*8 + j;
    int c = cb*16 + (ln&15);
    float v = (c < 128) ? cw1[(size_t)l*33152 + (size_t)k*128 + c]
                        : cw1[(size_t)l*33152 + (size_t)(128+k)*128 + (c-128)];
    w1p[idx] = (_Float16)v;
  } else if (idx < 294912){
    int t = idx - 196608;
    int j   = t & 7;
    int ln  = (t >> 3) & 63;
    int rest= t >> 9;
    int cb  = rest & 7;
    int rest2 = rest >> 3;
    int ks  = rest2 & 3;
    int l   = rest2 >> 2;
    int k = ks*32 + (ln>>4)*8 + j;
    int c = cb*16 + (ln&15);
    w2p[t] = (_Float16)cw2[(size_t)l*16384 + (size_t)k*128 + c];
  } else {
    int t2 = idx - 294912;
    if (t2 < 16384){
      int j = t2 & 7, ln = (t2>>3)&63, cb = (t2>>9)&7, ks = t2>>12;
      int k = ks*32 + (ln>>4)*8 + j;
      int c = cb*16 + (ln&15);
      w1dp[t2] = (_Float16)dw1[(size_t)k*128 + c];
    } else {
      int t = t2 - 16384;
      int j = t & 7, ln = (t>>3)&63, cb = (t>>9)&3, ks = t>>11;
      int k = ks*32 + (ln>>4)*8 + j;
      int c = cb*16 + (ln&15);
      w2dp[t] = (_Float16)dw2[(size_t)k*64 + c];
    }
  }
}

// ---------------- CSR build (r4 exact) ----------------
__global__ __launch_bounds__(256) void count_kernel(const int* __restrict__ ei, int* __restrict__ cnt){
  int e = blockIdx.x*256 + threadIdx.x;   // EE/256 exact
  bool is64 = ei_is64(ei);
  atomicAdd(&cnt[ei_dst(ei, e, is64)], 1);
}

__global__ __launch_bounds__(1024) void scan_kernel(int* __restrict__ cntcur,
                                                    int* __restrict__ row_start,
                                                    float* __restrict__ invd){
  __shared__ int part[1024];
  const int t = threadIdx.x;
  const int base = t*20;
  int loc[20];
  int sum = 0;
  #pragma unroll
  for (int i=0;i<20;++i){
    int n = base+i;
    int v = (n < NN) ? cntcur[n] : 0;
    loc[i] = sum; sum += v;
  }
  part[t] = sum;
  __syncthreads();
  for (int off=1; off<1024; off<<=1){
    int v = (t >= off) ? part[t-off] : 0;
    __syncthreads();
    part[t] += v;
    __syncthreads();
  }
  int pre = (t > 0) ? part[t-1] : 0;
  #pragma unroll
  for (int i=0;i<20;++i){
    int n = base+i;
    if (n < NN){
      int rs = pre + loc[i];
      int deg = ((i<19)?loc[i+1]:sum) - loc[i];
      row_start[n] = rs;
      invd[n] = (deg > 0) ? 1.f/(float)deg : 0.f;
      cntcur[n] = rs;
    }
  }
  if (t == 1023) row_start[NN] = part[1023];
}

// scatter (r4 exact): one 16B rec per edge {ea0,ea1,ea2 fp32 bits, src*256}.
__global__ __launch_bounds__(256) void scatter_kernel(const int* __restrict__ ei,
                                                      const float* __restrict__ eattr,
                                                      int* __restrict__ cur,
                                                      int4* __restrict__ rec){
  int e = blockIdx.x*256 + threadIdx.x;   // EE/256 exact
  bool is64 = ei_is64(ei);
  int s = ei_src(ei, e, is64);
  int d = ei_dst(ei, e, is64);
  int pos = atomicAdd(&cur[d], 1);
  int4 r;
  r.x = __float_as_int(eattr[(size_t)e*3+0]);
  r.y = __float_as_int(eattr[(size_t)e*3+1]);
  r.z = __float_as_int(eattr[(size_t)e*3+2]);
  r.w = s*256;   // pre-scaled UV row element-offset
  rec[pos] = r;
}

// ---------------- encoder (r4 exact — r9's proj fusion cost 88 VGPR / 12% occ / 48us; reverted) ----------------
__global__ __launch_bounds__(128) void encoder_kernel(
    const float* __restrict__ x, const float* __restrict__ w1, const float* __restrict__ b1,
    const float* __restrict__ w2, const float* __restrict__ b2,
    float* __restrict__ h, _Float16* __restrict__ hh)
{
  __shared__ float xs[16][14];
  __shared__ float s1[16][128];
  const int n0 = blockIdx.x*16;
  const int tid = threadIdx.x;
  for (int idx=tid; idx<224; idx+=128){
    int i = idx/14, k = idx%14;
    xs[i][k] = x[(size_t)(n0+i)*14 + k];
  }
  __syncthreads();
  const int o = tid;
  float acc[16];
  float bv = b1[o];
  #pragma unroll
  for (int i=0;i<16;++i) acc[i] = bv;
  for (int k=0;k<14;++k){
    float w = w1[k*128+o];
    #pragma unroll
    for (int i=0;i<16;++i) acc[i] += xs[i][k]*w;
  }
  #pragma unroll
  for (int i=0;i<16;++i) s1[i][o] = silu_f(acc[i]);
  __syncthreads();
  float bv2 = b2[o];
  #pragma unroll
  for (int i=0;i<16;++i) acc[i] = bv2;
  for (int k=0;k<128;k+=4){
    float w0=w2[(k+0)*128+o], w1v=w2[(k+1)*128+o], w2v=w2[(k+2)*128+o], w3v=w2[(k+3)*128+o];
    #pragma unroll
    for (int i=0;i<16;++i){
      float4 sv = *(const float4*)&s1[i][k];
      acc[i] += sv.x*w0 + sv.y*w1v + sv.z*w2v + sv.w*w3v;
    }
  }
  #pragma unroll
  for (int i=0;i<16;++i){
    size_t off = (size_t)(n0+i)*HD + o;
    h[off] = acc[i];
    hh[off] = (_Float16)acc[i];
  }
}

// ---------------- proj (r4 exact: 1250 blocks, 256 thr, 4 cb/wave) ----------------
__global__ __launch_bounds__(256) void proj_kernel(
    const _Float16* __restrict__ hh, const _Float16* __restrict__ w1p,
    const float* __restrict__ b1, _Float16* __restrict__ UV)
{
  const int tid = threadIdx.x;
  const int wv  = tid >> 6;
  const int ln  = tid & 63;
  const int q   = ln >> 4;
  const int m   = ln & 15;
  const int n0  = blockIdx.x*16;      // grid = NN/16 = 1250 exact

  floatx4 acc[4];
  #pragma unroll
  for (int j=0;j<4;++j) acc[j] = (floatx4){0.f,0.f,0.f,0.f};

  #pragma unroll
  for (int ks=0; ks<4; ++ks){
    half8 a = *(const half8*)(hh + (size_t)(n0+m)*HD + ks*32 + q*8);
    const _Float16* wb = w1p + (size_t)(ks*16*64 + ln)*8;
    #pragma unroll
    for (int j=0; j<4; ++j){
      half8 b = *(const half8*)(wb + (size_t)(wv*4+j)*512);
      acc[j] = __builtin_amdgcn_mfma_f32_16x16x32_f16(a, b, acc[j], 0,0,0);
    }
  }
  #pragma unroll
  for (int j=0; j<4; ++j){
    const int c = (wv*4+j)*16 + m;
    const float bias = (c < 128) ? b1[c] : 0.f;
    #pragma unroll
    for (int r=0;r<4;++r)
      UV[(size_t)(n0+q*4+r)*256 + c] = (_Float16)(acc[j][r] + bias);
  }
}

// ---------------- edge_agg (r4 exact — best known, do not touch) ----------------
__device__ __forceinline__ float2v edge_contrib(int4 r, half2v v, float2v u,
                                                float2v wc0, float2v wc1, float2v wc2){
  float2v p = u;
  p += __int_as_float(r.x) * wc0;
  p += __int_as_float(r.y) * wc1;
  p += __int_as_float(r.z) * wc2;
  p[0] += (float)v[0];
  p[1] += (float)v[1];
  float2v s;
  s[0] = silu_f(p[0]);
  s[1] = silu_f(p[1]);
  return s;
}

__global__ __launch_bounds__(256) void edge_agg_kernel(
    const _Float16* __restrict__ UV, const int* __restrict__ row_start,
    const int4* __restrict__ rec,
    const float* __restrict__ w1e, const float* __restrict__ invd,
    _Float16* __restrict__ S)
{
  const int tid = threadIdx.x;
  const int wv  = __builtin_amdgcn_readfirstlane(tid >> 6);
  const int ln  = tid & 63;
  const int n   = blockIdx.x*4 + wv;   // grid NN/4 = 5000 exact
  const int c0  = ln*2;

  const float2v wc0 = *(const float2v*)(w1e +   0 + c0);
  const float2v wc1 = *(const float2v*)(w1e + 128 + c0);
  const float2v wc2 = *(const float2v*)(w1e + 256 + c0);

  half2v uvp = *(const half2v*)(UV + (size_t)n*256 + c0);
  float2v u; u[0] = (float)uvp[0]; u[1] = (float)uvp[1];

  const int rs = row_start[n], re = row_start[n+1];
  float2v a0 = {0.f,0.f}, a1 = {0.f,0.f}, a2 = {0.f,0.f}, a3 = {0.f,0.f};

  const int nq = (re - rs) >> 2;       // full quads
  int e = rs;
  for (int q = 0; q < nq; ++q, e += 4){
    const int4 r0 = rec[e+0];
    const int4 r1 = rec[e+1];
    const int4 r2 = rec[e+2];
    const int4 r3 = rec[e+3];
    const half2v v0 = *(const half2v*)(UV + (size_t)r0.w + 128 + c0);
    const half2v v1 = *(const half2v*)(UV + (size_t)r1.w + 128 + c0);
    const half2v v2 = *(const half2v*)(UV + (size_t)r2.w + 128 + c0);
    const half2v v3 = *(const half2v*)(UV + (size_t)r3.w + 128 + c0);
    a0 += edge_contrib(r0, v0, u, wc0, wc1, wc2);
    a1 += edge_contrib(r1, v1, u, wc0, wc1, wc2);
    a2 += edge_contrib(r2, v2, u, wc0, wc1, wc2);
    a3 += edge_contrib(r3, v3, u, wc0, wc1, wc2);
  }
  if (e < re){                          // remainder 1-3 edges (wave-uniform)
    const int e1 = (e+1 < re) ? e+1 : e;
    const int e2 = (e+2 < re) ? e+2 : e;
    const int4 r0 = rec[e];
    const int4 r1 = rec[e1];
    const int4 r2 = rec[e2];
    const half2v v0 = *(const half2v*)(UV + (size_t)r0.w + 128 + c0);
    const half2v v1 = *(const half2v*)(UV + (size_t)r1.w + 128 + c0);
    const half2v v2 = *(const half2v*)(UV + (size_t)r2.w + 128 + c0);
    a0 += edge_contrib(r0, v0, u, wc0, wc1, wc2);
    if (e+1 < re) a1 += edge_contrib(r1, v1, u, wc0, wc1, wc2);
    if (e+2 < re) a2 += edge_contrib(r2, v2, u, wc0, wc1, wc2);
  }
  float2v a = (a0 + a1) + (a2 + a3);
  const float iv = invd[n];
  half2v outv; outv[0] = (_Float16)(a[0]*iv); outv[1] = (_Float16)(a[1]*iv);
  *(half2v*)(S + (size_t)n*HD + c0) = outv;
}

// ---------------- node_proj + fused proj(l+1) OR fused decoder (l==5) — r9 kept ----------------
__global__ __launch_bounds__(256) void node_proj_kernel(
    const _Float16* __restrict__ S, const _Float16* __restrict__ w2p,
    const float* __restrict__ b2, const float* __restrict__ invd,
    float* __restrict__ h, _Float16* __restrict__ hh,
    const _Float16* __restrict__ w1pn, const float* __restrict__ b1n,
    _Float16* __restrict__ UV, int do_proj,
    const _Float16* __restrict__ w1dp, const float* __restrict__ db1,
    const _Float16* __restrict__ w2dp, const float* __restrict__ db2,
    const float* __restrict__ dw3, const float* __restrict__ db3,
    float* __restrict__ out, int do_dec)
{
  __shared__ _Float16 hl[16][136];
  __shared__ _Float16 d1[16][136];
  __shared__ float s2m[16][66];
  const int tid = threadIdx.x;
  const int wv  = tid >> 6;
  const int ln  = tid & 63;
  const int q   = ln >> 4;
  const int m   = ln & 15;
  const int n0  = blockIdx.x*16;      // grid = NN/16 = 1250 exact

  floatx4 acc[2];
  acc[0] = (floatx4){0.f,0.f,0.f,0.f};
  acc[1] = (floatx4){0.f,0.f,0.f,0.f};
  #pragma unroll
  for (int ks=0; ks<4; ++ks){
    half8 a = *(const half8*)(S + (size_t)(n0+m)*HD + ks*32 + q*8);
    const _Float16* wb = w2p + (size_t)(ks*8*64 + ln)*8;
    #pragma unroll
    for (int j=0;j<2;++j){
      half8 b = *(const half8*)(wb + (size_t)(wv*2+j)*512);
      acc[j] = __builtin_amdgcn_mfma_f32_16x16x32_f16(a, b, acc[j], 0,0,0);
    }
  }
  float gate[4];
  #pragma unroll
  for (int r=0;r<4;++r) gate[r] = (invd[n0 + q*4 + r] > 0.f) ? 1.f : 0.f;
  #pragma unroll
  for (int j=0; j<2; ++j){
    const int c = (wv*2+j)*16 + m;
    const float bv = b2[c];
    #pragma unroll
    for (int r=0;r<4;++r){
      size_t off = (size_t)(n0+q*4+r)*HD + c;
      float hv = h[off] + acc[j][r] + gate[r]*bv;
      h[off] = hv;
      hh[off] = (_Float16)hv;
      hl[q*4+r][c] = (_Float16)hv;
    }
  }
  __syncthreads();

  if (do_proj){
    floatx4 acc2[4];
    #pragma unroll
    for (int j=0;j<4;++j) acc2[j] = (floatx4){0.f,0.f,0.f,0.f};
    #pragma unroll
    for (int ks=0; ks<4; ++ks){
      half8 a = *(const half8*)&hl[m][ks*32 + q*8];
      const _Float16* wb = w1pn + (size_t)(ks*16*64 + ln)*8;
      #pragma unroll
      for (int j=0; j<4; ++j){
        half8 b = *(const half8*)(wb + (size_t)(wv*4+j)*512);
        acc2[j] = __builtin_amdgcn_mfma_f32_16x16x32_f16(a, b, acc2[j], 0,0,0);
      }
    }
    #pragma unroll
    for (int j=0; j<4; ++j){
      const int c = (wv*4+j)*16 + m;
      const float bias = (c < 128) ? b1n[c] : 0.f;
      #pragma unroll
      for (int r=0;r<4;++r)
        UV[(size_t)(n0+q*4+r)*256 + c] = (_Float16)(acc2[j][r] + bias);
    }
  }

  if (do_dec){
    // ---- fused decoder: reads hl (block-local hh), writes out ----
    floatx4 acc1[2];
    acc1[0] = (floatx4){0.f,0.f,0.f,0.f};
    acc1[1] = (floatx4){0.f,0.f,0.f,0.f};
    #pragma unroll
    for (int ks=0; ks<4; ++ks){
      half8 a = *(const half8*)&hl[m][ks*32 + q*8];
      const _Float16* wb = w1dp + (size_t)(ks*8*64 + ln)*8;
      #pragma unroll
      for (int j=0; j<2; ++j){
        half8 b = *(const half8*)(wb + (size_t)(wv*2+j)*512);
        acc1[j] = __builtin_amdgcn_mfma_f32_16x16x32_f16(a, b, acc1[j], 0,0,0);
      }
    }
    #pragma unroll
    for (int j=0; j<2; ++j){
      const int c = (wv*2+j)*16 + m;
      const float bv = db1[c];
      #pragma unroll
      for (int r=0;r<4;++r)
        d1[q*4+r][c] = (_Float16)silu_f(acc1[j][r] + bv);
    }
    __syncthreads();

    floatx4 acc2 = (floatx4){0.f,0.f,0.f,0.f};
    #pragma unroll
    for (int ks=0; ks<4; ++ks){
      half8 a = *(const half8*)&d1[m][ks*32 + q*8];
      const _Float16* wb = w2dp + (size_t)(ks*4*64 + ln)*8;
      half8 b = *(const half8*)(wb + (size_t)wv*512);
      acc2 = __builtin_amdgcn_mfma_f32_16x16x32_f16(a, b, acc2, 0,0,0);
    }
    {
      const int c = wv*16 + m;
      const float bv = db2[c];
      #pragma unroll
      for (int r=0;r<4;++r)
        s2m[q*4+r][c] = silu_f(acc2[r] + bv);
    }
    __syncthreads();

    if (tid < 144){
      int i = tid/9, oo = tid%9;
      float a = db3[oo];
      #pragma unroll 8
      for (int k=0;k<64;++k) a += s2m[i][k]*dw3[k*9+oo];
      out[(size_t)(n0+i)*9 + oo] = a;
    }
  }
}

// ---------------- workspace layout (36,719,040 B — r4 exact) ----------------
constexpr size_t OFF_H    = 0;                         // 10,240,000
constexpr size_t OFF_HH   = 10240000;                  //  5,120,000
constexpr size_t OFF_UV   = 15360000;                  // 10,240,000
constexpr size_t OFF_S    = 25600000;                  //  5,120,000 (fp16)
constexpr size_t OFF_INVD = 30720000;                  //     80,000
constexpr size_t OFF_RS   = 30800000;                  //     80,064
constexpr size_t OFF_CUR  = 30880064;                  //     80,000
constexpr size_t OFF_REC  = 30960064;                  //  5,120,000 (int4/edge)
constexpr size_t OFF_W1P  = 36080064;                  //    393,216
constexpr size_t OFF_W2P  = 36473280;                  //    196,608
constexpr size_t OFF_DW1P = 36669888;                  //     32,768
constexpr size_t OFF_DW2P = 36702656;                  //     16,384
constexpr size_t WS_NEEDED= 36719040;

extern "C" void kernel_launch(void* const* d_in, const int* in_sizes, int n_in,
                              void* d_out, int out_size, void* d_ws, size_t ws_size,
                              hipStream_t stream)
{
  float* out = (float*)d_out;
  const int nout_blk = (out_size + 255)/256;

  static const int EXP_SIZES[17] = {280000,640000,960000,1792,128,16384,128,
                                    198912,768,98304,768,16384,128,8192,64,576,9};
  if (n_in != 17){
    sentinel_kernel<<<nout_blk, 256, 0, stream>>>(out, out_size, 2.0e7f + (float)n_in*1.0e3f);
    return;
  }
  for (int i = 0; i < 17; ++i){
    if (in_sizes[i] != EXP_SIZES[i]){
      int sz = in_sizes[i] < 99999 ? in_sizes[i] : 99999;
      sentinel_kernel<<<nout_blk, 256, 0, stream>>>(out, out_size,
          1.0e7f + (float)i*1.0e5f + (float)sz);
      return;
    }
  }
  if (ws_size < WS_NEEDED){
    sentinel_kernel<<<nout_blk, 256, 0, stream>>>(out, out_size, 1.0e6f);
    return;
  }

  const float* x       = (const float*)d_in[0];
  const int*   ei      = (const int*)  d_in[1];
  const float* eattr   = (const float*)d_in[2];
  const float* enc_w1  = (const float*)d_in[3];
  const float* enc_b1  = (const float*)d_in[4];
  const float* enc_w2  = (const float*)d_in[5];
  const float* enc_b2  = (const float*)d_in[6];
  const float* conv_w1 = (const float*)d_in[7];
  const float* conv_b1 = (const float*)d_in[8];
  const float* conv_w2 = (const float*)d_in[9];
  const float* conv_b2 = (const float*)d_in[10];
  const float* dec_w1  = (const float*)d_in[11];
  const float* dec_b1  = (const float*)d_in[12];
  const float* dec_w2  = (const float*)d_in[13];
  const float* dec_b2  = (const float*)d_in[14];
  const float* dec_w3  = (const float*)d_in[15];
  const float* dec_b3  = (const float*)d_in[16];

  char* ws = (char*)d_ws;
  float*    h     = (float*)   (ws + OFF_H);
  _Float16* hh    = (_Float16*)(ws + OFF_HH);
  _Float16* UV    = (_Float16*)(ws + OFF_UV);
  _Float16* S     = (_Float16*)(ws + OFF_S);
  float*    invd  = (float*)   (ws + OFF_INVD);
  int*      rstart= (int*)     (ws + OFF_RS);
  int*      cur   = (int*)     (ws + OFF_CUR);
  int4*     rec   = (int4*)    (ws + OFF_REC);
  _Float16* w1p   = (_Float16*)(ws + OFF_W1P);
  _Float16* w2p   = (_Float16*)(ws + OFF_W2P);
  _Float16* w1dp  = (_Float16*)(ws + OFF_DW1P);
  _Float16* w2dp  = (_Float16*)(ws + OFF_DW2P);

  pack_all_kernel<<<1327, 256, 0, stream>>>(conv_w1, conv_w2, dec_w1, dec_w2,
                                            w1p, w2p, w1dp, w2dp, cur);
  count_kernel<<<EE/256, 256, 0, stream>>>(ei, cur);
  scan_kernel<<<1, 1024, 0, stream>>>(cur, rstart, invd);
  scatter_kernel<<<EE/256, 256, 0, stream>>>(ei, eattr, cur, rec);
  encoder_kernel<<<NN/16, 128, 0, stream>>>(x, enc_w1, enc_b1, enc_w2, enc_b2, h, hh);
  proj_kernel<<<NN/16, 256, 0, stream>>>(hh, w1p, conv_b1, UV);   // layer 0 proj
  for (int l=0; l<6; ++l){
    edge_agg_kernel<<<NN/4, 256, 0, stream>>>(UV, rstart, rec,
                                              conv_w1 + (size_t)l*33152 + 32768,
                                              invd, S);
    const int lp = (l < 5) ? l+1 : 0;   // dummy valid ptrs for last layer
    node_proj_kernel<<<NN/16, 256, 0, stream>>>(S, w2p + (size_t)l*16384,
                                                conv_b2 + (size_t)l*128, invd, h, hh,
                                                w1p + (size_t)lp*32768,
                                                conv_b1 + (size_t)lp*128,
                                                UV, (l < 5) ? 1 : 0,
                                                w1dp, dec_b1, w2dp, dec_b2,
                                                dec_w3, dec_b3, out,
                                                (l == 5) ? 1 : 0);
  }
}

// Round 11
// 389.647 us; speedup vs baseline: 1.1256x; 1.0401x over previous
//
#include <hip/hip_runtime.h>
#include <hip/hip_bf16.h>

#define NN 20000
#define EE 320000
#define HD 128   // hidden

typedef _Float16 half8 __attribute__((ext_vector_type(8)));
typedef _Float16 half4 __attribute__((ext_vector_type(4)));
typedef _Float16 half2v __attribute__((ext_vector_type(2)));
typedef float floatx4 __attribute__((ext_vector_type(4)));
typedef float float2v __attribute__((ext_vector_type(2)));

// silu via HW rcp (1-ulp) instead of exact fp32 divide.
__device__ __forceinline__ float silu_f(float x){
  float e = __expf(-x);
  return x * __builtin_amdgcn_rcpf(1.f + e);
}

__device__ __forceinline__ bool ei_is64(const int* __restrict__ ei){
  return (ei[1] | ei[3] | ei[5] | ei[7]) == 0;
}
__device__ __forceinline__ int ei_src(const int* __restrict__ ei, int e, bool is64){
  return is64 ? ei[2*(size_t)e] : ei[e];
}
__device__ __forceinline__ int ei_dst(const int* __restrict__ ei, int e, bool is64){
  return is64 ? ei[2*(size_t)EE + 2*(size_t)e] : ei[EE + e];
}

__global__ __launch_bounds__(256) void sentinel_kernel(float* __restrict__ out, int n, float val){
  int i = blockIdx.x*256 + threadIdx.x;
  if (i < n) out[i] = val;
}

// ---------------- merged weight packing + cur zeroing (r9 — kept) ----------------
__global__ __launch_bounds__(256) void pack_all_kernel(const float* __restrict__ cw1,
                                                       const float* __restrict__ cw2,
                                                       const float* __restrict__ dw1,
                                                       const float* __restrict__ dw2,
                                                       _Float16* __restrict__ w1p,
                                                       _Float16* __restrict__ w2p,
                                                       _Float16* __restrict__ w1dp,
                                                       _Float16* __restrict__ w2dp,
                                                       int* __restrict__ cur){
  int idx = blockIdx.x*256 + threadIdx.x;
  if (idx >= 319488){
    int j = idx - 319488;
    if (j < NN) cur[j] = 0;
    return;
  }
  if (idx < 196608){
    int j   = idx & 7;
    int ln  = (idx >> 3) & 63;
    int rest= idx >> 9;
    int cb  = rest & 15;
    int rest2 = rest >> 4;
    int ks  = rest2 & 3;
    int l   = rest2 >> 2;
    int k = ks*32 + (ln>>4)*8 + j;
    int c = cb*16 + (ln&15);
    float v = (c < 128) ? cw1[(size_t)l*33152 + (size_t)k*128 + c]
                        : cw1[(size_t)l*33152 + (size_t)(128+k)*128 + (c-128)];
    w1p[idx] = (_Float16)v;
  } else if (idx < 294912){
    int t = idx - 196608;
    int j   = t & 7;
    int ln  = (t >> 3) & 63;
    int rest= t >> 9;
    int cb  = rest & 7;
    int rest2 = rest >> 3;
    int ks  = rest2 & 3;
    int l   = rest2 >> 2;
    int k = ks*32 + (ln>>4)*8 + j;
    int c = cb*16 + (ln&15);
    w2p[t] = (_Float16)cw2[(size_t)l*16384 + (size_t)k*128 + c];
  } else {
    int t2 = idx - 294912;
    if (t2 < 16384){
      int j = t2 & 7, ln = (t2>>3)&63, cb = (t2>>9)&7, ks = t2>>12;
      int k = ks*32 + (ln>>4)*8 + j;
      int c = cb*16 + (ln&15);
      w1dp[t2] = (_Float16)dw1[(size_t)k*128 + c];
    } else {
      int t = t2 - 16384;
      int j = t & 7, ln = (t>>3)&63, cb = (t>>9)&3, ks = t>>11;
      int k = ks*32 + (ln>>4)*8 + j;
      int c = cb*16 + (ln&15);
      w2dp[t] = (_Float16)dw2[(size_t)k*64 + c];
    }
  }
}

// ---------------- CSR build (r4 exact) ----------------
__global__ __launch_bounds__(256) void count_kernel(const int* __restrict__ ei, int* __restrict__ cnt){
  int e = blockIdx.x*256 + threadIdx.x;   // EE/256 exact
  bool is64 = ei_is64(ei);
  atomicAdd(&cnt[ei_dst(ei, e, is64)], 1);
}

__global__ __launch_bounds__(1024) void scan_kernel(int* __restrict__ cntcur,
                                                    int* __restrict__ row_start,
                                                    float* __restrict__ invd){
  __shared__ int part[1024];
  const int t = threadIdx.x;
  const int base = t*20;
  int loc[20];
  int sum = 0;
  #pragma unroll
  for (int i=0;i<20;++i){
    int n = base+i;
    int v = (n < NN) ? cntcur[n] : 0;
    loc[i] = sum; sum += v;
  }
  part[t] = sum;
  __syncthreads();
  for (int off=1; off<1024; off<<=1){
    int v = (t >= off) ? part[t-off] : 0;
    __syncthreads();
    part[t] += v;
    __syncthreads();
  }
  int pre = (t > 0) ? part[t-1] : 0;
  #pragma unroll
  for (int i=0;i<20;++i){
    int n = base+i;
    if (n < NN){
      int rs = pre + loc[i];
      int deg = ((i<19)?loc[i+1]:sum) - loc[i];
      row_start[n] = rs;
      invd[n] = (deg > 0) ? 1.f/(float)deg : 0.f;
      cntcur[n] = rs;
    }
  }
  if (t == 1023) row_start[NN] = part[1023];
}

// ---------------- scatter + encoder merged (r11): disjoint block ranges ----------------
// Blocks 0..2499: scatter (128 thr = 128 edges each). Blocks 2500..3749: encoder.
// Both previously serialized in-stream; merging deletes one dispatch gap.
__global__ __launch_bounds__(128) void scatter_encoder_kernel(
    const int* __restrict__ ei, const float* __restrict__ eattr,
    int* __restrict__ cur, int4* __restrict__ rec,
    const float* __restrict__ x, const float* __restrict__ w1, const float* __restrict__ b1,
    const float* __restrict__ w2, const float* __restrict__ b2,
    float* __restrict__ h, _Float16* __restrict__ hh)
{
  __shared__ float xs[16][14];
  __shared__ float s1[16][128];
  const int tid = threadIdx.x;

  if (blockIdx.x < 2500){
    // ---- scatter (r4 logic) ----
    int e = blockIdx.x*128 + tid;       // 2500*128 = 320000 exact
    bool is64 = ei_is64(ei);
    int s = ei_src(ei, e, is64);
    int d = ei_dst(ei, e, is64);
    int pos = atomicAdd(&cur[d], 1);
    int4 r;
    r.x = __float_as_int(eattr[(size_t)e*3+0]);
    r.y = __float_as_int(eattr[(size_t)e*3+1]);
    r.z = __float_as_int(eattr[(size_t)e*3+2]);
    r.w = s*256;   // pre-scaled UV row element-offset
    rec[pos] = r;
    return;
  }

  // ---- encoder (r4 logic) ----
  const int n0 = (blockIdx.x - 2500)*16;
  for (int idx=tid; idx<224; idx+=128){
    int i = idx/14, k = idx%14;
    xs[i][k] = x[(size_t)(n0+i)*14 + k];
  }
  __syncthreads();
  const int o = tid;
  float acc[16];
  float bv = b1[o];
  #pragma unroll
  for (int i=0;i<16;++i) acc[i] = bv;
  for (int k=0;k<14;++k){
    float w = w1[k*128+o];
    #pragma unroll
    for (int i=0;i<16;++i) acc[i] += xs[i][k]*w;
  }
  #pragma unroll
  for (int i=0;i<16;++i) s1[i][o] = silu_f(acc[i]);
  __syncthreads();
  float bv2 = b2[o];
  #pragma unroll
  for (int i=0;i<16;++i) acc[i] = bv2;
  for (int k=0;k<128;k+=4){
    float w0=w2[(k+0)*128+o], w1v=w2[(k+1)*128+o], w2v=w2[(k+2)*128+o], w3v=w2[(k+3)*128+o];
    #pragma unroll
    for (int i=0;i<16;++i){
      float4 sv = *(const float4*)&s1[i][k];
      acc[i] += sv.x*w0 + sv.y*w1v + sv.z*w2v + sv.w*w3v;
    }
  }
  #pragma unroll
  for (int i=0;i<16;++i){
    size_t off = (size_t)(n0+i)*HD + o;
    h[off] = acc[i];
    hh[off] = (_Float16)acc[i];
  }
}

// ---------------- proj (r4 exact: 1250 blocks, 256 thr, 4 cb/wave) ----------------
__global__ __launch_bounds__(256) void proj_kernel(
    const _Float16* __restrict__ hh, const _Float16* __restrict__ w1p,
    const float* __restrict__ b1, _Float16* __restrict__ UV)
{
  const int tid = threadIdx.x;
  const int wv  = tid >> 6;
  const int ln  = tid & 63;
  const int q   = ln >> 4;
  const int m   = ln & 15;
  const int n0  = blockIdx.x*16;      // grid = NN/16 = 1250 exact

  floatx4 acc[4];
  #pragma unroll
  for (int j=0;j<4;++j) acc[j] = (floatx4){0.f,0.f,0.f,0.f};

  #pragma unroll
  for (int ks=0; ks<4; ++ks){
    half8 a = *(const half8*)(hh + (size_t)(n0+m)*HD + ks*32 + q*8);
    const _Float16* wb = w1p + (size_t)(ks*16*64 + ln)*8;
    #pragma unroll
    for (int j=0; j<4; ++j){
      half8 b = *(const half8*)(wb + (size_t)(wv*4+j)*512);
      acc[j] = __builtin_amdgcn_mfma_f32_16x16x32_f16(a, b, acc[j], 0,0,0);
    }
  }
  #pragma unroll
  for (int j=0; j<4; ++j){
    const int c = (wv*4+j)*16 + m;
    const float bias = (c < 128) ? b1[c] : 0.f;
    #pragma unroll
    for (int r=0;r<4;++r)
      UV[(size_t)(n0+q*4+r)*256 + c] = (_Float16)(acc[j][r] + bias);
  }
}

// ---------------- edge_agg (r4 exact — best known, do not touch) ----------------
__device__ __forceinline__ float2v edge_contrib(int4 r, half2v v, float2v u,
                                                float2v wc0, float2v wc1, float2v wc2){
  float2v p = u;
  p += __int_as_float(r.x) * wc0;
  p += __int_as_float(r.y) * wc1;
  p += __int_as_float(r.z) * wc2;
  p[0] += (float)v[0];
  p[1] += (float)v[1];
  float2v s;
  s[0] = silu_f(p[0]);
  s[1] = silu_f(p[1]);
  return s;
}

__global__ __launch_bounds__(256) void edge_agg_kernel(
    const _Float16* __restrict__ UV, const int* __restrict__ row_start,
    const int4* __restrict__ rec,
    const float* __restrict__ w1e, const float* __restrict__ invd,
    _Float16* __restrict__ S)
{
  const int tid = threadIdx.x;
  const int wv  = __builtin_amdgcn_readfirstlane(tid >> 6);
  const int ln  = tid & 63;
  const int n   = blockIdx.x*4 + wv;   // grid NN/4 = 5000 exact
  const int c0  = ln*2;

  const float2v wc0 = *(const float2v*)(w1e +   0 + c0);
  const float2v wc1 = *(const float2v*)(w1e + 128 + c0);
  const float2v wc2 = *(const float2v*)(w1e + 256 + c0);

  half2v uvp = *(const half2v*)(UV + (size_t)n*256 + c0);
  float2v u; u[0] = (float)uvp[0]; u[1] = (float)uvp[1];

  const int rs = row_start[n], re = row_start[n+1];
  float2v a0 = {0.f,0.f}, a1 = {0.f,0.f}, a2 = {0.f,0.f}, a3 = {0.f,0.f};

  const int nq = (re - rs) >> 2;       // full quads
  int e = rs;
  for (int q = 0; q < nq; ++q, e += 4){
    const int4 r0 = rec[e+0];
    const int4 r1 = rec[e+1];
    const int4 r2 = rec[e+2];
    const int4 r3 = rec[e+3];
    const half2v v0 = *(const half2v*)(UV + (size_t)r0.w + 128 + c0);
    const half2v v1 = *(const half2v*)(UV + (size_t)r1.w + 128 + c0);
    const half2v v2 = *(const half2v*)(UV + (size_t)r2.w + 128 + c0);
    const half2v v3 = *(const half2v*)(UV + (size_t)r3.w + 128 + c0);
    a0 += edge_contrib(r0, v0, u, wc0, wc1, wc2);
    a1 += edge_contrib(r1, v1, u, wc0, wc1, wc2);
    a2 += edge_contrib(r2, v2, u, wc0, wc1, wc2);
    a3 += edge_contrib(r3, v3, u, wc0, wc1, wc2);
  }
  if (e < re){                          // remainder 1-3 edges (wave-uniform)
    const int e1 = (e+1 < re) ? e+1 : e;
    const int e2 = (e+2 < re) ? e+2 : e;
    const int4 r0 = rec[e];
    const int4 r1 = rec[e1];
    const int4 r2 = rec[e2];
    const half2v v0 = *(const half2v*)(UV + (size_t)r0.w + 128 + c0);
    const half2v v1 = *(const half2v*)(UV + (size_t)r1.w + 128 + c0);
    const half2v v2 = *(const half2v*)(UV + (size_t)r2.w + 128 + c0);
    a0 += edge_contrib(r0, v0, u, wc0, wc1, wc2);
    if (e+1 < re) a1 += edge_contrib(r1, v1, u, wc0, wc1, wc2);
    if (e+2 < re) a2 += edge_contrib(r2, v2, u, wc0, wc1, wc2);
  }
  float2v a = (a0 + a1) + (a2 + a3);
  const float iv = invd[n];
  half2v outv; outv[0] = (_Float16)(a[0]*iv); outv[1] = (_Float16)(a[1]*iv);
  *(half2v*)(S + (size_t)n*HD + c0) = outv;
}

// ---------------- node_proj (r11): LDS-staged coalesced h RMW; dead hh/h stores dropped ----------------
// Phase 1: MFMA S·W2 -> delta to LDS (fp32). Phase 2: float4-coalesced
// h RMW (replaces 8 scalar loads + 16 scalar stores per thread at fragment
// addressing); hh store removed (dead: proj reads encoder's hh, proj/dec
// phases read LDS hl); h store gated off at l==5 (dead). Phase 3: fused
// proj(l+1) or decoder. dl unions with d1/s2m (disjoint phases) -> 12.9KB LDS.
__global__ __launch_bounds__(256) void node_proj_kernel(
    const _Float16* __restrict__ S, const _Float16* __restrict__ w2p,
    const float* __restrict__ b2, const float* __restrict__ invd,
    float* __restrict__ h,
    const _Float16* __restrict__ w1pn, const float* __restrict__ b1n,
    _Float16* __restrict__ UV, int do_proj,
    const _Float16* __restrict__ w1dp, const float* __restrict__ db1,
    const _Float16* __restrict__ w2dp, const float* __restrict__ db2,
    const float* __restrict__ dw3, const float* __restrict__ db3,
    float* __restrict__ out, int do_dec)
{
  __shared__ _Float16 hl[16][136];
  __shared__ __align__(16) char ubuf[8576];           // dl | (d1 + s2m)
  float    (*dl)[132]  = (float(*)[132])ubuf;         // 16*132*4 = 8448
  _Float16 (*d1)[136]  = (_Float16(*)[136])ubuf;      // 16*136*2 = 4352
  float    (*s2m)[66]  = (float(*)[66])(ubuf + 4352); // 16*66*4  = 4224

  const int tid = threadIdx.x;
  const int wv  = tid >> 6;
  const int ln  = tid & 63;
  const int q   = ln >> 4;
  const int m   = ln & 15;
  const int n0  = blockIdx.x*16;      // grid = NN/16 = 1250 exact

  // ---- phase 1: MFMA S·W2 -> dl ----
  floatx4 acc[2];
  acc[0] = (floatx4){0.f,0.f,0.f,0.f};
  acc[1] = (floatx4){0.f,0.f,0.f,0.f};
  #pragma unroll
  for (int ks=0; ks<4; ++ks){
    half8 a = *(const half8*)(S + (size_t)(n0+m)*HD + ks*32 + q*8);
    const _Float16* wb = w2p + (size_t)(ks*8*64 + ln)*8;
    #pragma unroll
    for (int j=0;j<2;++j){
      half8 b = *(const half8*)(wb + (size_t)(wv*2+j)*512);
      acc[j] = __builtin_amdgcn_mfma_f32_16x16x32_f16(a, b, acc[j], 0,0,0);
    }
  }
  #pragma unroll
  for (int j=0; j<2; ++j){
    const int c = (wv*2+j)*16 + m;
    #pragma unroll
    for (int r=0;r<4;++r) dl[q*4+r][c] = acc[j][r];
  }
  __syncthreads();

  // ---- phase 2: coalesced h RMW; hl fp16 for MFMA phases ----
  {
    const int idx = tid*8;                 // 2048 elements, 8 per thread
    const int row = idx >> 7;
    const int col = idx & 127;
    const float g = (invd[n0 + row] > 0.f) ? 1.f : 0.f;
    float4 h0 = *(const float4*)&h[(size_t)(n0+row)*HD + col];
    float4 h1 = *(const float4*)&h[(size_t)(n0+row)*HD + col + 4];
    float4 b0 = *(const float4*)&b2[col];
    float4 b1v = *(const float4*)&b2[col + 4];
    float4 d0 = *(const float4*)&dl[row][col];
    float4 d1v = *(const float4*)&dl[row][col + 4];
    h0.x += d0.x + g*b0.x;  h0.y += d0.y + g*b0.y;
    h0.z += d0.z + g*b0.z;  h0.w += d0.w + g*b0.w;
    h1.x += d1v.x + g*b1v.x; h1.y += d1v.y + g*b1v.y;
    h1.z += d1v.z + g*b1v.z; h1.w += d1v.w + g*b1v.w;
    if (!do_dec){           // h dead after last layer
      *(float4*)&h[(size_t)(n0+row)*HD + col]     = h0;
      *(float4*)&h[(size_t)(n0+row)*HD + col + 4] = h1;
    }
    half4 p0, p1;
    p0[0]=(_Float16)h0.x; p0[1]=(_Float16)h0.y; p0[2]=(_Float16)h0.z; p0[3]=(_Float16)h0.w;
    p1[0]=(_Float16)h1.x; p1[1]=(_Float16)h1.y; p1[2]=(_Float16)h1.z; p1[3]=(_Float16)h1.w;
    *(half4*)&hl[row][col]     = p0;
    *(half4*)&hl[row][col + 4] = p1;
  }
  __syncthreads();

  // ---- phase 3a: fused proj(l+1) ----
  if (do_proj){
    floatx4 acc2[4];
    #pragma unroll
    for (int j=0;j<4;++j) acc2[j] = (floatx4){0.f,0.f,0.f,0.f};
    #pragma unroll
    for (int ks=0; ks<4; ++ks){
      half8 a = *(const half8*)&hl[m][ks*32 + q*8];
      const _Float16* wb = w1pn + (size_t)(ks*16*64 + ln)*8;
      #pragma unroll
      for (int j=0; j<4; ++j){
        half8 b = *(const half8*)(wb + (size_t)(wv*4+j)*512);
        acc2[j] = __builtin_amdgcn_mfma_f32_16x16x32_f16(a, b, acc2[j], 0,0,0);
      }
    }
    #pragma unroll
    for (int j=0; j<4; ++j){
      const int c = (wv*4+j)*16 + m;
      const float bias = (c < 128) ? b1n[c] : 0.f;
      #pragma unroll
      for (int r=0;r<4;++r)
        UV[(size_t)(n0+q*4+r)*256 + c] = (_Float16)(acc2[j][r] + bias);
    }
  }

  // ---- phase 3b: fused decoder (l==5) ----
  if (do_dec){
    floatx4 acc1[2];
    acc1[0] = (floatx4){0.f,0.f,0.f,0.f};
    acc1[1] = (floatx4){0.f,0.f,0.f,0.f};
    #pragma unroll
    for (int ks=0; ks<4; ++ks){
      half8 a = *(const half8*)&hl[m][ks*32 + q*8];
      const _Float16* wb = w1dp + (size_t)(ks*8*64 + ln)*8;
      #pragma unroll
      for (int j=0; j<2; ++j){
        half8 b = *(const half8*)(wb + (size_t)(wv*2+j)*512);
        acc1[j] = __builtin_amdgcn_mfma_f32_16x16x32_f16(a, b, acc1[j], 0,0,0);
      }
    }
    __syncthreads();            // dl reads done (phase 2); d1 aliases dl
    #pragma unroll
    for (int j=0; j<2; ++j){
      const int c = (wv*2+j)*16 + m;
      const float bv = db1[c];
      #pragma unroll
      for (int r=0;r<4;++r)
        d1[q*4+r][c] = (_Float16)silu_f(acc1[j][r] + bv);
    }
    __syncthreads();

    floatx4 acc2 = (floatx4){0.f,0.f,0.f,0.f};
    #pragma unroll
    for (int ks=0; ks<4; ++ks){
      half8 a = *(const half8*)&d1[m][ks*32 + q*8];
      const _Float16* wb = w2dp + (size_t)(ks*4*64 + ln)*8;
      half8 b = *(const half8*)(wb + (size_t)wv*512);
      acc2 = __builtin_amdgcn_mfma_f32_16x16x32_f16(a, b, acc2, 0,0,0);
    }
    {
      const int c = wv*16 + m;
      const float bv = db2[c];
      #pragma unroll
      for (int r=0;r<4;++r)
        s2m[q*4+r][c] = silu_f(acc2[r] + bv);
    }
    __syncthreads();

    if (tid < 144){
      int i = tid/9, oo = tid%9;
      float a = db3[oo];
      #pragma unroll 8
      for (int k=0;k<64;++k) a += s2m[i][k]*dw3[k*9+oo];
      out[(size_t)(n0+i)*9 + oo] = a;
    }
  }
}

// ---------------- workspace layout (36,719,040 B — r4 exact) ----------------
constexpr size_t OFF_H    = 0;                         // 10,240,000
constexpr size_t OFF_HH   = 10240000;                  //  5,120,000
constexpr size_t OFF_UV   = 15360000;                  // 10,240,000
constexpr size_t OFF_S    = 25600000;                  //  5,120,000 (fp16)
constexpr size_t OFF_INVD = 30720000;                  //     80,000
constexpr size_t OFF_RS   = 30800000;                  //     80,064
constexpr size_t OFF_CUR  = 30880064;                  //     80,000
constexpr size_t OFF_REC  = 30960064;                  //  5,120,000 (int4/edge)
constexpr size_t OFF_W1P  = 36080064;                  //    393,216
constexpr size_t OFF_W2P  = 36473280;                  //    196,608
constexpr size_t OFF_DW1P = 36669888;                  //     32,768
constexpr size_t OFF_DW2P = 36702656;                  //     16,384
constexpr size_t WS_NEEDED= 36719040;

extern "C" void kernel_launch(void* const* d_in, const int* in_sizes, int n_in,
                              void* d_out, int out_size, void* d_ws, size_t ws_size,
                              hipStream_t stream)
{
  float* out = (float*)d_out;
  const int nout_blk = (out_size + 255)/256;

  static const int EXP_SIZES[17] = {280000,640000,960000,1792,128,16384,128,
                                    198912,768,98304,768,16384,128,8192,64,576,9};
  if (n_in != 17){
    sentinel_kernel<<<nout_blk, 256, 0, stream>>>(out, out_size, 2.0e7f + (float)n_in*1.0e3f);
    return;
  }
  for (int i = 0; i < 17; ++i){
    if (in_sizes[i] != EXP_SIZES[i]){
      int sz = in_sizes[i] < 99999 ? in_sizes[i] : 99999;
      sentinel_kernel<<<nout_blk, 256, 0, stream>>>(out, out_size,
          1.0e7f + (float)i*1.0e5f + (float)sz);
      return;
    }
  }
  if (ws_size < WS_NEEDED){
    sentinel_kernel<<<nout_blk, 256, 0, stream>>>(out, out_size, 1.0e6f);
    return;
  }

  const float* x       = (const float*)d_in[0];
  const int*   ei      = (const int*)  d_in[1];
  const float* eattr   = (const float*)d_in[2];
  const float* enc_w1  = (const float*)d_in[3];
  const float* enc_b1  = (const float*)d_in[4];
  const float* enc_w2  = (const float*)d_in[5];
  const float* enc_b2  = (const float*)d_in[6];
  const float* conv_w1 = (const float*)d_in[7];
  const float* conv_b1 = (const float*)d_in[8];
  const float* conv_w2 = (const float*)d_in[9];
  const float* conv_b2 = (const float*)d_in[10];
  const float* dec_w1  = (const float*)d_in[11];
  const float* dec_b1  = (const float*)d_in[12];
  const float* dec_w2  = (const float*)d_in[13];
  const float* dec_b2  = (const float*)d_in[14];
  const float* dec_w3  = (const float*)d_in[15];
  const float* dec_b3  = (const float*)d_in[16];

  char* ws = (char*)d_ws;
  float*    h     = (float*)   (ws + OFF_H);
  _Float16* hh    = (_Float16*)(ws + OFF_HH);
  _Float16* UV    = (_Float16*)(ws + OFF_UV);
  _Float16* S     = (_Float16*)(ws + OFF_S);
  float*    invd  = (float*)   (ws + OFF_INVD);
  int*      rstart= (int*)     (ws + OFF_RS);
  int*      cur   = (int*)     (ws + OFF_CUR);
  int4*     rec   = (int4*)    (ws + OFF_REC);
  _Float16* w1p   = (_Float16*)(ws + OFF_W1P);
  _Float16* w2p   = (_Float16*)(ws + OFF_W2P);
  _Float16* w1dp  = (_Float16*)(ws + OFF_DW1P);
  _Float16* w2dp  = (_Float16*)(ws + OFF_DW2P);

  pack_all_kernel<<<1327, 256, 0, stream>>>(conv_w1, conv_w2, dec_w1, dec_w2,
                                            w1p, w2p, w1dp, w2dp, cur);
  count_kernel<<<EE/256, 256, 0, stream>>>(ei, cur);
  scan_kernel<<<1, 1024, 0, stream>>>(cur, rstart, invd);
  scatter_encoder_kernel<<<3750, 128, 0, stream>>>(ei, eattr, cur, rec,
                                                   x, enc_w1, enc_b1, enc_w2, enc_b2,
                                                   h, hh);
  proj_kernel<<<NN/16, 256, 0, stream>>>(hh, w1p, conv_b1, UV);   // layer 0 proj
  for (int l=0; l<6; ++l){
    edge_agg_kernel<<<NN/4, 256, 0, stream>>>(UV, rstart, rec,
                                              conv_w1 + (size_t)l*33152 + 32768,
                                              invd, S);
    const int lp = (l < 5) ? l+1 : 0;   // dummy valid ptrs for last layer
    node_proj_kernel<<<NN/16, 256, 0, stream>>>(S, w2p + (size_t)l*16384,
                                                conv_b2 + (size_t)l*128, invd, h,
                                                w1p + (size_t)lp*32768,
                                                conv_b1 + (size_t)lp*128,
                                                UV, (l < 5) ? 1 : 0,
                                                w1dp, dec_b1, w2dp, dec_b2,
                                                dec_w3, dec_b3, out,
                                                (l == 5) ? 1 : 0);
  }
}

// Round 12
// 372.371 us; speedup vs baseline: 1.1778x; 1.0464x over previous
//
#include <hip/hip_runtime.h>
#include <hip/hip_bf16.h>

#define NN 20000
#define EE 320000
#define HD 128   // hidden

typedef _Float16 half8 __attribute__((ext_vector_type(8)));
typedef _Float16 half4 __attribute__((ext_vector_type(4)));
typedef _Float16 half2v __attribute__((ext_vector_type(2)));
typedef float floatx4 __attribute__((ext_vector_type(4)));
typedef float float2v __attribute__((ext_vector_type(2)));

// silu via HW rcp (1-ulp) instead of exact fp32 divide.
__device__ __forceinline__ float silu_f(float x){
  float e = __expf(-x);
  return x * __builtin_amdgcn_rcpf(1.f + e);
}

__device__ __forceinline__ bool ei_is64(const int* __restrict__ ei){
  return (ei[1] | ei[3] | ei[5] | ei[7]) == 0;
}
__device__ __forceinline__ int ei_src(const int* __restrict__ ei, int e, bool is64){
  return is64 ? ei[2*(size_t)e] : ei[e];
}
__device__ __forceinline__ int ei_dst(const int* __restrict__ ei, int e, bool is64){
  return is64 ? ei[2*(size_t)EE + 2*(size_t)e] : ei[EE + e];
}

__global__ __launch_bounds__(256) void sentinel_kernel(float* __restrict__ out, int n, float val){
  int i = blockIdx.x*256 + threadIdx.x;
  if (i < n) out[i] = val;
}

// ---------------- merged weight packing + cur zeroing (r9 — kept) ----------------
__global__ __launch_bounds__(256) void pack_all_kernel(const float* __restrict__ cw1,
                                                       const float* __restrict__ cw2,
                                                       const float* __restrict__ dw1,
                                                       const float* __restrict__ dw2,
                                                       _Float16* __restrict__ w1p,
                                                       _Float16* __restrict__ w2p,
                                                       _Float16* __restrict__ w1dp,
                                                       _Float16* __restrict__ w2dp,
                                                       int* __restrict__ cur){
  int idx = blockIdx.x*256 + threadIdx.x;
  if (idx >= 319488){
    int j = idx - 319488;
    if (j < NN) cur[j] = 0;
    return;
  }
  if (idx < 196608){
    int j   = idx & 7;
    int ln  = (idx >> 3) & 63;
    int rest= idx >> 9;
    int cb  = rest & 15;
    int rest2 = rest >> 4;
    int ks  = rest2 & 3;
    int l   = rest2 >> 2;
    int k = ks*32 + (ln>>4)*8 + j;
    int c = cb*16 + (ln&15);
    float v = (c < 128) ? cw1[(size_t)l*33152 + (size_t)k*128 + c]
                        : cw1[(size_t)l*33152 + (size_t)(128+k)*128 + (c-128)];
    w1p[idx] = (_Float16)v;
  } else if (idx < 294912){
    int t = idx - 196608;
    int j   = t & 7;
    int ln  = (t >> 3) & 63;
    int rest= t >> 9;
    int cb  = rest & 7;
    int rest2 = rest >> 3;
    int ks  = rest2 & 3;
    int l   = rest2 >> 2;
    int k = ks*32 + (ln>>4)*8 + j;
    int c = cb*16 + (ln&15);
    w2p[t] = (_Float16)cw2[(size_t)l*16384 + (size_t)k*128 + c];
  } else {
    int t2 = idx - 294912;
    if (t2 < 16384){
      int j = t2 & 7, ln = (t2>>3)&63, cb = (t2>>9)&7, ks = t2>>12;
      int k = ks*32 + (ln>>4)*8 + j;
      int c = cb*16 + (ln&15);
      w1dp[t2] = (_Float16)dw1[(size_t)k*128 + c];
    } else {
      int t = t2 - 16384;
      int j = t & 7, ln = (t>>3)&63, cb = (t>>9)&3, ks = t>>11;
      int k = ks*32 + (ln>>4)*8 + j;
      int c = cb*16 + (ln&15);
      w2dp[t] = (_Float16)dw2[(size_t)k*64 + c];
    }
  }
}

// ---------------- CSR build ----------------
// r12: count also records each edge's rank within its dst bucket (the value
// the atomicAdd returns — previously discarded). Coalesced 4B stream. This
// makes the later scatter atomic-free and dependency-free.
__global__ __launch_bounds__(256) void count_kernel(const int* __restrict__ ei,
                                                    int* __restrict__ cnt,
                                                    int* __restrict__ rank){
  int e = blockIdx.x*256 + threadIdx.x;   // EE/256 exact
  bool is64 = ei_is64(ei);
  rank[e] = atomicAdd(&cnt[ei_dst(ei, e, is64)], 1);
}

__global__ __launch_bounds__(1024) void scan_kernel(const int* __restrict__ cntcur,
                                                    int* __restrict__ row_start,
                                                    float* __restrict__ invd){
  __shared__ int part[1024];
  const int t = threadIdx.x;
  const int base = t*20;
  int loc[20];
  int sum = 0;
  #pragma unroll
  for (int i=0;i<20;++i){
    int n = base+i;
    int v = (n < NN) ? cntcur[n] : 0;
    loc[i] = sum; sum += v;
  }
  part[t] = sum;
  __syncthreads();
  for (int off=1; off<1024; off<<=1){
    int v = (t >= off) ? part[t-off] : 0;
    __syncthreads();
    part[t] += v;
    __syncthreads();
  }
  int pre = (t > 0) ? part[t-1] : 0;
  #pragma unroll
  for (int i=0;i<20;++i){
    int n = base+i;
    if (n < NN){
      int rs = pre + loc[i];
      int deg = ((i<19)?loc[i+1]:sum) - loc[i];
      row_start[n] = rs;
      invd[n] = (deg > 0) ? 1.f/(float)deg : 0.f;
    }
  }
  if (t == 1023) row_start[NN] = part[1023];
}

// ---------------- scatter + encoder merged (r11 structure; r12 atomic-free scatter) ----------------
// Blocks 0..2499: scatter — pos = row_start[d] + rank[e]; no atomic, no
// return-value dependency; the scattered rec store is fire-and-forget and
// finishes under the encoder blocks' shadow. Blocks 2500..3749: encoder.
__global__ __launch_bounds__(128) void scatter_encoder_kernel(
    const int* __restrict__ ei, const float* __restrict__ eattr,
    const int* __restrict__ rstart, const int* __restrict__ rank,
    int4* __restrict__ rec,
    const float* __restrict__ x, const float* __restrict__ w1, const float* __restrict__ b1,
    const float* __restrict__ w2, const float* __restrict__ b2,
    float* __restrict__ h, _Float16* __restrict__ hh)
{
  __shared__ float xs[16][14];
  __shared__ float s1[16][128];
  const int tid = threadIdx.x;

  if (blockIdx.x < 2500){
    // ---- scatter (atomic-free) ----
    int e = blockIdx.x*128 + tid;       // 2500*128 = 320000 exact
    bool is64 = ei_is64(ei);
    int s = ei_src(ei, e, is64);
    int d = ei_dst(ei, e, is64);
    int pos = rstart[d] + rank[e];
    int4 r;
    r.x = __float_as_int(eattr[(size_t)e*3+0]);
    r.y = __float_as_int(eattr[(size_t)e*3+1]);
    r.z = __float_as_int(eattr[(size_t)e*3+2]);
    r.w = s*256;   // pre-scaled UV row element-offset
    rec[pos] = r;
    return;
  }

  // ---- encoder (r4 logic) ----
  const int n0 = (blockIdx.x - 2500)*16;
  for (int idx=tid; idx<224; idx+=128){
    int i = idx/14, k = idx%14;
    xs[i][k] = x[(size_t)(n0+i)*14 + k];
  }
  __syncthreads();
  const int o = tid;
  float acc[16];
  float bv = b1[o];
  #pragma unroll
  for (int i=0;i<16;++i) acc[i] = bv;
  for (int k=0;k<14;++k){
    float w = w1[k*128+o];
    #pragma unroll
    for (int i=0;i<16;++i) acc[i] += xs[i][k]*w;
  }
  #pragma unroll
  for (int i=0;i<16;++i) s1[i][o] = silu_f(acc[i]);
  __syncthreads();
  float bv2 = b2[o];
  #pragma unroll
  for (int i=0;i<16;++i) acc[i] = bv2;
  for (int k=0;k<128;k+=4){
    float w0=w2[(k+0)*128+o], w1v=w2[(k+1)*128+o], w2v=w2[(k+2)*128+o], w3v=w2[(k+3)*128+o];
    #pragma unroll
    for (int i=0;i<16;++i){
      float4 sv = *(const float4*)&s1[i][k];
      acc[i] += sv.x*w0 + sv.y*w1v + sv.z*w2v + sv.w*w3v;
    }
  }
  #pragma unroll
  for (int i=0;i<16;++i){
    size_t off = (size_t)(n0+i)*HD + o;
    h[off] = acc[i];
    hh[off] = (_Float16)acc[i];
  }
}

// ---------------- proj (r4 exact: 1250 blocks, 256 thr, 4 cb/wave) ----------------
__global__ __launch_bounds__(256) void proj_kernel(
    const _Float16* __restrict__ hh, const _Float16* __restrict__ w1p,
    const float* __restrict__ b1, _Float16* __restrict__ UV)
{
  const int tid = threadIdx.x;
  const int wv  = tid >> 6;
  const int ln  = tid & 63;
  const int q   = ln >> 4;
  const int m   = ln & 15;
  const int n0  = blockIdx.x*16;      // grid = NN/16 = 1250 exact

  floatx4 acc[4];
  #pragma unroll
  for (int j=0;j<4;++j) acc[j] = (floatx4){0.f,0.f,0.f,0.f};

  #pragma unroll
  for (int ks=0; ks<4; ++ks){
    half8 a = *(const half8*)(hh + (size_t)(n0+m)*HD + ks*32 + q*8);
    const _Float16* wb = w1p + (size_t)(ks*16*64 + ln)*8;
    #pragma unroll
    for (int j=0; j<4; ++j){
      half8 b = *(const half8*)(wb + (size_t)(wv*4+j)*512);
      acc[j] = __builtin_amdgcn_mfma_f32_16x16x32_f16(a, b, acc[j], 0,0,0);
    }
  }
  #pragma unroll
  for (int j=0; j<4; ++j){
    const int c = (wv*4+j)*16 + m;
    const float bias = (c < 128) ? b1[c] : 0.f;
    #pragma unroll
    for (int r=0;r<4;++r)
      UV[(size_t)(n0+q*4+r)*256 + c] = (_Float16)(acc[j][r] + bias);
  }
}

// ---------------- edge_agg (r4 exact — best known, do not touch) ----------------
__device__ __forceinline__ float2v edge_contrib(int4 r, half2v v, float2v u,
                                                float2v wc0, float2v wc1, float2v wc2){
  float2v p = u;
  p += __int_as_float(r.x) * wc0;
  p += __int_as_float(r.y) * wc1;
  p += __int_as_float(r.z) * wc2;
  p[0] += (float)v[0];
  p[1] += (float)v[1];
  float2v s;
  s[0] = silu_f(p[0]);
  s[1] = silu_f(p[1]);
  return s;
}

__global__ __launch_bounds__(256) void edge_agg_kernel(
    const _Float16* __restrict__ UV, const int* __restrict__ row_start,
    const int4* __restrict__ rec,
    const float* __restrict__ w1e, const float* __restrict__ invd,
    _Float16* __restrict__ S)
{
  const int tid = threadIdx.x;
  const int wv  = __builtin_amdgcn_readfirstlane(tid >> 6);
  const int ln  = tid & 63;
  const int n   = blockIdx.x*4 + wv;   // grid NN/4 = 5000 exact
  const int c0  = ln*2;

  const float2v wc0 = *(const float2v*)(w1e +   0 + c0);
  const float2v wc1 = *(const float2v*)(w1e + 128 + c0);
  const float2v wc2 = *(const float2v*)(w1e + 256 + c0);

  half2v uvp = *(const half2v*)(UV + (size_t)n*256 + c0);
  float2v u; u[0] = (float)uvp[0]; u[1] = (float)uvp[1];

  const int rs = row_start[n], re = row_start[n+1];
  float2v a0 = {0.f,0.f}, a1 = {0.f,0.f}, a2 = {0.f,0.f}, a3 = {0.f,0.f};

  const int nq = (re - rs) >> 2;       // full quads
  int e = rs;
  for (int q = 0; q < nq; ++q, e += 4){
    const int4 r0 = rec[e+0];
    const int4 r1 = rec[e+1];
    const int4 r2 = rec[e+2];
    const int4 r3 = rec[e+3];
    const half2v v0 = *(const half2v*)(UV + (size_t)r0.w + 128 + c0);
    const half2v v1 = *(const half2v*)(UV + (size_t)r1.w + 128 + c0);
    const half2v v2 = *(const half2v*)(UV + (size_t)r2.w + 128 + c0);
    const half2v v3 = *(const half2v*)(UV + (size_t)r3.w + 128 + c0);
    a0 += edge_contrib(r0, v0, u, wc0, wc1, wc2);
    a1 += edge_contrib(r1, v1, u, wc0, wc1, wc2);
    a2 += edge_contrib(r2, v2, u, wc0, wc1, wc2);
    a3 += edge_contrib(r3, v3, u, wc0, wc1, wc2);
  }
  if (e < re){                          // remainder 1-3 edges (wave-uniform)
    const int e1 = (e+1 < re) ? e+1 : e;
    const int e2 = (e+2 < re) ? e+2 : e;
    const int4 r0 = rec[e];
    const int4 r1 = rec[e1];
    const int4 r2 = rec[e2];
    const half2v v0 = *(const half2v*)(UV + (size_t)r0.w + 128 + c0);
    const half2v v1 = *(const half2v*)(UV + (size_t)r1.w + 128 + c0);
    const half2v v2 = *(const half2v*)(UV + (size_t)r2.w + 128 + c0);
    a0 += edge_contrib(r0, v0, u, wc0, wc1, wc2);
    if (e+1 < re) a1 += edge_contrib(r1, v1, u, wc0, wc1, wc2);
    if (e+2 < re) a2 += edge_contrib(r2, v2, u, wc0, wc1, wc2);
  }
  float2v a = (a0 + a1) + (a2 + a3);
  const float iv = invd[n];
  half2v outv; outv[0] = (_Float16)(a[0]*iv); outv[1] = (_Float16)(a[1]*iv);
  *(half2v*)(S + (size_t)n*HD + c0) = outv;
}

// ---------------- node_proj (r11 exact): LDS-staged coalesced h RMW ----------------
__global__ __launch_bounds__(256) void node_proj_kernel(
    const _Float16* __restrict__ S, const _Float16* __restrict__ w2p,
    const float* __restrict__ b2, const float* __restrict__ invd,
    float* __restrict__ h,
    const _Float16* __restrict__ w1pn, const float* __restrict__ b1n,
    _Float16* __restrict__ UV, int do_proj,
    const _Float16* __restrict__ w1dp, const float* __restrict__ db1,
    const _Float16* __restrict__ w2dp, const float* __restrict__ db2,
    const float* __restrict__ dw3, const float* __restrict__ db3,
    float* __restrict__ out, int do_dec)
{
  __shared__ _Float16 hl[16][136];
  __shared__ __align__(16) char ubuf[8576];           // dl | (d1 + s2m)
  float    (*dl)[132]  = (float(*)[132])ubuf;         // 16*132*4 = 8448
  _Float16 (*d1)[136]  = (_Float16(*)[136])ubuf;      // 16*136*2 = 4352
  float    (*s2m)[66]  = (float(*)[66])(ubuf + 4352); // 16*66*4  = 4224

  const int tid = threadIdx.x;
  const int wv  = tid >> 6;
  const int ln  = tid & 63;
  const int q   = ln >> 4;
  const int m   = ln & 15;
  const int n0  = blockIdx.x*16;      // grid = NN/16 = 1250 exact

  // ---- phase 1: MFMA S·W2 -> dl ----
  floatx4 acc[2];
  acc[0] = (floatx4){0.f,0.f,0.f,0.f};
  acc[1] = (floatx4){0.f,0.f,0.f,0.f};
  #pragma unroll
  for (int ks=0; ks<4; ++ks){
    half8 a = *(const half8*)(S + (size_t)(n0+m)*HD + ks*32 + q*8);
    const _Float16* wb = w2p + (size_t)(ks*8*64 + ln)*8;
    #pragma unroll
    for (int j=0;j<2;++j){
      half8 b = *(const half8*)(wb + (size_t)(wv*2+j)*512);
      acc[j] = __builtin_amdgcn_mfma_f32_16x16x32_f16(a, b, acc[j], 0,0,0);
    }
  }
  #pragma unroll
  for (int j=0; j<2; ++j){
    const int c = (wv*2+j)*16 + m;
    #pragma unroll
    for (int r=0;r<4;++r) dl[q*4+r][c] = acc[j][r];
  }
  __syncthreads();

  // ---- phase 2: coalesced h RMW; hl fp16 for MFMA phases ----
  {
    const int idx = tid*8;                 // 2048 elements, 8 per thread
    const int row = idx >> 7;
    const int col = idx & 127;
    const float g = (invd[n0 + row] > 0.f) ? 1.f : 0.f;
    float4 h0 = *(const float4*)&h[(size_t)(n0+row)*HD + col];
    float4 h1 = *(const float4*)&h[(size_t)(n0+row)*HD + col + 4];
    float4 b0 = *(const float4*)&b2[col];
    float4 b1v = *(const float4*)&b2[col + 4];
    float4 d0 = *(const float4*)&dl[row][col];
    float4 d1v = *(const float4*)&dl[row][col + 4];
    h0.x += d0.x + g*b0.x;  h0.y += d0.y + g*b0.y;
    h0.z += d0.z + g*b0.z;  h0.w += d0.w + g*b0.w;
    h1.x += d1v.x + g*b1v.x; h1.y += d1v.y + g*b1v.y;
    h1.z += d1v.z + g*b1v.z; h1.w += d1v.w + g*b1v.w;
    if (!do_dec){           // h dead after last layer
      *(float4*)&h[(size_t)(n0+row)*HD + col]     = h0;
      *(float4*)&h[(size_t)(n0+row)*HD + col + 4] = h1;
    }
    half4 p0, p1;
    p0[0]=(_Float16)h0.x; p0[1]=(_Float16)h0.y; p0[2]=(_Float16)h0.z; p0[3]=(_Float16)h0.w;
    p1[0]=(_Float16)h1.x; p1[1]=(_Float16)h1.y; p1[2]=(_Float16)h1.z; p1[3]=(_Float16)h1.w;
    *(half4*)&hl[row][col]     = p0;
    *(half4*)&hl[row][col + 4] = p1;
  }
  __syncthreads();

  // ---- phase 3a: fused proj(l+1) ----
  if (do_proj){
    floatx4 acc2[4];
    #pragma unroll
    for (int j=0;j<4;++j) acc2[j] = (floatx4){0.f,0.f,0.f,0.f};
    #pragma unroll
    for (int ks=0; ks<4; ++ks){
      half8 a = *(const half8*)&hl[m][ks*32 + q*8];
      const _Float16* wb = w1pn + (size_t)(ks*16*64 + ln)*8;
      #pragma unroll
      for (int j=0; j<4; ++j){
        half8 b = *(const half8*)(wb + (size_t)(wv*4+j)*512);
        acc2[j] = __builtin_amdgcn_mfma_f32_16x16x32_f16(a, b, acc2[j], 0,0,0);
      }
    }
    #pragma unroll
    for (int j=0; j<4; ++j){
      const int c = (wv*4+j)*16 + m;
      const float bias = (c < 128) ? b1n[c] : 0.f;
      #pragma unroll
      for (int r=0;r<4;++r)
        UV[(size_t)(n0+q*4+r)*256 + c] = (_Float16)(acc2[j][r] + bias);
    }
  }

  // ---- phase 3b: fused decoder (l==5) ----
  if (do_dec){
    floatx4 acc1[2];
    acc1[0] = (floatx4){0.f,0.f,0.f,0.f};
    acc1[1] = (floatx4){0.f,0.f,0.f,0.f};
    #pragma unroll
    for (int ks=0; ks<4; ++ks){
      half8 a = *(const half8*)&hl[m][ks*32 + q*8];
      const _Float16* wb = w1dp + (size_t)(ks*8*64 + ln)*8;
      #pragma unroll
      for (int j=0; j<2; ++j){
        half8 b = *(const half8*)(wb + (size_t)(wv*2+j)*512);
        acc1[j] = __builtin_amdgcn_mfma_f32_16x16x32_f16(a, b, acc1[j], 0,0,0);
      }
    }
    __syncthreads();            // dl reads done (phase 2); d1 aliases dl
    #pragma unroll
    for (int j=0; j<2; ++j){
      const int c = (wv*2+j)*16 + m;
      const float bv = db1[c];
      #pragma unroll
      for (int r=0;r<4;++r)
        d1[q*4+r][c] = (_Float16)silu_f(acc1[j][r] + bv);
    }
    __syncthreads();

    floatx4 acc2 = (floatx4){0.f,0.f,0.f,0.f};
    #pragma unroll
    for (int ks=0; ks<4; ++ks){
      half8 a = *(const half8*)&d1[m][ks*32 + q*8];
      const _Float16* wb = w2dp + (size_t)(ks*4*64 + ln)*8;
      half8 b = *(const half8*)(wb + (size_t)wv*512);
      acc2 = __builtin_amdgcn_mfma_f32_16x16x32_f16(a, b, acc2, 0,0,0);
    }
    {
      const int c = wv*16 + m;
      const float bv = db2[c];
      #pragma unroll
      for (int r=0;r<4;++r)
        s2m[q*4+r][c] = silu_f(acc2[r] + bv);
    }
    __syncthreads();

    if (tid < 144){
      int i = tid/9, oo = tid%9;
      float a = db3[oo];
      #pragma unroll 8
      for (int k=0;k<64;++k) a += s2m[i][k]*dw3[k*9+oo];
      out[(size_t)(n0+i)*9 + oo] = a;
    }
  }
}

// ---------------- workspace layout (37,999,040 B) ----------------
constexpr size_t OFF_H    = 0;                         // 10,240,000
constexpr size_t OFF_HH   = 10240000;                  //  5,120,000
constexpr size_t OFF_UV   = 15360000;                  // 10,240,000
constexpr size_t OFF_S    = 25600000;                  //  5,120,000 (fp16)
constexpr size_t OFF_INVD = 30720000;                  //     80,000
constexpr size_t OFF_RS   = 30800000;                  //     80,064
constexpr size_t OFF_CUR  = 30880064;                  //     80,000
constexpr size_t OFF_REC  = 30960064;                  //  5,120,000 (int4/edge)
constexpr size_t OFF_RANK = 36080064;                  //  1,280,000 (int/edge)
constexpr size_t OFF_W1P  = 37360064;                  //    393,216
constexpr size_t OFF_W2P  = 37753280;                  //    196,608
constexpr size_t OFF_DW1P = 37949888;                  //     32,768
constexpr size_t OFF_DW2P = 37982656;                  //     16,384
constexpr size_t WS_NEEDED= 37999040;

extern "C" void kernel_launch(void* const* d_in, const int* in_sizes, int n_in,
                              void* d_out, int out_size, void* d_ws, size_t ws_size,
                              hipStream_t stream)
{
  float* out = (float*)d_out;
  const int nout_blk = (out_size + 255)/256;

  static const int EXP_SIZES[17] = {280000,640000,960000,1792,128,16384,128,
                                    198912,768,98304,768,16384,128,8192,64,576,9};
  if (n_in != 17){
    sentinel_kernel<<<nout_blk, 256, 0, stream>>>(out, out_size, 2.0e7f + (float)n_in*1.0e3f);
    return;
  }
  for (int i = 0; i < 17; ++i){
    if (in_sizes[i] != EXP_SIZES[i]){
      int sz = in_sizes[i] < 99999 ? in_sizes[i] : 99999;
      sentinel_kernel<<<nout_blk, 256, 0, stream>>>(out, out_size,
          1.0e7f + (float)i*1.0e5f + (float)sz);
      return;
    }
  }
  if (ws_size < WS_NEEDED){
    sentinel_kernel<<<nout_blk, 256, 0, stream>>>(out, out_size, 1.0e6f);
    return;
  }

  const float* x       = (const float*)d_in[0];
  const int*   ei      = (const int*)  d_in[1];
  const float* eattr   = (const float*)d_in[2];
  const float* enc_w1  = (const float*)d_in[3];
  const float* enc_b1  = (const float*)d_in[4];
  const float* enc_w2  = (const float*)d_in[5];
  const float* enc_b2  = (const float*)d_in[6];
  const float* conv_w1 = (const float*)d_in[7];
  const float* conv_b1 = (const float*)d_in[8];
  const float* conv_w2 = (const float*)d_in[9];
  const float* conv_b2 = (const float*)d_in[10];
  const float* dec_w1  = (const float*)d_in[11];
  const float* dec_b1  = (const float*)d_in[12];
  const float* dec_w2  = (const float*)d_in[13];
  const float* dec_b2  = (const float*)d_in[14];
  const float* dec_w3  = (const float*)d_in[15];
  const float* dec_b3  = (const float*)d_in[16];

  char* ws = (char*)d_ws;
  float*    h     = (float*)   (ws + OFF_H);
  _Float16* hh    = (_Float16*)(ws + OFF_HH);
  _Float16* UV    = (_Float16*)(ws + OFF_UV);
  _Float16* S     = (_Float16*)(ws + OFF_S);
  float*    invd  = (float*)   (ws + OFF_INVD);
  int*      rstart= (int*)     (ws + OFF_RS);
  int*      cur   = (int*)     (ws + OFF_CUR);
  int4*     rec   = (int4*)    (ws + OFF_REC);
  int*      rank  = (int*)     (ws + OFF_RANK);
  _Float16* w1p   = (_Float16*)(ws + OFF_W1P);
  _Float16* w2p   = (_Float16*)(ws + OFF_W2P);
  _Float16* w1dp  = (_Float16*)(ws + OFF_DW1P);
  _Float16* w2dp  = (_Float16*)(ws + OFF_DW2P);

  pack_all_kernel<<<1327, 256, 0, stream>>>(conv_w1, conv_w2, dec_w1, dec_w2,
                                            w1p, w2p, w1dp, w2dp, cur);
  count_kernel<<<EE/256, 256, 0, stream>>>(ei, cur, rank);
  scan_kernel<<<1, 1024, 0, stream>>>(cur, rstart, invd);
  scatter_encoder_kernel<<<3750, 128, 0, stream>>>(ei, eattr, rstart, rank, rec,
                                                   x, enc_w1, enc_b1, enc_w2, enc_b2,
                                                   h, hh);
  proj_kernel<<<NN/16, 256, 0, stream>>>(hh, w1p, conv_b1, UV);   // layer 0 proj
  for (int l=0; l<6; ++l){
    edge_agg_kernel<<<NN/4, 256, 0, stream>>>(UV, rstart, rec,
                                              conv_w1 + (size_t)l*33152 + 32768,
                                              invd, S);
    const int lp = (l < 5) ? l+1 : 0;   // dummy valid ptrs for last layer
    node_proj_kernel<<<NN/16, 256, 0, stream>>>(S, w2p + (size_t)l*16384,
                                                conv_b2 + (size_t)l*128, invd, h,
                                                w1p + (size_t)lp*32768,
                                                conv_b1 + (size_t)lp*128,
                                                UV, (l < 5) ? 1 : 0,
                                                w1dp, dec_b1, w2dp, dec_b2,
                                                dec_w3, dec_b3, out,
                                                (l == 5) ? 1 : 0);
  }
}

// Round 13
// 330.534 us; speedup vs baseline: 1.3269x; 1.1266x over previous
//
#include <hip/hip_runtime.h>
#include <hip/hip_bf16.h>

#define NN 20000
#define EE 320000
#define HD 128   // hidden

typedef _Float16 half8 __attribute__((ext_vector_type(8)));
typedef _Float16 half4 __attribute__((ext_vector_type(4)));
typedef _Float16 half2v __attribute__((ext_vector_type(2)));
typedef float floatx4 __attribute__((ext_vector_type(4)));
typedef float float2v __attribute__((ext_vector_type(2)));

// silu via HW rcp (1-ulp) instead of exact fp32 divide.
__device__ __forceinline__ float silu_f(float x){
  float e = __expf(-x);
  return x * __builtin_amdgcn_rcpf(1.f + e);
}

__device__ __forceinline__ bool ei_is64(const int* __restrict__ ei){
  return (ei[1] | ei[3] | ei[5] | ei[7]) == 0;
}
__device__ __forceinline__ int ei_src(const int* __restrict__ ei, int e, bool is64){
  return is64 ? ei[2*(size_t)e] : ei[e];
}
__device__ __forceinline__ int ei_dst(const int* __restrict__ ei, int e, bool is64){
  return is64 ? ei[2*(size_t)EE + 2*(size_t)e] : ei[EE + e];
}

__global__ __launch_bounds__(256) void sentinel_kernel(float* __restrict__ out, int n, float val){
  int i = blockIdx.x*256 + threadIdx.x;
  if (i < n) out[i] = val;
}

// ---------------- merged weight packing + cur zeroing (r9 — kept) ----------------
__global__ __launch_bounds__(256) void pack_all_kernel(const float* __restrict__ cw1,
                                                       const float* __restrict__ cw2,
                                                       const float* __restrict__ dw1,
                                                       const float* __restrict__ dw2,
                                                       _Float16* __restrict__ w1p,
                                                       _Float16* __restrict__ w2p,
                                                       _Float16* __restrict__ w1dp,
                                                       _Float16* __restrict__ w2dp,
                                                       int* __restrict__ cur){
  int idx = blockIdx.x*256 + threadIdx.x;
  if (idx >= 319488){
    int j = idx - 319488;
    if (j < NN) cur[j] = 0;
    return;
  }
  if (idx < 196608){
    int j   = idx & 7;
    int ln  = (idx >> 3) & 63;
    int rest= idx >> 9;
    int cb  = rest & 15;
    int rest2 = rest >> 4;
    int ks  = rest2 & 3;
    int l   = rest2 >> 2;
    int k = ks*32 + (ln>>4)*8 + j;
    int c = cb*16 + (ln&15);
    float v = (c < 128) ? cw1[(size_t)l*33152 + (size_t)k*128 + c]
                        : cw1[(size_t)l*33152 + (size_t)(128+k)*128 + (c-128)];
    w1p[idx] = (_Float16)v;
  } else if (idx < 294912){
    int t = idx - 196608;
    int j   = t & 7;
    int ln  = (t >> 3) & 63;
    int rest= t >> 9;
    int cb  = rest & 7;
    int rest2 = rest >> 3;
    int ks  = rest2 & 3;
    int l   = rest2 >> 2;
    int k = ks*32 + (ln>>4)*8 + j;
    int c = cb*16 + (ln&15);
    w2p[t] = (_Float16)cw2[(size_t)l*16384 + (size_t)k*128 + c];
  } else {
    int t2 = idx - 294912;
    if (t2 < 16384){
      int j = t2 & 7, ln = (t2>>3)&63, cb = (t2>>9)&7, ks = t2>>12;
      int k = ks*32 + (ln>>4)*8 + j;
      int c = cb*16 + (ln&15);
      w1dp[t2] = (_Float16)dw1[(size_t)k*128 + c];
    } else {
      int t = t2 - 16384;
      int j = t & 7, ln = (t>>3)&63, cb = (t>>9)&3, ks = t>>11;
      int k = ks*32 + (ln>>4)*8 + j;
      int c = cb*16 + (ln&15);
      w2dp[t] = (_Float16)dw2[(size_t)k*64 + c];
    }
  }
}

// ---------------- CSR build (r12 exact) ----------------
__global__ __launch_bounds__(256) void count_kernel(const int* __restrict__ ei,
                                                    int* __restrict__ cnt,
                                                    int* __restrict__ rank){
  int e = blockIdx.x*256 + threadIdx.x;   // EE/256 exact
  bool is64 = ei_is64(ei);
  rank[e] = atomicAdd(&cnt[ei_dst(ei, e, is64)], 1);
}

__global__ __launch_bounds__(1024) void scan_kernel(const int* __restrict__ cntcur,
                                                    int* __restrict__ row_start,
                                                    float* __restrict__ invd){
  __shared__ int part[1024];
  const int t = threadIdx.x;
  const int base = t*20;
  int loc[20];
  int sum = 0;
  #pragma unroll
  for (int i=0;i<20;++i){
    int n = base+i;
    int v = (n < NN) ? cntcur[n] : 0;
    loc[i] = sum; sum += v;
  }
  part[t] = sum;
  __syncthreads();
  for (int off=1; off<1024; off<<=1){
    int v = (t >= off) ? part[t-off] : 0;
    __syncthreads();
    part[t] += v;
    __syncthreads();
  }
  int pre = (t > 0) ? part[t-1] : 0;
  #pragma unroll
  for (int i=0;i<20;++i){
    int n = base+i;
    if (n < NN){
      int rs = pre + loc[i];
      int deg = ((i<19)?loc[i+1]:sum) - loc[i];
      row_start[n] = rs;
      invd[n] = (deg > 0) ? 1.f/(float)deg : 0.f;
    }
  }
  if (t == 1023) row_start[NN] = part[1023];
}

// ---------------- scatter + encoder merged (r12 exact) ----------------
__global__ __launch_bounds__(128) void scatter_encoder_kernel(
    const int* __restrict__ ei, const float* __restrict__ eattr,
    const int* __restrict__ rstart, const int* __restrict__ rank,
    int4* __restrict__ rec,
    const float* __restrict__ x, const float* __restrict__ w1, const float* __restrict__ b1,
    const float* __restrict__ w2, const float* __restrict__ b2,
    float* __restrict__ h, _Float16* __restrict__ hh)
{
  __shared__ float xs[16][14];
  __shared__ float s1[16][128];
  const int tid = threadIdx.x;

  if (blockIdx.x < 2500){
    int e = blockIdx.x*128 + tid;       // 2500*128 = 320000 exact
    bool is64 = ei_is64(ei);
    int s = ei_src(ei, e, is64);
    int d = ei_dst(ei, e, is64);
    int pos = rstart[d] + rank[e];
    int4 r;
    r.x = __float_as_int(eattr[(size_t)e*3+0]);
    r.y = __float_as_int(eattr[(size_t)e*3+1]);
    r.z = __float_as_int(eattr[(size_t)e*3+2]);
    r.w = s*256;   // pre-scaled UV row element-offset
    rec[pos] = r;
    return;
  }

  const int n0 = (blockIdx.x - 2500)*16;
  for (int idx=tid; idx<224; idx+=128){
    int i = idx/14, k = idx%14;
    xs[i][k] = x[(size_t)(n0+i)*14 + k];
  }
  __syncthreads();
  const int o = tid;
  float acc[16];
  float bv = b1[o];
  #pragma unroll
  for (int i=0;i<16;++i) acc[i] = bv;
  for (int k=0;k<14;++k){
    float w = w1[k*128+o];
    #pragma unroll
    for (int i=0;i<16;++i) acc[i] += xs[i][k]*w;
  }
  #pragma unroll
  for (int i=0;i<16;++i) s1[i][o] = silu_f(acc[i]);
  __syncthreads();
  float bv2 = b2[o];
  #pragma unroll
  for (int i=0;i<16;++i) acc[i] = bv2;
  for (int k=0;k<128;k+=4){
    float w0=w2[(k+0)*128+o], w1v=w2[(k+1)*128+o], w2v=w2[(k+2)*128+o], w3v=w2[(k+3)*128+o];
    #pragma unroll
    for (int i=0;i<16;++i){
      float4 sv = *(const float4*)&s1[i][k];
      acc[i] += sv.x*w0 + sv.y*w1v + sv.z*w2v + sv.w*w3v;
    }
  }
  #pragma unroll
  for (int i=0;i<16;++i){
    size_t off = (size_t)(n0+i)*HD + o;
    h[off] = acc[i];
    hh[off] = (_Float16)acc[i];
  }
}

// ---------------- proj (r4 exact): layer-0 UV from hh ----------------
__global__ __launch_bounds__(256) void proj_kernel(
    const _Float16* __restrict__ hh, const _Float16* __restrict__ w1p,
    const float* __restrict__ b1, _Float16* __restrict__ UV)
{
  const int tid = threadIdx.x;
  const int wv  = tid >> 6;
  const int ln  = tid & 63;
  const int q   = ln >> 4;
  const int m   = ln & 15;
  const int n0  = blockIdx.x*16;      // grid = NN/16 = 1250 exact

  floatx4 acc[4];
  #pragma unroll
  for (int j=0;j<4;++j) acc[j] = (floatx4){0.f,0.f,0.f,0.f};

  #pragma unroll
  for (int ks=0; ks<4; ++ks){
    half8 a = *(const half8*)(hh + (size_t)(n0+m)*HD + ks*32 + q*8);
    const _Float16* wb = w1p + (size_t)(ks*16*64 + ln)*8;
    #pragma unroll
    for (int j=0; j<4; ++j){
      half8 b = *(const half8*)(wb + (size_t)(wv*4+j)*512);
      acc[j] = __builtin_amdgcn_mfma_f32_16x16x32_f16(a, b, acc[j], 0,0,0);
    }
  }
  #pragma unroll
  for (int j=0; j<4; ++j){
    const int c = (wv*4+j)*16 + m;
    const float bias = (c < 128) ? b1[c] : 0.f;
    #pragma unroll
    for (int r=0;r<4;++r)
      UV[(size_t)(n0+q*4+r)*256 + c] = (_Float16)(acc[j][r] + bias);
  }
}

// ---------------- fused layer (r13): 1024 thr = 16 waves = 16 nodes ----------------
// Edge phase is r4's edge_agg VERBATIM per wave (1 node/wave — the r2 fusion's
// 4-nodes/wave serialization is gone). S lives in LDS (no 10MB/layer HBM
// round-trip). Node phases reuse the block's S/h: S·W2 (waves 0-7, 1 cb each),
// coalesced h RMW, then proj(l+1) (16 waves, 1 cb each) or decoder (l==5).
// launch_bounds(1024,8) -> <=64 VGPR -> 2 blocks/CU -> 8 waves/SIMD preserved.
__device__ __forceinline__ float2v edge_contrib(int4 r, half2v v, float2v u,
                                                float2v wc0, float2v wc1, float2v wc2){
  float2v p = u;
  p += __int_as_float(r.x) * wc0;
  p += __int_as_float(r.y) * wc1;
  p += __int_as_float(r.z) * wc2;
  p[0] += (float)v[0];
  p[1] += (float)v[1];
  float2v s;
  s[0] = silu_f(p[0]);
  s[1] = silu_f(p[1]);
  return s;
}

__global__ __launch_bounds__(1024, 8) void layer_kernel(
    const _Float16* __restrict__ UVc, _Float16* __restrict__ UVn,
    const int* __restrict__ row_start, const int4* __restrict__ rec,
    const float* __restrict__ w1e, const float* __restrict__ invd,
    const _Float16* __restrict__ w2p, const float* __restrict__ b2,
    float* __restrict__ h,
    const _Float16* __restrict__ w1pn, const float* __restrict__ b1n,
    int do_proj,
    const _Float16* __restrict__ w1dp, const float* __restrict__ db1,
    const _Float16* __restrict__ w2dp, const float* __restrict__ db2,
    const float* __restrict__ dw3, const float* __restrict__ db3,
    float* __restrict__ out, int do_dec)
{
  __shared__ _Float16 Sl[16][136];
  __shared__ _Float16 hl[16][136];
  __shared__ __align__(16) char ubuf[8576];           // dl | (d1 + s2m)
  float    (*dl)[132]  = (float(*)[132])ubuf;         // 16*132*4 = 8448
  _Float16 (*d1)[136]  = (_Float16(*)[136])ubuf;      // 16*136*2 = 4352
  float    (*s2m)[66]  = (float(*)[66])(ubuf + 4352); // 16*66*4  = 4224

  const int tid = threadIdx.x;
  const int w   = __builtin_amdgcn_readfirstlane(tid >> 6);   // wave 0..15
  const int ln  = tid & 63;
  const int q   = ln >> 4;
  const int m   = ln & 15;
  const int n0  = blockIdx.x*16;      // grid = NN/16 = 1250 exact

  // ---- phase 0: edge aggregation, 1 node per wave (r4-identical) ----
  {
    const int n  = n0 + w;
    const int c0 = ln*2;
    const float2v wc0 = *(const float2v*)(w1e +   0 + c0);
    const float2v wc1 = *(const float2v*)(w1e + 128 + c0);
    const float2v wc2 = *(const float2v*)(w1e + 256 + c0);

    half2v uvp = *(const half2v*)(UVc + (size_t)n*256 + c0);
    float2v u; u[0] = (float)uvp[0]; u[1] = (float)uvp[1];

    const int rs = row_start[n], re = row_start[n+1];
    float2v a0 = {0.f,0.f}, a1 = {0.f,0.f}, a2 = {0.f,0.f}, a3 = {0.f,0.f};

    const int nq = (re - rs) >> 2;
    int e = rs;
    for (int qq = 0; qq < nq; ++qq, e += 4){
      const int4 r0 = rec[e+0];
      const int4 r1 = rec[e+1];
      const int4 r2 = rec[e+2];
      const int4 r3 = rec[e+3];
      const half2v v0 = *(const half2v*)(UVc + (size_t)r0.w + 128 + c0);
      const half2v v1 = *(const half2v*)(UVc + (size_t)r1.w + 128 + c0);
      const half2v v2 = *(const half2v*)(UVc + (size_t)r2.w + 128 + c0);
      const half2v v3 = *(const half2v*)(UVc + (size_t)r3.w + 128 + c0);
      a0 += edge_contrib(r0, v0, u, wc0, wc1, wc2);
      a1 += edge_contrib(r1, v1, u, wc0, wc1, wc2);
      a2 += edge_contrib(r2, v2, u, wc0, wc1, wc2);
      a3 += edge_contrib(r3, v3, u, wc0, wc1, wc2);
    }
    if (e < re){
      const int e1 = (e+1 < re) ? e+1 : e;
      const int e2 = (e+2 < re) ? e+2 : e;
      const int4 r0 = rec[e];
      const int4 r1 = rec[e1];
      const int4 r2 = rec[e2];
      const half2v v0 = *(const half2v*)(UVc + (size_t)r0.w + 128 + c0);
      const half2v v1 = *(const half2v*)(UVc + (size_t)r1.w + 128 + c0);
      const half2v v2 = *(const half2v*)(UVc + (size_t)r2.w + 128 + c0);
      a0 += edge_contrib(r0, v0, u, wc0, wc1, wc2);
      if (e+1 < re) a1 += edge_contrib(r1, v1, u, wc0, wc1, wc2);
      if (e+2 < re) a2 += edge_contrib(r2, v2, u, wc0, wc1, wc2);
    }
    float2v a = (a0 + a1) + (a2 + a3);
    const float iv = invd[n];
    half2v outv; outv[0] = (_Float16)(a[0]*iv); outv[1] = (_Float16)(a[1]*iv);
    *(half2v*)&Sl[w][c0] = outv;
  }
  __syncthreads();

  // ---- phase 1: S·W2 -> dl (waves 0-7, one 16x16 col-block each) ----
  if (w < 8){
    floatx4 acc = (floatx4){0.f,0.f,0.f,0.f};
    #pragma unroll
    for (int ks=0; ks<4; ++ks){
      half8 a = *(const half8*)&Sl[m][ks*32 + q*8];
      half8 b = *(const half8*)(w2p + (size_t)(ks*8*64 + ln)*8 + (size_t)w*512);
      acc = __builtin_amdgcn_mfma_f32_16x16x32_f16(a, b, acc, 0,0,0);
    }
    const int c = w*16 + m;
    #pragma unroll
    for (int r=0;r<4;++r) dl[q*4+r][c] = acc[r];
  }
  __syncthreads();

  // ---- phase 2: coalesced h RMW (2 ch/thread); hl fp16 ----
  {
    const int row = w;                  // 2048 elems / 1024 thr = 2 each
    const int col = ln*2;
    const float g = (invd[n0 + row] > 0.f) ? 1.f : 0.f;
    float2 hv = *(const float2*)&h[(size_t)(n0+row)*HD + col];
    float2 bv = *(const float2*)&b2[col];
    float2 dv = *(const float2*)&dl[row][col];
    hv.x += dv.x + g*bv.x;
    hv.y += dv.y + g*bv.y;
    if (!do_dec)
      *(float2*)&h[(size_t)(n0+row)*HD + col] = hv;
    half2v p; p[0] = (_Float16)hv.x; p[1] = (_Float16)hv.y;
    *(half2v*)&hl[row][col] = p;
  }
  __syncthreads();

  // ---- phase 3a: fused proj(l+1) (16 waves, one col-block each) ----
  if (do_proj){
    floatx4 acc = (floatx4){0.f,0.f,0.f,0.f};
    #pragma unroll
    for (int ks=0; ks<4; ++ks){
      half8 a = *(const half8*)&hl[m][ks*32 + q*8];
      half8 b = *(const half8*)(w1pn + (size_t)(ks*16*64 + ln)*8 + (size_t)w*512);
      acc = __builtin_amdgcn_mfma_f32_16x16x32_f16(a, b, acc, 0,0,0);
    }
    const int c = w*16 + m;
    const float bias = (c < 128) ? b1n[c] : 0.f;
    #pragma unroll
    for (int r=0;r<4;++r)
      UVn[(size_t)(n0+q*4+r)*256 + c] = (_Float16)(acc[r] + bias);
  }

  // ---- phase 3b: fused decoder (l==5) ----
  if (do_dec){
    if (w < 8){
      floatx4 acc = (floatx4){0.f,0.f,0.f,0.f};
      #pragma unroll
      for (int ks=0; ks<4; ++ks){
        half8 a = *(const half8*)&hl[m][ks*32 + q*8];
        half8 b = *(const half8*)(w1dp + (size_t)(ks*8*64 + ln)*8 + (size_t)w*512);
        acc = __builtin_amdgcn_mfma_f32_16x16x32_f16(a, b, acc, 0,0,0);
      }
      const int c = w*16 + m;
      const float bv = db1[c];
      #pragma unroll
      for (int r=0;r<4;++r)
        d1[q*4+r][c] = (_Float16)silu_f(acc[r] + bv);
    }
    __syncthreads();

    if (w < 4){
      floatx4 acc = (floatx4){0.f,0.f,0.f,0.f};
      #pragma unroll
      for (int ks=0; ks<4; ++ks){
        half8 a = *(const half8*)&d1[m][ks*32 + q*8];
        half8 b = *(const half8*)(w2dp + (size_t)(ks*4*64 + ln)*8 + (size_t)w*512);
        acc = __builtin_amdgcn_mfma_f32_16x16x32_f16(a, b, acc, 0,0,0);
      }
      const int c = w*16 + m;
      const float bv = db2[c];
      #pragma unroll
      for (int r=0;r<4;++r)
        s2m[q*4+r][c] = silu_f(acc[r] + bv);
    }
    __syncthreads();

    if (tid < 144){
      int i = tid/9, oo = tid%9;
      float a = db3[oo];
      #pragma unroll 8
      for (int k=0;k<64;++k) a += s2m[i][k]*dw3[k*9+oo];
      out[(size_t)(n0+i)*9 + oo] = a;
    }
  }
}

// ---------------- workspace layout (43,119,040 B) ----------------
constexpr size_t OFF_H    = 0;                         // 10,240,000
constexpr size_t OFF_HH   = 10240000;                  //  5,120,000
constexpr size_t OFF_UVA  = 15360000;                  // 10,240,000
constexpr size_t OFF_UVB  = 25600000;                  // 10,240,000
constexpr size_t OFF_INVD = 35840000;                  //     80,000
constexpr size_t OFF_RS   = 35920000;                  //     80,064
constexpr size_t OFF_CUR  = 36000064;                  //     80,000
constexpr size_t OFF_REC  = 36080064;                  //  5,120,000 (int4/edge)
constexpr size_t OFF_RANK = 41200064;                  //  1,280,000 (int/edge)
constexpr size_t OFF_W1P  = 42480064;                  //    393,216
constexpr size_t OFF_W2P  = 42873280;                  //    196,608
constexpr size_t OFF_DW1P = 43069888;                  //     32,768
constexpr size_t OFF_DW2P = 43102656;                  //     16,384
constexpr size_t WS_NEEDED= 43119040;

extern "C" void kernel_launch(void* const* d_in, const int* in_sizes, int n_in,
                              void* d_out, int out_size, void* d_ws, size_t ws_size,
                              hipStream_t stream)
{
  float* out = (float*)d_out;
  const int nout_blk = (out_size + 255)/256;

  static const int EXP_SIZES[17] = {280000,640000,960000,1792,128,16384,128,
                                    198912,768,98304,768,16384,128,8192,64,576,9};
  if (n_in != 17){
    sentinel_kernel<<<nout_blk, 256, 0, stream>>>(out, out_size, 2.0e7f + (float)n_in*1.0e3f);
    return;
  }
  for (int i = 0; i < 17; ++i){
    if (in_sizes[i] != EXP_SIZES[i]){
      int sz = in_sizes[i] < 99999 ? in_sizes[i] : 99999;
      sentinel_kernel<<<nout_blk, 256, 0, stream>>>(out, out_size,
          1.0e7f + (float)i*1.0e5f + (float)sz);
      return;
    }
  }
  if (ws_size < WS_NEEDED){
    sentinel_kernel<<<nout_blk, 256, 0, stream>>>(out, out_size, 1.0e6f);
    return;
  }

  const float* x       = (const float*)d_in[0];
  const int*   ei      = (const int*)  d_in[1];
  const float* eattr   = (const float*)d_in[2];
  const float* enc_w1  = (const float*)d_in[3];
  const float* enc_b1  = (const float*)d_in[4];
  const float* enc_w2  = (const float*)d_in[5];
  const float* enc_b2  = (const float*)d_in[6];
  const float* conv_w1 = (const float*)d_in[7];
  const float* conv_b1 = (const float*)d_in[8];
  const float* conv_w2 = (const float*)d_in[9];
  const float* conv_b2 = (const float*)d_in[10];
  const float* dec_w1  = (const float*)d_in[11];
  const float* dec_b1  = (const float*)d_in[12];
  const float* dec_w2  = (const float*)d_in[13];
  const float* dec_b2  = (const float*)d_in[14];
  const float* dec_w3  = (const float*)d_in[15];
  const float* dec_b3  = (const float*)d_in[16];

  char* ws = (char*)d_ws;
  float*    h     = (float*)   (ws + OFF_H);
  _Float16* hh    = (_Float16*)(ws + OFF_HH);
  _Float16* UVa   = (_Float16*)(ws + OFF_UVA);
  _Float16* UVb   = (_Float16*)(ws + OFF_UVB);
  float*    invd  = (float*)   (ws + OFF_INVD);
  int*      rstart= (int*)     (ws + OFF_RS);
  int*      cur   = (int*)     (ws + OFF_CUR);
  int4*     rec   = (int4*)    (ws + OFF_REC);
  int*      rank  = (int*)     (ws + OFF_RANK);
  _Float16* w1p   = (_Float16*)(ws + OFF_W1P);
  _Float16* w2p   = (_Float16*)(ws + OFF_W2P);
  _Float16* w1dp  = (_Float16*)(ws + OFF_DW1P);
  _Float16* w2dp  = (_Float16*)(ws + OFF_DW2P);

  pack_all_kernel<<<1327, 256, 0, stream>>>(conv_w1, conv_w2, dec_w1, dec_w2,
                                            w1p, w2p, w1dp, w2dp, cur);
  count_kernel<<<EE/256, 256, 0, stream>>>(ei, cur, rank);
  scan_kernel<<<1, 1024, 0, stream>>>(cur, rstart, invd);
  scatter_encoder_kernel<<<3750, 128, 0, stream>>>(ei, eattr, rstart, rank, rec,
                                                   x, enc_w1, enc_b1, enc_w2, enc_b2,
                                                   h, hh);
  proj_kernel<<<NN/16, 256, 0, stream>>>(hh, w1p, conv_b1, UVa);   // layer 0 proj
  for (int l=0; l<6; ++l){
    _Float16* UVc = (l & 1) ? UVb : UVa;
    _Float16* UVn = (l & 1) ? UVa : UVb;
    const int lp = (l < 5) ? l+1 : 0;   // dummy valid ptrs for last layer
    layer_kernel<<<NN/16, 1024, 0, stream>>>(UVc, UVn, rstart, rec,
                                             conv_w1 + (size_t)l*33152 + 32768,
                                             invd,
                                             w2p + (size_t)l*16384,
                                             conv_b2 + (size_t)l*128,
                                             h,
                                             w1p + (size_t)lp*32768,
                                             conv_b1 + (size_t)lp*128,
                                             (l < 5) ? 1 : 0,
                                             w1dp, dec_b1, w2dp, dec_b2,
                                             dec_w3, dec_b3, out,
                                             (l == 5) ? 1 : 0);
  }
}